// Round 5
// baseline (1120.935 us; speedup 1.0000x reference)
//
#include <hip/hip_runtime.h>
#include <hip/hip_bf16.h>
#include <math.h>

using bf16 = __hip_bfloat16;
typedef short s16x8 __attribute__((ext_vector_type(8)));
typedef short s16x4 __attribute__((ext_vector_type(4)));
typedef float f32x4 __attribute__((ext_vector_type(4)));

#define DEVI __device__ __forceinline__

static constexpr int NB    = 4;
static constexpr int NTOK  = 1024;
static constexpr int DIM   = 768;
static constexpr int NH    = 12;
static constexpr int MLPD  = 3072;
static constexpr int NLAYER= 4;
static constexpr int NIMG  = 4;
static constexpr int NCLS  = 1000;
static constexpr int MR    = NB * NTOK;   // 4096 rows
static constexpr size_t SLAB = (size_t)MR * 768;  // embed GEMM output slab (f32 elems)

DEVI float b2f(bf16 v){ return __bfloat162float(v); }
DEVI bf16  f2b(float v){ return __float2bfloat16(v); }
DEVI float bu2f(unsigned short u){ union{unsigned u32; float f;} w; w.u32 = ((unsigned)u)<<16; return w.f; }
DEVI unsigned short f2bu(float f){ bf16 b = f2b(f); return *(unsigned short*)&b; }

DEVI void async16(const void* g, void* l) {
  __builtin_amdgcn_global_load_lds((const __attribute__((address_space(1))) void*)g,
                                   (__attribute__((address_space(3))) void*)l, 16, 0, 0);
}

DEVI f32x4 mfma16(s16x8 a, s16x8 b, f32x4 c) {
  return __builtin_amdgcn_mfma_f32_16x16x32_bf16(a, b, c, 0, 0, 0);
}

template<int N> DEVI void waitcnt_vm() {
  if constexpr (N == 0)      asm volatile("s_waitcnt vmcnt(0)" ::: "memory");
  else if constexpr (N == 2) asm volatile("s_waitcnt vmcnt(2)" ::: "memory");
  else if constexpr (N == 3) asm volatile("s_waitcnt vmcnt(3)" ::: "memory");
  else if constexpr (N == 4) asm volatile("s_waitcnt vmcnt(4)" ::: "memory");
  else if constexpr (N == 6) asm volatile("s_waitcnt vmcnt(6)" ::: "memory");
}

DEVI float block_sum(float v, float* scratch, int tid) {
  #pragma unroll
  for (int o = 32; o >= 1; o >>= 1) v += __shfl_xor(v, o);
  __syncthreads();
  if ((tid & 63) == 0) scratch[tid >> 6] = v;
  __syncthreads();
  return scratch[0] + scratch[1] + scratch[2] + scratch[3];
}

DEVI float block_max(float v, float* scratch, int tid) {
  #pragma unroll
  for (int o = 32; o >= 1; o >>= 1) v = fmaxf(v, __shfl_xor(v, o));
  __syncthreads();
  if ((tid & 63) == 0) scratch[tid >> 6] = v;
  __syncthreads();
  return fmaxf(fmaxf(scratch[0], scratch[1]), fmaxf(scratch[2], scratch[3]));
}

// ---------------------------------------------------------------- transpose + f32->bf16 convert
// 128x128 tiles: 64KB read / 32KB write per block; 512B read bursts, 256B write bursts.
// Register-staged loads (16 in flight) then LDS; column gather pitch 132 u16 (~2-way aliasing).
struct TEntry { const float* src; bf16* dst; int R, C, tiles, tC; };
struct TDesc  { TEntry e[22]; };

__global__ __launch_bounds__(256) void transpose_kernel(TDesc D, int nent) {
  int bid = blockIdx.x, ei = 0;
  while (ei < nent - 1 && bid >= D.e[ei].tiles) { bid -= D.e[ei].tiles; ++ei; }
  const TEntry E = D.e[ei];
  const int tr = bid / E.tC, tc = bid % E.tC;
  __shared__ unsigned short t[128][132];   // 33 KB
  const int tid = threadIdx.x;
  {
    const int c = (tid & 31) * 4;          // 32 threads x 4 floats = 128 cols
    const int rb = tid >> 5;               // 0..7
    float4 v[16];
    #pragma unroll
    for (int p = 0; p < 16; ++p)
      v[p] = *(const float4*)(E.src + (size_t)(tr*128 + p*8 + rb)*E.C + tc*128 + c);
    #pragma unroll
    for (int p = 0; p < 16; ++p) {
      unsigned short* dst = &t[p*8 + rb][c];
      dst[0] = f2bu(v[p].x); dst[1] = f2bu(v[p].y); dst[2] = f2bu(v[p].z); dst[3] = f2bu(v[p].w);
    }
  }
  __syncthreads();
  const int n  = tid >> 1;                 // 0..127 output row (= source col)
  const int kh = (tid & 1) * 64;           // which half of the 128 source rows
  #pragma unroll
  for (int p = 0; p < 8; ++p) {
    const int r0 = kh + p*8;
    s16x8 o;
    #pragma unroll
    for (int i = 0; i < 8; ++i) o[i] = (short)t[r0 + i][n];
    *(s16x8*)((short*)E.dst + (size_t)(tc*128 + n)*E.R + tr*128 + r0) = o;
  }
}

// ---------------------------------------------------------------- LayerNorm (768 cols), f32 in, bf16 out
__global__ __launch_bounds__(256) void ln768_kernel(const float* __restrict__ in,
    const float* __restrict__ g, bf16* __restrict__ out)
{
  __shared__ float scratch[4];
  const int row = blockIdx.x, tid = threadIdx.x;
  const float* p = in + (size_t)row*768;
  const float v0 = p[tid], v1 = p[tid+256], v2 = p[tid+512];
  const float s  = block_sum(v0+v1+v2, scratch, tid);
  const float ss = block_sum(v0*v0+v1*v1+v2*v2, scratch, tid);
  const float mu = s * (1.0f/768.0f);
  const float var = ss * (1.0f/768.0f) - mu*mu;
  const float rstd = rsqrtf(var + 1e-5f);
  bf16* o = out + (size_t)row*768;
  o[tid]     = f2b((v0-mu)*rstd*g[tid]);
  o[tid+256] = f2b((v1-mu)*rstd*g[tid+256]);
  o[tid+512] = f2b((v2-mu)*rstd*g[tid+512]);
}

// Fused embed: P holds (patches_ln @ W_emb + b_emb); x = LN(P)*g + pos_h + pos_w;
// xn = LN(x)*g2 (layer-0 attn LN)
__global__ __launch_bounds__(256) void ln_pos2_kernel(const float* __restrict__ P,
    const float* __restrict__ g,
    const float* __restrict__ pos_h, const float* __restrict__ pos_w,
    const int* __restrict__ ppos, float* __restrict__ out,
    const float* __restrict__ g2, bf16* __restrict__ xn)
{
  __shared__ float scratch[4];
  const int row = blockIdx.x, tid = threadIdx.x;
  const size_t base = (size_t)row*768;
  const float* p0 = P + base;
  float v[3];
  #pragma unroll
  for (int i = 0; i < 3; ++i) v[i] = p0[tid + i*256];
  const float s  = block_sum(v[0]+v[1]+v[2], scratch, tid);
  const float ss = block_sum(v[0]*v[0]+v[1]*v[1]+v[2]*v[2], scratch, tid);
  const float mu = s * (1.0f/768.0f);
  const float rstd = rsqrtf(ss*(1.0f/768.0f) - mu*mu + 1e-5f);
  const int p0i = ppos[row*2], p1i = ppos[row*2+1];
  const float* ph = pos_h + (size_t)p0i*768;
  const float* pw = pos_w + (size_t)p1i*768;
  float* o = out + base;
  float xv[3];
  #pragma unroll
  for (int i = 0; i < 3; ++i) {
    const int c = tid + i*256;
    xv[i] = (v[i]-mu)*rstd*g[c] + ph[c] + pw[c];
    o[c] = xv[i];
  }
  // second LN (layer-0 attention LN) on the register-resident row
  const float s2  = block_sum(xv[0]+xv[1]+xv[2], scratch, tid);
  const float ss2 = block_sum(xv[0]*xv[0]+xv[1]*xv[1]+xv[2]*xv[2], scratch, tid);
  const float mu2 = s2 * (1.0f/768.0f);
  const float rstd2 = rsqrtf(ss2*(1.0f/768.0f) - mu2*mu2 + 1e-5f);
  bf16* on = xn + base;
  #pragma unroll
  for (int i = 0; i < 3; ++i) {
    const int c = tid + i*256;
    on[c] = f2b((xv[i]-mu2)*rstd2*g2[c]);
  }
}

// ---------------------------------------------------------------- GEMM (MFMA, XOR-swizzled LDS)
// PD-deep global_load_lds pipeline, counted vmcnt (T3/T4), XCD-bijective swizzle (T1).
// BM: M-tile (128 or 64). BM=64 gives 2x the blocks for small-N GEMMs (occupancy) with
// direct residual += (DO_RES) — replaces the old split-K + slab-reduce path.
// RMSQKV (BM=128/NTILE=64 only): epilogue applies qk-RMSnorm per head slice and writes
// Qb/Kb, or transposes V into VT — replaces the rms_qkv kernel.
template<int DO_BIAS, int DO_GELU, int OUT_BF16, int DO_RES, int BM, int NTILE, int RMSQKV>
__global__ __launch_bounds__(256)
void gemm_mfma(const bf16* __restrict__ A, const bf16* __restrict__ BT,
               const float* __restrict__ bias, float* __restrict__ Cf,
               bf16* __restrict__ Cb,
               const float* __restrict__ qg, const float* __restrict__ kg,
               bf16* __restrict__ Qp, bf16* __restrict__ Kp, bf16* __restrict__ Vp,
               int M, int Nn, int K)
{
  constexpr int MF  = BM / 32;              // m-frags per wave (2 or 4)
  constexpr int NF  = NTILE / 32;           // n-frags per wave (2 or 4)
  constexpr int PD  = 3;                    // pipeline depth (LDS buffers)
  constexpr int LPI = BM/64 + NTILE/64;     // loads per thread per iter
  constexpr int VW  = (PD - 2) * LPI;       // steady-state vmcnt
  __shared__ bf16 As[PD][BM*32];
  __shared__ bf16 Bs[PD][NTILE*32];
  const int tid = threadIdx.x;
  const int wid = tid >> 6, lane = tid & 63;
  const int quad = lane >> 4, l15 = lane & 15;
  const int wy = wid >> 1, wx = wid & 1;

  // XCD-aware bijective swizzle (m204 form)
  const int gx  = gridDim.x;
  const int nwg = gx * gridDim.y;
  const int bid = blockIdx.y * gx + blockIdx.x;
  const int qq  = nwg >> 3, rm = nwg & 7;
  const int xcd = bid & 7,  li = bid >> 3;
  const int swz = (xcd < rm ? xcd * (qq + 1) : rm * (qq + 1) + (xcd - rm) * qq) + li;
  const int m0 = (swz / gx) * BM, n0 = (swz % gx) * NTILE;

  const int rl = lane >> 3;                 // local LDS row 0..7
  const int cs = lane & 7;                  // slot 0..7

  f32x4 acc[MF][NF];
  #pragma unroll
  for (int i = 0; i < MF; ++i)
    #pragma unroll
    for (int j = 0; j < NF; ++j) acc[i][j] = (f32x4){0.f,0.f,0.f,0.f};

  auto stage = [&](int buf, int k0) {
    #pragma unroll
    for (int c = 0; c < BM/64; ++c) {
      const int rbase = wid*8 + c*32;
      const int r_abs = rbase + rl;
      const int ceff  = cs ^ (r_abs & 7);
      const int mg    = 2*r_abs + (ceff >> 2);
      const int jb    = (ceff & 3) * 16;
      async16((const char*)A + ((size_t)(m0 + mg)*K + k0)*2 + jb, (char*)As[buf] + rbase*128);
    }
    #pragma unroll
    for (int c = 0; c < NTILE/64; ++c) {
      const int rbase = wid*8 + c*32;
      const int r_abs = rbase + rl;
      const int ceff  = cs ^ (r_abs & 7);
      const int ng    = 2*r_abs + (ceff >> 2);
      const int jb    = (ceff & 3) * 16;
      async16((const char*)BT + ((size_t)(n0 + ng)*K + k0)*2 + jb, (char*)Bs[buf] + rbase*128);
    }
  };

  auto compute = [&](int cb) {
    s16x8 af[MF], bfr[NF];
    #pragma unroll
    for (int mt = 0; mt < MF; ++mt) {
      const int m = wy*(BM/2) + mt*16 + l15;
      const int r = m >> 1;
      const int cq = (((m & 1) << 2) | quad) ^ (r & 7);
      af[mt] = *(const s16x8*)((const char*)As[cb] + r*128 + cq*16);
    }
    #pragma unroll
    for (int nt = 0; nt < NF; ++nt) {
      const int n = wx*(NTILE/2) + nt*16 + l15;
      const int r = n >> 1;
      const int cq = (((n & 1) << 2) | quad) ^ (r & 7);
      bfr[nt] = *(const s16x8*)((const char*)Bs[cb] + r*128 + cq*16);
    }
    #pragma unroll
    for (int mt = 0; mt < MF; ++mt)
      #pragma unroll
      for (int nt = 0; nt < NF; ++nt)
        acc[mt][nt] = mfma16(af[mt], bfr[nt], acc[mt][nt]);
  };

  const int nk = K >> 5;
  #pragma unroll
  for (int t = 0; t < PD - 1; ++t) stage(t, t << 5);

  int cbuf = 0, sbuf = PD - 1;
  const int mainN = nk - (PD - 1);
  for (int kt = 0; kt < mainN; ++kt) {
    __builtin_amdgcn_sched_barrier(0);
    waitcnt_vm<VW>();                       // tile kt complete; later tiles stay in flight
    __builtin_amdgcn_s_barrier();
    __builtin_amdgcn_sched_barrier(0);
    stage(sbuf, (kt + PD - 1) << 5);
    compute(cbuf);
    cbuf = (cbuf + 1 == PD) ? 0 : cbuf + 1;
    sbuf = (sbuf + 1 == PD) ? 0 : sbuf + 1;
  }
  for (int kt = mainN; kt < nk; ++kt) {     // tail: drain
    __builtin_amdgcn_sched_barrier(0);
    waitcnt_vm<0>();
    __builtin_amdgcn_s_barrier();
    __builtin_amdgcn_sched_barrier(0);
    compute(cbuf);
    cbuf = (cbuf + 1 == PD) ? 0 : cbuf + 1;
  }

  if constexpr (RMSQKV) {
    // BM=128/NTILE=64: this n-tile is exactly one head slice. Rows of acc are tokens.
    __shared__ float red[128][2];
    const int hg = n0 >> 6;                 // 0..35
    const int region = hg / NH;             // 0:Q 1:K 2:V
    const int h  = hg - region*NH;
    const int b  = m0 >> 10;
    const int bh = b*NH + h;
    const int tokb = m0 & (NTOK-1);
    if (region < 2) {
      float sl[MF][4];
      #pragma unroll
      for (int mt = 0; mt < MF; ++mt)
        #pragma unroll
        for (int rr = 0; rr < 4; ++rr) {
          float ssq = 0.f;
          #pragma unroll
          for (int nt = 0; nt < NF; ++nt) ssq += acc[mt][nt][rr]*acc[mt][nt][rr];
          #pragma unroll
          for (int o = 1; o <= 8; o <<= 1) ssq += __shfl_xor(ssq, o);
          sl[mt][rr] = ssq;
        }
      if (l15 == 0) {
        #pragma unroll
        for (int mt = 0; mt < MF; ++mt)
          #pragma unroll
          for (int rr = 0; rr < 4; ++rr)
            red[wy*(BM/2) + mt*16 + quad*4 + rr][wx] = sl[mt][rr];
      }
      __syncthreads();
      const float* gp = (region == 0) ? (qg + n0) : (kg + (n0 - 768));
      bf16* outb = (region == 0) ? Qp : Kp;
      #pragma unroll
      for (int mt = 0; mt < MF; ++mt)
        #pragma unroll
        for (int rr = 0; rr < 4; ++rr) {
          const int rlc = wy*(BM/2) + mt*16 + quad*4 + rr;
          const float rn = 8.0f / fmaxf(sqrtf(red[rlc][0] + red[rlc][1]), 1e-12f);
          const int tok = tokb + rlc;
          #pragma unroll
          for (int nt = 0; nt < NF; ++nt) {
            const int d = wx*32 + nt*16 + l15;
            outb[((size_t)bh*NTOK + tok)*64 + d] = f2b(acc[mt][nt][rr]*rn*gp[d]);
          }
        }
    } else {
      // V: write transposed VT[bh*64+d][tok], 4 consecutive tokens per 8B store
      #pragma unroll
      for (int mt = 0; mt < MF; ++mt)
        #pragma unroll
        for (int nt = 0; nt < NF; ++nt) {
          const int d = wx*32 + nt*16 + l15;
          const int tok = tokb + wy*(BM/2) + mt*16 + quad*4;
          s16x4 pk;
          #pragma unroll
          for (int rr = 0; rr < 4; ++rr) pk[rr] = (short)f2bu(acc[mt][nt][rr]);
          *(s16x4*)((short*)Vp + ((size_t)bh*64 + d)*NTOK + tok) = pk;
        }
    }
  } else {
    #pragma unroll
    for (int nt = 0; nt < NF; ++nt) {
      const int col = n0 + wx*(NTILE/2) + nt*16 + l15;
      float bv = 0.f;
      if constexpr (DO_BIAS) bv = bias[col];
      #pragma unroll
      for (int mt = 0; mt < MF; ++mt) {
        #pragma unroll
        for (int r = 0; r < 4; ++r) {
          const int row = m0 + wy*(BM/2) + mt*16 + quad*4 + r;
          float v = acc[mt][nt][r];
          if constexpr (DO_BIAS) v += bv;
          if constexpr (DO_GELU) v = 0.5f*v*(1.0f + erff(v*0.70710678118654752f));
          const size_t idx = (size_t)row*Nn + col;
          if constexpr (OUT_BF16) Cb[idx] = f2b(v);
          else if constexpr (DO_RES) Cf[idx] += v;
          else Cf[idx] = v;
        }
      }
    }
  }
}

// ---------------------------------------------------------------- small-M GEMM (M=16, K=768)
template<int IN_BF16, int DO_BIAS>
__global__ __launch_bounds__(256) void smallm_gemm(const void* __restrict__ Xv,
    const float* __restrict__ W, const float* __restrict__ bias,
    float* __restrict__ out, int Nn)
{
  __shared__ float Xs[16*768];
  __shared__ float red[4][16][64];
  const int tid = threadIdx.x;
  if constexpr (IN_BF16) {
    const bf16* X = (const bf16*)Xv;
    for (int i = tid; i < 16*768; i += 256) Xs[i] = b2f(X[i]);
  } else {
    const float* X = (const float*)Xv;
    for (int i = tid; i < 16*768; i += 256) Xs[i] = X[i];
  }
  __syncthreads();
  const int cl = tid & 63, kg = tid >> 6;
  const int c = blockIdx.x*64 + cl;
  float acc[16];
  #pragma unroll
  for (int r = 0; r < 16; ++r) acc[r] = 0.f;
  if (c < Nn) {
    const int k0 = kg*192;
    #pragma unroll 4
    for (int k = k0; k < k0 + 192; ++k) {
      const float w = W[(size_t)k*Nn + c];
      #pragma unroll
      for (int r = 0; r < 16; ++r) acc[r] += Xs[r*768 + k] * w;
    }
  }
  #pragma unroll
  for (int r = 0; r < 16; ++r) red[kg][r][cl] = acc[r];
  __syncthreads();
  if (kg == 0 && c < Nn) {
    #pragma unroll
    for (int r = 0; r < 16; ++r) {
      float v = red[0][r][cl] + red[1][r][cl] + red[2][r][cl] + red[3][r][cl];
      if constexpr (DO_BIAS) v += bias[c];
      out[(size_t)r*Nn + c] = v;
    }
  }
}

// ---------------------------------------------------------------- fused MFMA attention
__global__ __launch_bounds__(256) void attn_mfma(const bf16* __restrict__ Qb,
    const bf16* __restrict__ Kb, const bf16* __restrict__ VTb, bf16* __restrict__ Ob,
    const int* __restrict__ ids, const int* __restrict__ lens)
{
  __shared__ bf16 Ps[4][16*72];   // per-wave P tile [m=16][j=64], row stride 72 elems
  __shared__ int  ids_s[NTOK];
  const int qt = blockIdx.x, h = blockIdx.y, b = blockIdx.z;
  const int tid = threadIdx.x;
  const int wid = tid >> 6, lane = tid & 63;
  const int quad = lane >> 4, l15 = lane & 15;
  const int bh = b*NH + h;
  const int q0 = qt*64;
  const int len = lens[b];

  #pragma unroll
  for (int i = 0; i < 4; ++i) ids_s[i*256 + tid] = ids[b*NTOK + i*256 + tid];
  __syncthreads();

  const bf16* qrow = Qb + ((size_t)bh*NTOK + q0 + wid*16 + l15)*64;
  const s16x8 aq0 = *(const s16x8*)(qrow + quad*8);
  const s16x8 aq1 = *(const s16x8*)(qrow + 32 + quad*8);

  int idq[4];
  #pragma unroll
  for (int rr = 0; rr < 4; ++rr) idq[rr] = ids_s[q0 + wid*16 + quad*4 + rr];

  unsigned qm = 0;
  #pragma unroll
  for (int rr = 0; rr < 4; ++rr) qm |= 1u << (idq[rr] & 31);
  #pragma unroll
  for (int o = 32; o >= 1; o >>= 1) qm |= (unsigned)__shfl_xor((int)qm, o);

  f32x4 oacc[4];
  #pragma unroll
  for (int nt = 0; nt < 4; ++nt) oacc[nt] = (f32x4){0.f,0.f,0.f,0.f};
  float mrow[4] = {-3.0e38f,-3.0e38f,-3.0e38f,-3.0e38f};
  float lrow[4] = {0.f,0.f,0.f,0.f};

  const bf16* Kgb = Kb  + (size_t)bh*NTOK*64;
  const bf16* Vgb = VTb + (size_t)bh*64*NTOK;
  bf16* pw = Ps[wid];

  for (int kt = 0; kt < 16; ++kt) {
    const int k0 = kt*64;
    const int idk_l = ids_s[k0 + lane];
    const bool ok = ((k0 + lane) < len) && (((qm >> (idk_l & 31)) & 1u) != 0u);
    if (__ballot(ok) == 0ULL) continue;

    f32x4 sA[4];
    #pragma unroll
    for (int jt = 0; jt < 4; ++jt) {
      const bf16* krow = Kgb + (size_t)(k0 + jt*16 + l15)*64;
      const s16x8 bk0 = *(const s16x8*)(krow + quad*8);
      const s16x8 bk1 = *(const s16x8*)(krow + 32 + quad*8);
      f32x4 s = (f32x4){0.f,0.f,0.f,0.f};
      s = mfma16(aq0, bk0, s);
      s = mfma16(aq1, bk1, s);
      sA[jt] = s;
    }
    #pragma unroll
    for (int jt = 0; jt < 4; ++jt) {
      const int j = k0 + jt*16 + l15;
      const int idk = ids_s[j];
      const bool kvld = j < len;
      #pragma unroll
      for (int rr = 0; rr < 4; ++rr)
        sA[jt][rr] = (kvld && idk == idq[rr]) ? sA[jt][rr] : -3.0e38f;
    }
    float alpha[4], mnew[4];
    #pragma unroll
    for (int rr = 0; rr < 4; ++rr) {
      float mx = fmaxf(fmaxf(sA[0][rr], sA[1][rr]), fmaxf(sA[2][rr], sA[3][rr]));
      mx = fmaxf(mx, __shfl_xor(mx, 1));
      mx = fmaxf(mx, __shfl_xor(mx, 2));
      mx = fmaxf(mx, __shfl_xor(mx, 4));
      mx = fmaxf(mx, __shfl_xor(mx, 8));
      const float mn = fmaxf(mrow[rr], mx);
      mnew[rr] = mn;
      alpha[rr] = expf(mrow[rr] - mn);
      mrow[rr] = mn;
    }
    #pragma unroll
    for (int rr = 0; rr < 4; ++rr) {
      float rs = 0.f;
      #pragma unroll
      for (int jt = 0; jt < 4; ++jt) {
        const float pv = (sA[jt][rr] > -1.0e38f) ? expf(sA[jt][rr] - mnew[rr]) : 0.0f;
        sA[jt][rr] = pv;
        rs += pv;
      }
      rs += __shfl_xor(rs, 1);
      rs += __shfl_xor(rs, 2);
      rs += __shfl_xor(rs, 4);
      rs += __shfl_xor(rs, 8);
      lrow[rr] = lrow[rr]*alpha[rr] + rs;
      #pragma unroll
      for (int nt = 0; nt < 4; ++nt) oacc[nt][rr] *= alpha[rr];
    }
    #pragma unroll
    for (int jt = 0; jt < 4; ++jt)
      #pragma unroll
      for (int rr = 0; rr < 4; ++rr)
        pw[(quad*4+rr)*72 + jt*16 + l15] = f2b(sA[jt][rr]);
    #pragma unroll
    for (int ss = 0; ss < 2; ++ss) {
      const s16x8 ap = *(const s16x8*)(pw + l15*72 + ss*32 + quad*8);
      #pragma unroll
      for (int nt = 0; nt < 4; ++nt) {
        const s16x8 bv = *(const s16x8*)(Vgb + (size_t)(nt*16 + l15)*NTOK + k0 + ss*32 + quad*8);
        oacc[nt] = mfma16(ap, bv, oacc[nt]);
      }
    }
  }

  #pragma unroll
  for (int rr = 0; rr < 4; ++rr) {
    const float inv = lrow[rr] > 0.f ? 1.0f/lrow[rr] : 0.0f;
    const int n = q0 + wid*16 + quad*4 + rr;
    bf16* orow = Ob + ((size_t)b*NTOK + n)*768 + h*64;
    #pragma unroll
    for (int nt = 0; nt < 4; ++nt)
      orow[nt*16 + l15] = f2b(oacc[nt][rr]*inv);
  }
}

// ---------------------------------------------------------------- pooling path
__global__ __launch_bounds__(256) void pool_q_kernel(const float* __restrict__ pool_q,
    const float* __restrict__ pool_ln_g, const float* __restrict__ pWq,
    const float* __restrict__ p_qn_g, float* __restrict__ qp)
{
  __shared__ float xn[768];
  __shared__ float scratch[4];
  __shared__ float qraw[64];
  const int h = blockIdx.x, tid = threadIdx.x;
  float v0 = pool_q[tid], v1 = pool_q[tid+256], v2 = pool_q[tid+512];
  const float s  = block_sum(v0+v1+v2, scratch, tid);
  const float ss = block_sum(v0*v0+v1*v1+v2*v2, scratch, tid);
  const float mu = s*(1.0f/768.0f);
  const float rstd = rsqrtf(ss*(1.0f/768.0f) - mu*mu + 1e-5f);
  xn[tid]     = (v0-mu)*rstd*pool_ln_g[tid];
  xn[tid+256] = (v1-mu)*rstd*pool_ln_g[tid+256];
  xn[tid+512] = (v2-mu)*rstd*pool_ln_g[tid+512];
  __syncthreads();
  const int d = tid >> 2, pp = tid & 3;
  const int col = h*64 + d;
  float acc = 0.f;
  for (int k = pp*192; k < (pp+1)*192; ++k) acc += xn[k]*pWq[(size_t)k*768 + col];
  acc += __shfl_xor(acc, 1); acc += __shfl_xor(acc, 2);
  if (pp == 0) qraw[d] = acc;
  __syncthreads();
  if (tid < 64) {
    const float q = qraw[tid];
    float sq = q*q;
    #pragma unroll
    for (int o = 32; o >= 1; o >>= 1) sq += __shfl_xor(sq, o);
    const float rn = 8.0f / fmaxf(sqrtf(sq), 1e-12f);
    qp[h*64 + tid] = q * rn * p_qn_g[h*64 + tid];
  }
}

__global__ __launch_bounds__(256) void pool_attn_kernel(const bf16* __restrict__ kvp,
    const float* __restrict__ qp, const float* __restrict__ kg,
    const int* __restrict__ ids, const int* __restrict__ lens, float* __restrict__ pooled)
{
  __shared__ float sp[1024];
  __shared__ float qg_s[64];
  __shared__ float scratch[4];
  __shared__ float outred[4][64];
  const int h = blockIdx.x, img = blockIdx.y, b = blockIdx.z;
  const int tid = threadIdx.x;
  const int len = lens[b];
  if (tid < 64) qg_s[tid] = qp[h*64 + tid] * kg[h*64 + tid];
  __syncthreads();

  float smax = -3.0e38f;
  for (int j = tid; j < 1024; j += 256) {
    float sv = -3.0e38f;
    if (j < len && ids[b*NTOK + j] == img) {
      const bf16* kr = kvp + (size_t)(b*NTOK + j)*1536 + h*64;
      float ssq = 0.f, dq = 0.f;
      #pragma unroll
      for (int dd = 0; dd < 64; dd += 8) {
        s16x8 k8 = *(const s16x8*)(kr + dd);
        #pragma unroll
        for (int i = 0; i < 8; ++i) {
          const float kv = bu2f((unsigned short)k8[i]);
          ssq += kv*kv;
          dq  += qg_s[dd+i]*kv;
        }
      }
      const float rn = 8.0f / fmaxf(sqrtf(ssq), 1e-12f);
      sv = dq * rn;
    }
    sp[j] = sv;
    smax = fmaxf(smax, sv);
  }
  const float M = block_max(smax, scratch, tid);
  float lsum = 0.f;
  for (int j = tid; j < 1024; j += 256) {
    const float p = (sp[j] > -1.0e38f) ? expf(sp[j] - M) : 0.0f;
    sp[j] = p;
    lsum += p;
  }
  const float L = block_sum(lsum, scratch, tid);
  const float invL = L > 0.f ? 1.0f / L : 0.0f;

  const int d = tid & 63, jg = tid >> 6;
  float acc = 0.f;
  for (int j = jg; j < 1024; j += 4) {
    const float p = sp[j];
    if (p > 0.f) acc += p * b2f(kvp[(size_t)(b*NTOK + j)*1536 + 768 + h*64 + d]);
  }
  outred[jg][d] = acc;
  __syncthreads();
  if (tid < 64) {
    const float o = (outred[0][tid] + outred[1][tid] + outred[2][tid] + outred[3][tid]) * invL;
    pooled[((size_t)b*NIMG + img)*768 + h*64 + tid] = o;
  }
}

// ---------------------------------------------------------------- host
extern "C" void kernel_launch(void* const* d_in, const int* in_sizes, int n_in,
                              void* d_out, int out_size, void* d_ws, size_t ws_size,
                              hipStream_t stream)
{
  const float* patches    = (const float*)d_in[0];
  const int*   ppos       = (const int*)d_in[1];
  const int*   image_ids  = (const int*)d_in[2];
  const int*   lengths    = (const int*)d_in[3];
  const float* emb_ln_g   = (const float*)d_in[4];
  const float* W_emb      = (const float*)d_in[5];
  const float* b_emb      = (const float*)d_in[6];
  const float* emb_ln2_g  = (const float*)d_in[7];
  const float* pos_h      = (const float*)d_in[8];
  const float* pos_w      = (const float*)d_in[9];
  const float* ln_attn_g  = (const float*)d_in[10];
  const float* Wq         = (const float*)d_in[11];
  const float* Wkv        = (const float*)d_in[12];
  const float* qn_g       = (const float*)d_in[13];
  const float* kn_g       = (const float*)d_in[14];
  const float* Wo         = (const float*)d_in[15];
  const float* ln_ff_g    = (const float*)d_in[16];
  const float* W1         = (const float*)d_in[17];
  const float* b1         = (const float*)d_in[18];
  const float* W2         = (const float*)d_in[19];
  const float* b2v        = (const float*)d_in[20];
  const float* final_ln_g = (const float*)d_in[21];
  const float* pool_q     = (const float*)d_in[22];
  const float* pool_ln_g  = (const float*)d_in[23];
  const float* pWq        = (const float*)d_in[24];
  const float* pWkv       = (const float*)d_in[25];
  const float* p_qn_g     = (const float*)d_in[26];
  const float* p_kn_g     = (const float*)d_in[27];
  const float* pWo        = (const float*)d_in[28];
  const float* head_ln_g  = (const float*)d_in[29];
  const float* W_head     = (const float*)d_in[30];

  char* ws = (char*)d_ws;
  size_t off = 0;
  auto alloc = [&](size_t sz){ size_t r = off; off += (sz + 255) & ~(size_t)255; return r; };

  const size_t o_WembT = alloc((size_t)768*768*2);
  size_t o_QKVT[4], o_WoT[4], o_W1T[4], o_W2T[4];
  for (int l = 0; l < NLAYER; ++l) {
    o_QKVT[l] = alloc((size_t)2304*768*2);
    o_WoT[l]  = alloc((size_t)768*768*2);
    o_W1T[l]  = alloc((size_t)3072*768*2);
    o_W2T[l]  = alloc((size_t)768*3072*2);
  }
  const size_t o_pWkvT = alloc((size_t)1536*768*2);
  const size_t o_x     = alloc((size_t)MR*768*4);
  const size_t o_xn    = alloc((size_t)MR*768*2);
  const size_t o_kv    = alloc((size_t)MR*3072*2);   // bf16: W1-out h (MRx3072); also pool kv
  const size_t o_P     = alloc(SLAB*4);              // embed GEMM f32 output
  const size_t o_Qb    = alloc((size_t)MR*768*2);
  const size_t o_Kb    = alloc((size_t)MR*768*2);
  const size_t o_VT    = alloc((size_t)MR*768*2);
  const size_t o_Ob    = alloc((size_t)MR*768*2);
  const size_t o_qp    = alloc((size_t)768*4);
  const size_t o_pool  = alloc((size_t)16*768*4);
  const size_t o_poolf = alloc((size_t)16*768*4);
  const size_t o_hl    = alloc((size_t)16*768*2);
  if (off > ws_size) return;  // workspace too small: fail visibly (poisoned out)

  float* x    = (float*)(ws + o_x);
  bf16*  xn   = (bf16*)(ws + o_xn);
  bf16*  hb   = (bf16*)(ws + o_kv);    // W1 output (bf16), MRx3072
  bf16*  kvb  = (bf16*)(ws + o_kv);    // pool kv (bf16), reuses same slab
  float* P    = (float*)(ws + o_P);
  bf16*  Qb   = (bf16*)(ws + o_Qb);
  bf16*  Kb   = (bf16*)(ws + o_Kb);
  bf16*  VTb  = (bf16*)(ws + o_VT);
  bf16*  Ob   = (bf16*)(ws + o_Ob);
  float* qp   = (float*)(ws + o_qp);
  float* pooled  = (float*)(ws + o_pool);
  float* pooledf = (float*)(ws + o_poolf);
  bf16*  hl   = (bf16*)(ws + o_hl);

  // ---- batched weight transpose + bf16 convert (128x128 tiles)
  TDesc td; int ne = 0, total = 0;
  auto add = [&](const float* s, size_t dofs, int R, int C){
    td.e[ne].src = s;
    td.e[ne].dst = (bf16*)(ws + dofs);
    td.e[ne].R = R; td.e[ne].C = C;
    td.e[ne].tiles = (R/128)*(C/128); td.e[ne].tC = C/128;
    total += td.e[ne].tiles; ++ne;
  };
  add(W_emb, o_WembT, 768, 768);
  for (int l = 0; l < NLAYER; ++l) {
    add(Wq  + (size_t)l*768*768,  o_QKVT[l],                 768, 768);
    add(Wkv + (size_t)l*768*1536, o_QKVT[l] + (size_t)768*768*2, 768, 1536);
    add(Wo  + (size_t)l*768*768,  o_WoT[l],                  768, 768);
    add(W1  + (size_t)l*768*3072, o_W1T[l],                  768, 3072);
    add(W2  + (size_t)l*3072*768, o_W2T[l],                  3072, 768);
  }
  add(pWkv, o_pWkvT, 768, 1536);
  transpose_kernel<<<total, 256, 0, stream>>>(td, ne);

  // ---- embed: LN -> GEMM(BM=64, +bias) -> fused LN+pos+attnLN0
  ln768_kernel<<<MR, 256, 0, stream>>>(patches, emb_ln_g, xn);
  gemm_mfma<1,0,0,0,64,64,0><<<dim3(12,64), 256, 0, stream>>>(xn, (const bf16*)(ws+o_WembT), b_emb,
      P, nullptr, nullptr, nullptr, nullptr, nullptr, nullptr, MR, 768, 768);
  ln_pos2_kernel<<<MR, 256, 0, stream>>>(P, emb_ln2_g, pos_h, pos_w, ppos, x, ln_attn_g, xn);

  // ---- transformer layers (xn holds LN(x) with this layer's attn gamma at loop entry)
  for (int l = 0; l < NLAYER; ++l) {
    // qkv GEMM with fused qk-RMSnorm + V-transpose epilogue -> Qb/Kb/VTb directly
    gemm_mfma<0,0,0,0,128,64,1><<<dim3(36,32), 256, 0, stream>>>(xn, (const bf16*)(ws+o_QKVT[l]), nullptr,
        nullptr, nullptr, qn_g + (size_t)l*768, kn_g + (size_t)l*768, Qb, Kb, VTb, MR, 2304, 768);
    attn_mfma<<<dim3(16,NH,NB), 256, 0, stream>>>(Qb, Kb, VTb, Ob, image_ids, lengths);
    // Wo: BM=64, direct residual += into x; then LN(ff gamma)
    gemm_mfma<0,0,0,1,64,64,0><<<dim3(12,64), 256, 0, stream>>>(Ob, (const bf16*)(ws+o_WoT[l]), nullptr,
        x, nullptr, nullptr, nullptr, nullptr, nullptr, nullptr, MR, 768, 768);
    ln768_kernel<<<MR, 256, 0, stream>>>(x, ln_ff_g + (size_t)l*768, xn);
    gemm_mfma<1,1,1,0,128,128,0><<<dim3(24,32), 256, 0, stream>>>(xn, (const bf16*)(ws+o_W1T[l]), b1 + (size_t)l*3072,
        nullptr, hb, nullptr, nullptr, nullptr, nullptr, nullptr, MR, 3072, 768);
    // W2: BM=64, direct residual += into x with bias; then LN(next gamma)
    gemm_mfma<1,0,0,1,64,64,0><<<dim3(12,64), 256, 0, stream>>>(hb, (const bf16*)(ws+o_W2T[l]), b2v + (size_t)l*768,
        x, nullptr, nullptr, nullptr, nullptr, nullptr, nullptr, MR, 768, 3072);
    const float* gnext = (l + 1 < NLAYER) ? (ln_attn_g + (size_t)(l+1)*768) : final_ln_g;
    ln768_kernel<<<MR, 256, 0, stream>>>(x, gnext, xn);
  }

  // ---- pooling + head (xn = LN(x, final_ln_g) from the last ln768)
  gemm_mfma<0,0,1,0,128,64,0><<<dim3(24,32), 256, 0, stream>>>(xn, (const bf16*)(ws+o_pWkvT), nullptr,
      nullptr, kvb, nullptr, nullptr, nullptr, nullptr, nullptr, MR, 1536, 768);
  pool_q_kernel<<<NH, 256, 0, stream>>>(pool_q, pool_ln_g, pWq, p_qn_g, qp);
  pool_attn_kernel<<<dim3(NH,NIMG,NB), 256, 0, stream>>>(kvb, qp, p_kn_g, image_ids, lengths, pooled);
  // pooled_final = pooled @ pWo + pool_q (k-parallel small-M GEMM)
  smallm_gemm<0,1><<<12, 256, 0, stream>>>(pooled, pWo, pool_q, pooledf, 768);
  ln768_kernel<<<16, 256, 0, stream>>>(pooledf, head_ln_g, hl);
  // out = LN(pooledf) @ W_head
  smallm_gemm<1,0><<<16, 256, 0, stream>>>(hl, W_head, nullptr, (float*)d_out, NCLS);
}

// Round 6
// 1105.137 us; speedup vs baseline: 1.0143x; 1.0143x over previous
//
#include <hip/hip_runtime.h>
#include <hip/hip_bf16.h>
#include <math.h>

using bf16 = __hip_bfloat16;
typedef short s16x8 __attribute__((ext_vector_type(8)));
typedef short s16x4 __attribute__((ext_vector_type(4)));
typedef float f32x4 __attribute__((ext_vector_type(4)));

#define DEVI __device__ __forceinline__

static constexpr int NB    = 4;
static constexpr int NTOK  = 1024;
static constexpr int DIM   = 768;
static constexpr int NH    = 12;
static constexpr int MLPD  = 3072;
static constexpr int NLAYER= 4;
static constexpr int NIMG  = 4;
static constexpr int NCLS  = 1000;
static constexpr int MR    = NB * NTOK;   // 4096 rows
static constexpr size_t SLAB = (size_t)MR * 768;  // split-K partial slab (f32 elems)

DEVI float b2f(bf16 v){ return __bfloat162float(v); }
DEVI bf16  f2b(float v){ return __float2bfloat16(v); }
DEVI float bu2f(unsigned short u){ union{unsigned u32; float f;} w; w.u32 = ((unsigned)u)<<16; return w.f; }
DEVI unsigned short f2bu(float f){ bf16 b = f2b(f); return *(unsigned short*)&b; }

DEVI void async16(const void* g, void* l) {
  __builtin_amdgcn_global_load_lds((const __attribute__((address_space(1))) void*)g,
                                   (__attribute__((address_space(3))) void*)l, 16, 0, 0);
}

DEVI f32x4 mfma16(s16x8 a, s16x8 b, f32x4 c) {
  return __builtin_amdgcn_mfma_f32_16x16x32_bf16(a, b, c, 0, 0, 0);
}

template<int N> DEVI void waitcnt_vm() {
  if constexpr (N == 0)      asm volatile("s_waitcnt vmcnt(0)" ::: "memory");
  else if constexpr (N == 3) asm volatile("s_waitcnt vmcnt(3)" ::: "memory");
  else if constexpr (N == 4) asm volatile("s_waitcnt vmcnt(4)" ::: "memory");
  else if constexpr (N == 6) asm volatile("s_waitcnt vmcnt(6)" ::: "memory");
}

DEVI float block_sum(float v, float* scratch, int tid) {
  #pragma unroll
  for (int o = 32; o >= 1; o >>= 1) v += __shfl_xor(v, o);
  __syncthreads();
  if ((tid & 63) == 0) scratch[tid >> 6] = v;
  __syncthreads();
  return scratch[0] + scratch[1] + scratch[2] + scratch[3];
}

DEVI float block_max(float v, float* scratch, int tid) {
  #pragma unroll
  for (int o = 32; o >= 1; o >>= 1) v = fmaxf(v, __shfl_xor(v, o));
  __syncthreads();
  if ((tid & 63) == 0) scratch[tid >> 6] = v;
  __syncthreads();
  return fmaxf(fmaxf(scratch[0], scratch[1]), fmaxf(scratch[2], scratch[3]));
}

// ---------------------------------------------------------------- transpose + f32->bf16 convert
// 64x64 tiles; pitch 70 u16 breaks the 8-way phase-2 gather conflict (bank = 24*(tid&7)+n/2).
struct TEntry { const float* src; bf16* dst; int R, C, tiles, tC; };
struct TDesc  { TEntry e[22]; };

__global__ __launch_bounds__(256) void transpose_kernel(TDesc D, int nent) {
  int bid = blockIdx.x, ei = 0;
  while (ei < nent - 1 && bid >= D.e[ei].tiles) { bid -= D.e[ei].tiles; ++ei; }
  const TEntry E = D.e[ei];
  const int tr = bid / E.tC, tc = bid % E.tC;
  __shared__ unsigned short t[64][70];
  const int tid = threadIdx.x;
  {
    const int r = tid >> 4, c = (tid & 15) * 4;
    float4 v[4];
    #pragma unroll
    for (int p = 0; p < 4; ++p)
      v[p] = *(const float4*)(E.src + (size_t)(tr*64 + p*16 + r)*E.C + tc*64 + c);
    #pragma unroll
    for (int p = 0; p < 4; ++p) {
      unsigned short* dst = &t[p*16 + r][c];
      dst[0] = f2bu(v[p].x); dst[1] = f2bu(v[p].y); dst[2] = f2bu(v[p].z); dst[3] = f2bu(v[p].w);
    }
  }
  __syncthreads();
  #pragma unroll
  for (int p = 0; p < 2; ++p) {
    const int n = p*32 + (tid >> 3);
    const int r0 = (tid & 7) * 8;
    s16x8 o;
    #pragma unroll
    for (int i = 0; i < 8; ++i) o[i] = (short)t[r0 + i][n];
    *(s16x8*)((short*)E.dst + (size_t)(tc*64 + n)*E.R + tr*64 + r0) = o;
  }
}

// ---------------------------------------------------------------- LayerNorm (768 cols), f32 in, bf16 out
__global__ __launch_bounds__(256) void ln768_kernel(const float* __restrict__ in,
    const float* __restrict__ g, bf16* __restrict__ out)
{
  __shared__ float scratch[4];
  const int row = blockIdx.x, tid = threadIdx.x;
  const float* p = in + (size_t)row*768;
  const float v0 = p[tid], v1 = p[tid+256], v2 = p[tid+512];
  const float s  = block_sum(v0+v1+v2, scratch, tid);
  const float ss = block_sum(v0*v0+v1*v1+v2*v2, scratch, tid);
  const float mu = s * (1.0f/768.0f);
  const float var = ss * (1.0f/768.0f) - mu*mu;
  const float rstd = rsqrtf(var + 1e-5f);
  bf16* o = out + (size_t)row*768;
  o[tid]     = f2b((v0-mu)*rstd*g[tid]);
  o[tid+256] = f2b((v1-mu)*rstd*g[tid+256]);
  o[tid+512] = f2b((v2-mu)*rstd*g[tid+512]);
}

// Fused split-K reduce + residual + LayerNorm:
// x += P0 + P1 (+bias); xn = LN(x)*g (bf16). x updated in place.
template<int HAS_BIAS>
__global__ __launch_bounds__(256) void res2_ln_kernel(float* __restrict__ x,
    const float* __restrict__ P, const float* __restrict__ bias,
    const float* __restrict__ g, bf16* __restrict__ xn)
{
  __shared__ float scratch[4];
  const int row = blockIdx.x, tid = threadIdx.x;
  const size_t base = (size_t)row*768;
  const float* p0 = P + base;
  const float* p1 = P + SLAB + base;
  float* xr = x + base;
  float v[3];
  #pragma unroll
  for (int i = 0; i < 3; ++i) {
    const int c = tid + i*256;
    float t = xr[c] + p0[c] + p1[c];
    if constexpr (HAS_BIAS) t += bias[c];
    v[i] = t;
    xr[c] = t;
  }
  const float s  = block_sum(v[0]+v[1]+v[2], scratch, tid);
  const float ss = block_sum(v[0]*v[0]+v[1]*v[1]+v[2]*v[2], scratch, tid);
  const float mu = s * (1.0f/768.0f);
  const float rstd = rsqrtf(ss*(1.0f/768.0f) - mu*mu + 1e-5f);
  bf16* o = xn + base;
  #pragma unroll
  for (int i = 0; i < 3; ++i) {
    const int c = tid + i*256;
    o[c] = f2b((v[i]-mu)*rstd*g[c]);
  }
}

// Fused embed: v = P0+P1+b_emb; x = LN(v)*g + pos_h + pos_w; xn = LN(x)*g2 (layer-0 attn LN)
__global__ __launch_bounds__(256) void ln_pos2_kernel(const float* __restrict__ P,
    const float* __restrict__ bias, const float* __restrict__ g,
    const float* __restrict__ pos_h, const float* __restrict__ pos_w,
    const int* __restrict__ ppos, float* __restrict__ out,
    const float* __restrict__ g2, bf16* __restrict__ xn)
{
  __shared__ float scratch[4];
  const int row = blockIdx.x, tid = threadIdx.x;
  const size_t base = (size_t)row*768;
  const float* p0 = P + base;
  const float* p1 = P + SLAB + base;
  float v[3];
  #pragma unroll
  for (int i = 0; i < 3; ++i) {
    const int c = tid + i*256;
    v[i] = p0[c] + p1[c] + bias[c];
  }
  const float s  = block_sum(v[0]+v[1]+v[2], scratch, tid);
  const float ss = block_sum(v[0]*v[0]+v[1]*v[1]+v[2]*v[2], scratch, tid);
  const float mu = s * (1.0f/768.0f);
  const float rstd = rsqrtf(ss*(1.0f/768.0f) - mu*mu + 1e-5f);
  const int p0i = ppos[row*2], p1i = ppos[row*2+1];
  const float* ph = pos_h + (size_t)p0i*768;
  const float* pw = pos_w + (size_t)p1i*768;
  float* o = out + base;
  float xv[3];
  #pragma unroll
  for (int i = 0; i < 3; ++i) {
    const int c = tid + i*256;
    xv[i] = (v[i]-mu)*rstd*g[c] + ph[c] + pw[c];
    o[c] = xv[i];
  }
  // second LN (layer-0 attention LN) on the register-resident row
  const float s2  = block_sum(xv[0]+xv[1]+xv[2], scratch, tid);
  const float ss2 = block_sum(xv[0]*xv[0]+xv[1]*xv[1]+xv[2]*xv[2], scratch, tid);
  const float mu2 = s2 * (1.0f/768.0f);
  const float rstd2 = rsqrtf(ss2*(1.0f/768.0f) - mu2*mu2 + 1e-5f);
  bf16* on = xn + base;
  #pragma unroll
  for (int i = 0; i < 3; ++i) {
    const int c = tid + i*256;
    on[c] = f2b((xv[i]-mu2)*rstd2*g2[c]);
  }
}

// ---------------------------------------------------------------- GEMM (MFMA, XOR-swizzled LDS)
// PD-deep global_load_lds pipeline, counted vmcnt (T3/T4), XCD-bijective swizzle (T1).
// SPLITK>1: blockIdx.z selects a K-chunk; partials to slab z, reduced in res2_ln/ln_pos2.
// RMSQKV (NTILE=128 only): each wave's 64-col half is exactly one head; epilogue applies
// qk-RMSnorm fully in-wave (shfl over l15) and writes Qb/Kb, or transposes V into VT.
template<int DO_BIAS, int DO_GELU, int OUT_BF16, int DO_RES, int NTILE, int SPLITK, int RMSQKV>
__global__ __launch_bounds__(256)
void gemm_mfma(const bf16* __restrict__ A, const bf16* __restrict__ BT,
               const float* __restrict__ bias, float* __restrict__ Cf,
               bf16* __restrict__ Cb,
               const float* __restrict__ qg, const float* __restrict__ kg,
               bf16* __restrict__ Qp, bf16* __restrict__ Kp, bf16* __restrict__ Vp,
               int M, int Nn, int K)
{
  constexpr int NF  = NTILE / 32;           // n-frags per wave (2 or 4)
  constexpr int PD  = 3;                    // pipeline depth (LDS buffers)
  constexpr int LPI = 2 + NTILE/64;         // loads per thread per iter
  constexpr int VW  = (PD - 2) * LPI;       // steady-state vmcnt
  __shared__ bf16 As[PD][64*64];            // PD x 8 KB
  __shared__ bf16 Bs[PD][(NTILE/2)*64];     // PD x (4 or 8) KB
  const int tid = threadIdx.x;
  const int wid = tid >> 6, lane = tid & 63;
  const int quad = lane >> 4, l15 = lane & 15;
  const int wy = wid >> 1, wx = wid & 1;

  // XCD-aware bijective swizzle (m204 form), per K-chunk plane.
  const int gx  = gridDim.x;
  const int nwg = gx * gridDim.y;
  const int bid = blockIdx.y * gx + blockIdx.x;
  const int qq  = nwg >> 3, rm = nwg & 7;
  const int xcd = bid & 7,  li = bid >> 3;
  const int swz = (xcd < rm ? xcd * (qq + 1) : rm * (qq + 1) + (xcd - rm) * qq) + li;
  const int m0 = (swz / gx) * 128, n0 = (swz % gx) * NTILE;

  const int kz    = (SPLITK > 1) ? blockIdx.z : 0;
  const int kloc  = K / SPLITK;             // K per chunk
  const int kbase = kz * kloc;

  const int rl = lane >> 3;                 // local LDS row 0..7
  const int cs = lane & 7;                  // slot 0..7

  f32x4 acc[4][NF];
  #pragma unroll
  for (int i = 0; i < 4; ++i)
    #pragma unroll
    for (int j = 0; j < NF; ++j) acc[i][j] = (f32x4){0.f,0.f,0.f,0.f};

  auto stage = [&](int buf, int k0) {
    #pragma unroll
    for (int c = 0; c < 2; ++c) {
      const int rbase = wid*8 + c*32;
      const int r_abs = rbase + rl;
      const int ceff  = cs ^ (r_abs & 7);
      const int mg    = 2*r_abs + (ceff >> 2);
      const int jb    = (ceff & 3) * 16;
      async16((const char*)A + ((size_t)(m0 + mg)*K + k0)*2 + jb, (char*)As[buf] + rbase*128);
    }
    #pragma unroll
    for (int c = 0; c < NTILE/64; ++c) {
      const int rbase = wid*8 + c*32;
      const int r_abs = rbase + rl;
      const int ceff  = cs ^ (r_abs & 7);
      const int ng    = 2*r_abs + (ceff >> 2);
      const int jb    = (ceff & 3) * 16;
      async16((const char*)BT + ((size_t)(n0 + ng)*K + k0)*2 + jb, (char*)Bs[buf] + rbase*128);
    }
  };

  auto compute = [&](int cb) {
    s16x8 af[4], bfr[NF];
    #pragma unroll
    for (int mt = 0; mt < 4; ++mt) {
      const int m = wy*64 + mt*16 + l15;
      const int r = m >> 1;
      const int cq = (((m & 1) << 2) | quad) ^ (r & 7);
      af[mt] = *(const s16x8*)((const char*)As[cb] + r*128 + cq*16);
    }
    #pragma unroll
    for (int nt = 0; nt < NF; ++nt) {
      const int n = wx*(NTILE/2) + nt*16 + l15;
      const int r = n >> 1;
      const int cq = (((n & 1) << 2) | quad) ^ (r & 7);
      bfr[nt] = *(const s16x8*)((const char*)Bs[cb] + r*128 + cq*16);
    }
    #pragma unroll
    for (int mt = 0; mt < 4; ++mt)
      #pragma unroll
      for (int nt = 0; nt < NF; ++nt)
        acc[mt][nt] = mfma16(af[mt], bfr[nt], acc[mt][nt]);
  };

  const int nk = kloc >> 5;
  #pragma unroll
  for (int t = 0; t < PD - 1; ++t) stage(t, kbase + (t << 5));

  int cbuf = 0, sbuf = PD - 1;
  const int mainN = nk - (PD - 1);
  for (int kt = 0; kt < mainN; ++kt) {
    __builtin_amdgcn_sched_barrier(0);
    waitcnt_vm<VW>();                       // tile kt complete; later tiles stay in flight
    __builtin_amdgcn_s_barrier();
    __builtin_amdgcn_sched_barrier(0);
    stage(sbuf, kbase + ((kt + PD - 1) << 5));
    compute(cbuf);
    cbuf = (cbuf + 1 == PD) ? 0 : cbuf + 1;
    sbuf = (sbuf + 1 == PD) ? 0 : sbuf + 1;
  }
  for (int kt = mainN; kt < nk; ++kt) {     // tail: drain
    __builtin_amdgcn_sched_barrier(0);
    waitcnt_vm<0>();
    __builtin_amdgcn_s_barrier();
    __builtin_amdgcn_sched_barrier(0);
    compute(cbuf);
    cbuf = (cbuf + 1 == PD) ? 0 : cbuf + 1;
  }

  if constexpr (RMSQKV) {
    // NTILE==128: wave wx's 64-col half is exactly one head slice; rms fully in-wave.
    const int hslice = (n0 >> 6) + wx;      // 0..35 (tiles never straddle Q/K/V regions)
    const int region = hslice / NH;         // 0:Q 1:K 2:V
    const int h  = hslice - region*NH;
    const int b  = m0 >> 10;
    const int bh = b*NH + h;
    const int tokb = m0 & (NTOK-1);
    if (region < 2) {
      const float* gp = (region == 0) ? (qg + h*64) : (kg + h*64);
      bf16* outb = (region == 0) ? Qp : Kp;
      #pragma unroll
      for (int mt = 0; mt < 4; ++mt)
        #pragma unroll
        for (int rr = 0; rr < 4; ++rr) {
          float ssq = 0.f;
          #pragma unroll
          for (int nt = 0; nt < NF; ++nt) ssq += acc[mt][nt][rr]*acc[mt][nt][rr];
          #pragma unroll
          for (int o = 1; o <= 8; o <<= 1) ssq += __shfl_xor(ssq, o);
          const float rn = 8.0f / fmaxf(sqrtf(ssq), 1e-12f);
          const int tok = tokb + wy*64 + mt*16 + quad*4 + rr;
          #pragma unroll
          for (int nt = 0; nt < NF; ++nt) {
            const int d = nt*16 + l15;
            outb[((size_t)bh*NTOK + tok)*64 + d] = f2b(acc[mt][nt][rr]*rn*gp[d]);
          }
        }
    } else {
      // V: write transposed VT[bh*64+d][tok], 4 consecutive tokens per 8B store
      #pragma unroll
      for (int mt = 0; mt < 4; ++mt)
        #pragma unroll
        for (int nt = 0; nt < NF; ++nt) {
          const int d = nt*16 + l15;
          const int tok = tokb + wy*64 + mt*16 + quad*4;
          s16x4 pk;
          #pragma unroll
          for (int rr = 0; rr < 4; ++rr) pk[rr] = (short)f2bu(acc[mt][nt][rr]);
          *(s16x4*)((short*)Vp + ((size_t)bh*64 + d)*NTOK + tok) = pk;
        }
    }
  } else {
    float* Cslab = (SPLITK > 1) ? (Cf + (size_t)kz * SLAB) : Cf;
    #pragma unroll
    for (int nt = 0; nt < NF; ++nt) {
      const int col = n0 + wx*(NTILE/2) + nt*16 + l15;
      float bv = 0.f;
      if constexpr (DO_BIAS) bv = bias[col];
      #pragma unroll
      for (int mt = 0; mt < 4; ++mt) {
        #pragma unroll
        for (int r = 0; r < 4; ++r) {
          const int row = m0 + wy*64 + mt*16 + quad*4 + r;
          float v = acc[mt][nt][r];
          if constexpr (DO_BIAS) v += bv;
          if constexpr (DO_GELU) v = 0.5f*v*(1.0f + erff(v*0.70710678118654752f));
          const size_t idx = (size_t)row*Nn + col;
          if constexpr (OUT_BF16) Cb[idx] = f2b(v);
          else if constexpr (DO_RES) Cf[idx] += v;
          else Cslab[idx] = v;
        }
      }
    }
  }
}

// ---------------------------------------------------------------- small-M GEMM (M=16, K=768)
template<int IN_BF16, int DO_BIAS>
__global__ __launch_bounds__(256) void smallm_gemm(const void* __restrict__ Xv,
    const float* __restrict__ W, const float* __restrict__ bias,
    float* __restrict__ out, int Nn)
{
  __shared__ float Xs[16*768];
  __shared__ float red[4][16][64];
  const int tid = threadIdx.x;
  if constexpr (IN_BF16) {
    const bf16* X = (const bf16*)Xv;
    for (int i = tid; i < 16*768; i += 256) Xs[i] = b2f(X[i]);
  } else {
    const float* X = (const float*)Xv;
    for (int i = tid; i < 16*768; i += 256) Xs[i] = X[i];
  }
  __syncthreads();
  const int cl = tid & 63, kg = tid >> 6;
  const int c = blockIdx.x*64 + cl;
  float acc[16];
  #pragma unroll
  for (int r = 0; r < 16; ++r) acc[r] = 0.f;
  if (c < Nn) {
    const int k0 = kg*192;
    #pragma unroll 4
    for (int k = k0; k < k0 + 192; ++k) {
      const float w = W[(size_t)k*Nn + c];
      #pragma unroll
      for (int r = 0; r < 16; ++r) acc[r] += Xs[r*768 + k] * w;
    }
  }
  #pragma unroll
  for (int r = 0; r < 16; ++r) red[kg][r][cl] = acc[r];
  __syncthreads();
  if (kg == 0 && c < Nn) {
    #pragma unroll
    for (int r = 0; r < 16; ++r) {
      float v = red[0][r][cl] + red[1][r][cl] + red[2][r][cl] + red[3][r][cl];
      if constexpr (DO_BIAS) v += bias[c];
      out[(size_t)r*Nn + c] = v;
    }
  }
}

// ---------------------------------------------------------------- fused MFMA attention
__global__ __launch_bounds__(256) void attn_mfma(const bf16* __restrict__ Qb,
    const bf16* __restrict__ Kb, const bf16* __restrict__ VTb, bf16* __restrict__ Ob,
    const int* __restrict__ ids, const int* __restrict__ lens)
{
  __shared__ bf16 Ps[4][16*72];   // per-wave P tile [m=16][j=64], row stride 72 elems
  __shared__ int  ids_s[NTOK];
  const int qt = blockIdx.x, h = blockIdx.y, b = blockIdx.z;
  const int tid = threadIdx.x;
  const int wid = tid >> 6, lane = tid & 63;
  const int quad = lane >> 4, l15 = lane & 15;
  const int bh = b*NH + h;
  const int q0 = qt*64;
  const int len = lens[b];

  #pragma unroll
  for (int i = 0; i < 4; ++i) ids_s[i*256 + tid] = ids[b*NTOK + i*256 + tid];
  __syncthreads();

  const bf16* qrow = Qb + ((size_t)bh*NTOK + q0 + wid*16 + l15)*64;
  const s16x8 aq0 = *(const s16x8*)(qrow + quad*8);
  const s16x8 aq1 = *(const s16x8*)(qrow + 32 + quad*8);

  int idq[4];
  #pragma unroll
  for (int rr = 0; rr < 4; ++rr) idq[rr] = ids_s[q0 + wid*16 + quad*4 + rr];

  unsigned qm = 0;
  #pragma unroll
  for (int rr = 0; rr < 4; ++rr) qm |= 1u << (idq[rr] & 31);
  #pragma unroll
  for (int o = 32; o >= 1; o >>= 1) qm |= (unsigned)__shfl_xor((int)qm, o);

  f32x4 oacc[4];
  #pragma unroll
  for (int nt = 0; nt < 4; ++nt) oacc[nt] = (f32x4){0.f,0.f,0.f,0.f};
  float mrow[4] = {-3.0e38f,-3.0e38f,-3.0e38f,-3.0e38f};
  float lrow[4] = {0.f,0.f,0.f,0.f};

  const bf16* Kgb = Kb  + (size_t)bh*NTOK*64;
  const bf16* Vgb = VTb + (size_t)bh*64*NTOK;
  bf16* pw = Ps[wid];

  for (int kt = 0; kt < 16; ++kt) {
    const int k0 = kt*64;
    const int idk_l = ids_s[k0 + lane];
    const bool ok = ((k0 + lane) < len) && (((qm >> (idk_l & 31)) & 1u) != 0u);
    if (__ballot(ok) == 0ULL) continue;

    f32x4 sA[4];
    #pragma unroll
    for (int jt = 0; jt < 4; ++jt) {
      const bf16* krow = Kgb + (size_t)(k0 + jt*16 + l15)*64;
      const s16x8 bk0 = *(const s16x8*)(krow + quad*8);
      const s16x8 bk1 = *(const s16x8*)(krow + 32 + quad*8);
      f32x4 s = (f32x4){0.f,0.f,0.f,0.f};
      s = mfma16(aq0, bk0, s);
      s = mfma16(aq1, bk1, s);
      sA[jt] = s;
    }
    #pragma unroll
    for (int jt = 0; jt < 4; ++jt) {
      const int j = k0 + jt*16 + l15;
      const int idk = ids_s[j];
      const bool kvld = j < len;
      #pragma unroll
      for (int rr = 0; rr < 4; ++rr)
        sA[jt][rr] = (kvld && idk == idq[rr]) ? sA[jt][rr] : -3.0e38f;
    }
    float alpha[4], mnew[4];
    #pragma unroll
    for (int rr = 0; rr < 4; ++rr) {
      float mx = fmaxf(fmaxf(sA[0][rr], sA[1][rr]), fmaxf(sA[2][rr], sA[3][rr]));
      mx = fmaxf(mx, __shfl_xor(mx, 1));
      mx = fmaxf(mx, __shfl_xor(mx, 2));
      mx = fmaxf(mx, __shfl_xor(mx, 4));
      mx = fmaxf(mx, __shfl_xor(mx, 8));
      const float mn = fmaxf(mrow[rr], mx);
      mnew[rr] = mn;
      alpha[rr] = expf(mrow[rr] - mn);
      mrow[rr] = mn;
    }
    #pragma unroll
    for (int rr = 0; rr < 4; ++rr) {
      float rs = 0.f;
      #pragma unroll
      for (int jt = 0; jt < 4; ++jt) {
        const float pv = (sA[jt][rr] > -1.0e38f) ? expf(sA[jt][rr] - mnew[rr]) : 0.0f;
        sA[jt][rr] = pv;
        rs += pv;
      }
      rs += __shfl_xor(rs, 1);
      rs += __shfl_xor(rs, 2);
      rs += __shfl_xor(rs, 4);
      rs += __shfl_xor(rs, 8);
      lrow[rr] = lrow[rr]*alpha[rr] + rs;
      #pragma unroll
      for (int nt = 0; nt < 4; ++nt) oacc[nt][rr] *= alpha[rr];
    }
    #pragma unroll
    for (int jt = 0; jt < 4; ++jt)
      #pragma unroll
      for (int rr = 0; rr < 4; ++rr)
        pw[(quad*4+rr)*72 + jt*16 + l15] = f2b(sA[jt][rr]);
    #pragma unroll
    for (int ss = 0; ss < 2; ++ss) {
      const s16x8 ap = *(const s16x8*)(pw + l15*72 + ss*32 + quad*8);
      #pragma unroll
      for (int nt = 0; nt < 4; ++nt) {
        const s16x8 bv = *(const s16x8*)(Vgb + (size_t)(nt*16 + l15)*NTOK + k0 + ss*32 + quad*8);
        oacc[nt] = mfma16(ap, bv, oacc[nt]);
      }
    }
  }

  #pragma unroll
  for (int rr = 0; rr < 4; ++rr) {
    const float inv = lrow[rr] > 0.f ? 1.0f/lrow[rr] : 0.0f;
    const int n = q0 + wid*16 + quad*4 + rr;
    bf16* orow = Ob + ((size_t)b*NTOK + n)*768 + h*64;
    #pragma unroll
    for (int nt = 0; nt < 4; ++nt)
      orow[nt*16 + l15] = f2b(oacc[nt][rr]*inv);
  }
}

// ---------------------------------------------------------------- pooling path
__global__ __launch_bounds__(256) void pool_q_kernel(const float* __restrict__ pool_q,
    const float* __restrict__ pool_ln_g, const float* __restrict__ pWq,
    const float* __restrict__ p_qn_g, float* __restrict__ qp)
{
  __shared__ float xn[768];
  __shared__ float scratch[4];
  __shared__ float qraw[64];
  const int h = blockIdx.x, tid = threadIdx.x;
  float v0 = pool_q[tid], v1 = pool_q[tid+256], v2 = pool_q[tid+512];
  const float s  = block_sum(v0+v1+v2, scratch, tid);
  const float ss = block_sum(v0*v0+v1*v1+v2*v2, scratch, tid);
  const float mu = s*(1.0f/768.0f);
  const float rstd = rsqrtf(ss*(1.0f/768.0f) - mu*mu + 1e-5f);
  xn[tid]     = (v0-mu)*rstd*pool_ln_g[tid];
  xn[tid+256] = (v1-mu)*rstd*pool_ln_g[tid+256];
  xn[tid+512] = (v2-mu)*rstd*pool_ln_g[tid+512];
  __syncthreads();
  const int d = tid >> 2, pp = tid & 3;
  const int col = h*64 + d;
  float acc = 0.f;
  for (int k = pp*192; k < (pp+1)*192; ++k) acc += xn[k]*pWq[(size_t)k*768 + col];
  acc += __shfl_xor(acc, 1); acc += __shfl_xor(acc, 2);
  if (pp == 0) qraw[d] = acc;
  __syncthreads();
  if (tid < 64) {
    const float q = qraw[tid];
    float sq = q*q;
    #pragma unroll
    for (int o = 32; o >= 1; o >>= 1) sq += __shfl_xor(sq, o);
    const float rn = 8.0f / fmaxf(sqrtf(sq), 1e-12f);
    qp[h*64 + tid] = q * rn * p_qn_g[h*64 + tid];
  }
}

__global__ __launch_bounds__(256) void pool_attn_kernel(const bf16* __restrict__ kvp,
    const float* __restrict__ qp, const float* __restrict__ kg,
    const int* __restrict__ ids, const int* __restrict__ lens, float* __restrict__ pooled)
{
  __shared__ float sp[1024];
  __shared__ float qg_s[64];
  __shared__ float scratch[4];
  __shared__ float outred[4][64];
  const int h = blockIdx.x, img = blockIdx.y, b = blockIdx.z;
  const int tid = threadIdx.x;
  const int len = lens[b];
  if (tid < 64) qg_s[tid] = qp[h*64 + tid] * kg[h*64 + tid];
  __syncthreads();

  float smax = -3.0e38f;
  for (int j = tid; j < 1024; j += 256) {
    float sv = -3.0e38f;
    if (j < len && ids[b*NTOK + j] == img) {
      const bf16* kr = kvp + (size_t)(b*NTOK + j)*1536 + h*64;
      float ssq = 0.f, dq = 0.f;
      #pragma unroll
      for (int dd = 0; dd < 64; dd += 8) {
        s16x8 k8 = *(const s16x8*)(kr + dd);
        #pragma unroll
        for (int i = 0; i < 8; ++i) {
          const float kv = bu2f((unsigned short)k8[i]);
          ssq += kv*kv;
          dq  += qg_s[dd+i]*kv;
        }
      }
      const float rn = 8.0f / fmaxf(sqrtf(ssq), 1e-12f);
      sv = dq * rn;
    }
    sp[j] = sv;
    smax = fmaxf(smax, sv);
  }
  const float M = block_max(smax, scratch, tid);
  float lsum = 0.f;
  for (int j = tid; j < 1024; j += 256) {
    const float p = (sp[j] > -1.0e38f) ? expf(sp[j] - M) : 0.0f;
    sp[j] = p;
    lsum += p;
  }
  const float L = block_sum(lsum, scratch, tid);
  const float invL = L > 0.f ? 1.0f / L : 0.0f;

  const int d = tid & 63, jg = tid >> 6;
  float acc = 0.f;
  for (int j = jg; j < 1024; j += 4) {
    const float p = sp[j];
    if (p > 0.f) acc += p * b2f(kvp[(size_t)(b*NTOK + j)*1536 + 768 + h*64 + d]);
  }
  outred[jg][d] = acc;
  __syncthreads();
  if (tid < 64) {
    const float o = (outred[0][tid] + outred[1][tid] + outred[2][tid] + outred[3][tid]) * invL;
    pooled[((size_t)b*NIMG + img)*768 + h*64 + tid] = o;
  }
}

// ---------------------------------------------------------------- host
extern "C" void kernel_launch(void* const* d_in, const int* in_sizes, int n_in,
                              void* d_out, int out_size, void* d_ws, size_t ws_size,
                              hipStream_t stream)
{
  const float* patches    = (const float*)d_in[0];
  const int*   ppos       = (const int*)d_in[1];
  const int*   image_ids  = (const int*)d_in[2];
  const int*   lengths    = (const int*)d_in[3];
  const float* emb_ln_g   = (const float*)d_in[4];
  const float* W_emb      = (const float*)d_in[5];
  const float* b_emb      = (const float*)d_in[6];
  const float* emb_ln2_g  = (const float*)d_in[7];
  const float* pos_h      = (const float*)d_in[8];
  const float* pos_w      = (const float*)d_in[9];
  const float* ln_attn_g  = (const float*)d_in[10];
  const float* Wq         = (const float*)d_in[11];
  const float* Wkv        = (const float*)d_in[12];
  const float* qn_g       = (const float*)d_in[13];
  const float* kn_g       = (const float*)d_in[14];
  const float* Wo         = (const float*)d_in[15];
  const float* ln_ff_g    = (const float*)d_in[16];
  const float* W1         = (const float*)d_in[17];
  const float* b1         = (const float*)d_in[18];
  const float* W2         = (const float*)d_in[19];
  const float* b2v        = (const float*)d_in[20];
  const float* final_ln_g = (const float*)d_in[21];
  const float* pool_q     = (const float*)d_in[22];
  const float* pool_ln_g  = (const float*)d_in[23];
  const float* pWq        = (const float*)d_in[24];
  const float* pWkv       = (const float*)d_in[25];
  const float* p_qn_g     = (const float*)d_in[26];
  const float* p_kn_g     = (const float*)d_in[27];
  const float* pWo        = (const float*)d_in[28];
  const float* head_ln_g  = (const float*)d_in[29];
  const float* W_head     = (const float*)d_in[30];

  char* ws = (char*)d_ws;
  size_t off = 0;
  auto alloc = [&](size_t sz){ size_t r = off; off += (sz + 255) & ~(size_t)255; return r; };

  const size_t o_WembT = alloc((size_t)768*768*2);
  size_t o_QKVT[4], o_WoT[4], o_W1T[4], o_W2T[4];
  for (int l = 0; l < NLAYER; ++l) {
    o_QKVT[l] = alloc((size_t)2304*768*2);
    o_WoT[l]  = alloc((size_t)768*768*2);
    o_W1T[l]  = alloc((size_t)3072*768*2);
    o_W2T[l]  = alloc((size_t)768*3072*2);
  }
  const size_t o_pWkvT = alloc((size_t)1536*768*2);
  const size_t o_x     = alloc((size_t)MR*768*4);
  const size_t o_xn    = alloc((size_t)MR*768*2);
  const size_t o_kv    = alloc((size_t)MR*3072*2);   // bf16: sized for W1-out h (MRx3072); also pool kv
  const size_t o_P     = alloc((size_t)2*SLAB*4);    // split-K partial slabs (2x 12.6MB)
  const size_t o_Qb    = alloc((size_t)MR*768*2);
  const size_t o_Kb    = alloc((size_t)MR*768*2);
  const size_t o_VT    = alloc((size_t)MR*768*2);
  const size_t o_Ob    = alloc((size_t)MR*768*2);
  const size_t o_qp    = alloc((size_t)768*4);
  const size_t o_pool  = alloc((size_t)16*768*4);
  const size_t o_poolf = alloc((size_t)16*768*4);
  const size_t o_hl    = alloc((size_t)16*768*2);
  if (off > ws_size) return;  // workspace too small: fail visibly (poisoned out)

  float* x    = (float*)(ws + o_x);
  bf16*  xn   = (bf16*)(ws + o_xn);
  bf16*  hb   = (bf16*)(ws + o_kv);    // W1 output (bf16), MRx3072
  bf16*  kvb  = (bf16*)(ws + o_kv);    // pool kv (bf16), reuses same slab
  float* P    = (float*)(ws + o_P);
  bf16*  Qb   = (bf16*)(ws + o_Qb);
  bf16*  Kb   = (bf16*)(ws + o_Kb);
  bf16*  VTb  = (bf16*)(ws + o_VT);
  bf16*  Ob   = (bf16*)(ws + o_Ob);
  float* qp   = (float*)(ws + o_qp);
  float* pooled  = (float*)(ws + o_pool);
  float* pooledf = (float*)(ws + o_poolf);
  bf16*  hl   = (bf16*)(ws + o_hl);

  // ---- batched weight transpose + bf16 convert (64x64 tiles)
  TDesc td; int ne = 0, total = 0;
  auto add = [&](const float* s, size_t dofs, int R, int C){
    td.e[ne].src = s;
    td.e[ne].dst = (bf16*)(ws + dofs);
    td.e[ne].R = R; td.e[ne].C = C;
    td.e[ne].tiles = (R/64)*(C/64); td.e[ne].tC = C/64;
    total += td.e[ne].tiles; ++ne;
  };
  add(W_emb, o_WembT, 768, 768);
  for (int l = 0; l < NLAYER; ++l) {
    add(Wq  + (size_t)l*768*768,  o_QKVT[l],                 768, 768);
    add(Wkv + (size_t)l*768*1536, o_QKVT[l] + (size_t)768*768*2, 768, 1536);
    add(Wo  + (size_t)l*768*768,  o_WoT[l],                  768, 768);
    add(W1  + (size_t)l*768*3072, o_W1T[l],                  768, 3072);
    add(W2  + (size_t)l*3072*768, o_W2T[l],                  3072, 768);
  }
  add(pWkv, o_pWkvT, 768, 1536);
  transpose_kernel<<<total, 256, 0, stream>>>(td, ne);

  // ---- embed: LN -> split-K GEMM -> fused reduce+bias+LN+pos+attnLN0
  ln768_kernel<<<MR, 256, 0, stream>>>(patches, emb_ln_g, xn);
  gemm_mfma<0,0,0,0,64,2,0><<<dim3(12,32,2), 256, 0, stream>>>(xn, (const bf16*)(ws+o_WembT), nullptr,
      P, nullptr, nullptr, nullptr, nullptr, nullptr, nullptr, MR, 768, 768);
  ln_pos2_kernel<<<MR, 256, 0, stream>>>(P, b_emb, emb_ln2_g, pos_h, pos_w, ppos, x, ln_attn_g, xn);

  // ---- transformer layers (xn holds LN(x) with this layer's attn gamma at loop entry)
  for (int l = 0; l < NLAYER; ++l) {
    // qkv GEMM (128x128 tile) with fused in-wave qk-RMSnorm + V-transpose epilogue
    gemm_mfma<0,0,0,0,128,1,1><<<dim3(18,32), 256, 0, stream>>>(xn, (const bf16*)(ws+o_QKVT[l]), nullptr,
        nullptr, nullptr, qn_g + (size_t)l*768, kn_g + (size_t)l*768, Qb, Kb, VTb, MR, 2304, 768);
    attn_mfma<<<dim3(16,NH,NB), 256, 0, stream>>>(Qb, Kb, VTb, Ob, image_ids, lengths);
    // Wo: split-K -> partials; fused reduce+residual+LN(ff gamma)
    gemm_mfma<0,0,0,0,64,2,0><<<dim3(12,32,2), 256, 0, stream>>>(Ob, (const bf16*)(ws+o_WoT[l]), nullptr,
        P, nullptr, nullptr, nullptr, nullptr, nullptr, nullptr, MR, 768, 768);
    res2_ln_kernel<0><<<MR, 256, 0, stream>>>(x, P, nullptr, ln_ff_g + (size_t)l*768, xn);
    gemm_mfma<1,1,1,0,128,1,0><<<dim3(24,32), 256, 0, stream>>>(xn, (const bf16*)(ws+o_W1T[l]), b1 + (size_t)l*3072,
        nullptr, hb, nullptr, nullptr, nullptr, nullptr, nullptr, MR, 3072, 768);
    // W2: split-K -> partials; fused reduce+bias+residual+LN(next gamma)
    gemm_mfma<0,0,0,0,64,2,0><<<dim3(12,32,2), 256, 0, stream>>>(hb, (const bf16*)(ws+o_W2T[l]), nullptr,
        P, nullptr, nullptr, nullptr, nullptr, nullptr, nullptr, MR, 768, 3072);
    const float* gnext = (l + 1 < NLAYER) ? (ln_attn_g + (size_t)(l+1)*768) : final_ln_g;
    res2_ln_kernel<1><<<MR, 256, 0, stream>>>(x, P, b2v + (size_t)l*768, gnext, xn);
  }

  // ---- pooling + head (xn = LN(x, final_ln_g) from the last res2_ln)
  gemm_mfma<0,0,1,0,64,1,0><<<dim3(24,32), 256, 0, stream>>>(xn, (const bf16*)(ws+o_pWkvT), nullptr,
      nullptr, kvb, nullptr, nullptr, nullptr, nullptr, nullptr, MR, 1536, 768);
  pool_q_kernel<<<NH, 256, 0, stream>>>(pool_q, pool_ln_g, pWq, p_qn_g, qp);
  pool_attn_kernel<<<dim3(NH,NIMG,NB), 256, 0, stream>>>(kvb, qp, p_kn_g, image_ids, lengths, pooled);
  // pooled_final = pooled @ pWo + pool_q (k-parallel small-M GEMM)
  smallm_gemm<0,1><<<12, 256, 0, stream>>>(pooled, pWo, pool_q, pooledf, 768);
  ln768_kernel<<<16, 256, 0, stream>>>(pooledf, head_ln_g, hl);
  // out = LN(pooledf) @ W_head
  smallm_gemm<1,0><<<16, 256, 0, stream>>>(hl, W_head, nullptr, (float*)d_out, NCLS);
}

// Round 7
// 1084.119 us; speedup vs baseline: 1.0340x; 1.0194x over previous
//
#include <hip/hip_runtime.h>
#include <hip/hip_bf16.h>
#include <math.h>

using bf16 = __hip_bfloat16;
typedef short s16x8 __attribute__((ext_vector_type(8)));
typedef short s16x4 __attribute__((ext_vector_type(4)));
typedef float f32x4 __attribute__((ext_vector_type(4)));

#define DEVI __device__ __forceinline__

static constexpr int NB    = 4;
static constexpr int NTOK  = 1024;
static constexpr int DIM   = 768;
static constexpr int NH    = 12;
static constexpr int MLPD  = 3072;
static constexpr int NLAYER= 4;
static constexpr int NIMG  = 4;
static constexpr int NCLS  = 1000;
static constexpr int MR    = NB * NTOK;   // 4096 rows
static constexpr size_t SLAB = (size_t)MR * 768;  // split-K partial slab (f32 elems)

DEVI float b2f(bf16 v){ return __bfloat162float(v); }
DEVI bf16  f2b(float v){ return __float2bfloat16(v); }
DEVI float bu2f(unsigned short u){ union{unsigned u32; float f;} w; w.u32 = ((unsigned)u)<<16; return w.f; }
DEVI unsigned short f2bu(float f){ bf16 b = f2b(f); return *(unsigned short*)&b; }

DEVI void async16(const void* g, void* l) {
  __builtin_amdgcn_global_load_lds((const __attribute__((address_space(1))) void*)g,
                                   (__attribute__((address_space(3))) void*)l, 16, 0, 0);
}

DEVI f32x4 mfma16(s16x8 a, s16x8 b, f32x4 c) {
  return __builtin_amdgcn_mfma_f32_16x16x32_bf16(a, b, c, 0, 0, 0);
}

template<int N> DEVI void waitcnt_vm() {
  if constexpr (N == 0)      asm volatile("s_waitcnt vmcnt(0)" ::: "memory");
  else if constexpr (N == 3) asm volatile("s_waitcnt vmcnt(3)" ::: "memory");
  else if constexpr (N == 4) asm volatile("s_waitcnt vmcnt(4)" ::: "memory");
  else if constexpr (N == 6) asm volatile("s_waitcnt vmcnt(6)" ::: "memory");
}

DEVI float block_sum(float v, float* scratch, int tid) {
  #pragma unroll
  for (int o = 32; o >= 1; o >>= 1) v += __shfl_xor(v, o);
  __syncthreads();
  if ((tid & 63) == 0) scratch[tid >> 6] = v;
  __syncthreads();
  return scratch[0] + scratch[1] + scratch[2] + scratch[3];
}

DEVI float block_max(float v, float* scratch, int tid) {
  #pragma unroll
  for (int o = 32; o >= 1; o >>= 1) v = fmaxf(v, __shfl_xor(v, o));
  __syncthreads();
  if ((tid & 63) == 0) scratch[tid >> 6] = v;
  __syncthreads();
  return fmaxf(fmaxf(scratch[0], scratch[1]), fmaxf(scratch[2], scratch[3]));
}

// ---------------------------------------------------------------- transpose + f32->bf16 convert
// 2x 64x64 tiles per block, deep-pipelined: all 8 global loads issued up-front (compiler
// gates uses with vmcnt(4)/vmcnt(0)), double-buffered LDS; tile0 stores overlap tile1 loads.
// Pitch 70 u16 keeps the phase-2 gather ~conflict-free.
struct TEntry { const float* src; bf16* dst; int R, C, tiles, tC; };
struct TDesc  { TEntry e[22]; };

__global__ __launch_bounds__(256) void transpose_kernel(TDesc D, int nent) {
  int tix = blockIdx.x * 2, ei = 0;            // tile index (entries all have even tile counts)
  while (ei < nent - 1 && tix >= D.e[ei].tiles) { tix -= D.e[ei].tiles; ++ei; }
  const TEntry E = D.e[ei];
  __shared__ unsigned short t[2][64][70];      // 2 x 8.75 KB
  const int tid = threadIdx.x;
  const int r = tid >> 4, c = (tid & 15) * 4;
  float4 v[2][4];
  #pragma unroll
  for (int q = 0; q < 2; ++q) {
    const int tr = (tix + q) / E.tC, tc = (tix + q) % E.tC;
    #pragma unroll
    for (int p = 0; p < 4; ++p)
      v[q][p] = *(const float4*)(E.src + (size_t)(tr*64 + p*16 + r)*E.C + tc*64 + c);
  }
  #pragma unroll
  for (int q = 0; q < 2; ++q) {
    #pragma unroll
    for (int p = 0; p < 4; ++p) {
      unsigned short* dst = &t[q][p*16 + r][c];
      dst[0] = f2bu(v[q][p].x); dst[1] = f2bu(v[q][p].y);
      dst[2] = f2bu(v[q][p].z); dst[3] = f2bu(v[q][p].w);
    }
    __syncthreads();
    const int tr = (tix + q) / E.tC, tc = (tix + q) % E.tC;
    #pragma unroll
    for (int p = 0; p < 2; ++p) {
      const int n = p*32 + (tid >> 3);
      const int r0 = (tid & 7) * 8;
      s16x8 o;
      #pragma unroll
      for (int i = 0; i < 8; ++i) o[i] = (short)t[q][r0 + i][n];
      *(s16x8*)((short*)E.dst + (size_t)(tc*64 + n)*E.R + tr*64 + r0) = o;
    }
  }
}

// ---------------------------------------------------------------- LayerNorm (768 cols), f32 in, bf16 out
__global__ __launch_bounds__(256) void ln768_kernel(const float* __restrict__ in,
    const float* __restrict__ g, bf16* __restrict__ out)
{
  __shared__ float scratch[4];
  const int row = blockIdx.x, tid = threadIdx.x;
  const float* p = in + (size_t)row*768;
  const float v0 = p[tid], v1 = p[tid+256], v2 = p[tid+512];
  const float s  = block_sum(v0+v1+v2, scratch, tid);
  const float ss = block_sum(v0*v0+v1*v1+v2*v2, scratch, tid);
  const float mu = s * (1.0f/768.0f);
  const float var = ss * (1.0f/768.0f) - mu*mu;
  const float rstd = rsqrtf(var + 1e-5f);
  bf16* o = out + (size_t)row*768;
  o[tid]     = f2b((v0-mu)*rstd*g[tid]);
  o[tid+256] = f2b((v1-mu)*rstd*g[tid+256]);
  o[tid+512] = f2b((v2-mu)*rstd*g[tid+512]);
}

// Fused split-K reduce + residual + LayerNorm:
// x += P0 + P1 (+bias); xn = LN(x)*g (bf16). x updated in place.
template<int HAS_BIAS>
__global__ __launch_bounds__(256) void res2_ln_kernel(float* __restrict__ x,
    const float* __restrict__ P, const float* __restrict__ bias,
    const float* __restrict__ g, bf16* __restrict__ xn)
{
  __shared__ float scratch[4];
  const int row = blockIdx.x, tid = threadIdx.x;
  const size_t base = (size_t)row*768;
  const float* p0 = P + base;
  const float* p1 = P + SLAB + base;
  float* xr = x + base;
  float v[3];
  #pragma unroll
  for (int i = 0; i < 3; ++i) {
    const int c = tid + i*256;
    float t = xr[c] + p0[c] + p1[c];
    if constexpr (HAS_BIAS) t += bias[c];
    v[i] = t;
    xr[c] = t;
  }
  const float s  = block_sum(v[0]+v[1]+v[2], scratch, tid);
  const float ss = block_sum(v[0]*v[0]+v[1]*v[1]+v[2]*v[2], scratch, tid);
  const float mu = s * (1.0f/768.0f);
  const float rstd = rsqrtf(ss*(1.0f/768.0f) - mu*mu + 1e-5f);
  bf16* o = xn + base;
  #pragma unroll
  for (int i = 0; i < 3; ++i) {
    const int c = tid + i*256;
    o[c] = f2b((v[i]-mu)*rstd*g[c]);
  }
}

// Fused embed: v = P0+P1+b_emb; x = LN(v)*g + pos_h + pos_w; xn = LN(x)*g2 (layer-0 attn LN)
__global__ __launch_bounds__(256) void ln_pos2_kernel(const float* __restrict__ P,
    const float* __restrict__ bias, const float* __restrict__ g,
    const float* __restrict__ pos_h, const float* __restrict__ pos_w,
    const int* __restrict__ ppos, float* __restrict__ out,
    const float* __restrict__ g2, bf16* __restrict__ xn)
{
  __shared__ float scratch[4];
  const int row = blockIdx.x, tid = threadIdx.x;
  const size_t base = (size_t)row*768;
  const float* p0 = P + base;
  const float* p1 = P + SLAB + base;
  float v[3];
  #pragma unroll
  for (int i = 0; i < 3; ++i) {
    const int c = tid + i*256;
    v[i] = p0[c] + p1[c] + bias[c];
  }
  const float s  = block_sum(v[0]+v[1]+v[2], scratch, tid);
  const float ss = block_sum(v[0]*v[0]+v[1]*v[1]+v[2]*v[2], scratch, tid);
  const float mu = s * (1.0f/768.0f);
  const float rstd = rsqrtf(ss*(1.0f/768.0f) - mu*mu + 1e-5f);
  const int p0i = ppos[row*2], p1i = ppos[row*2+1];
  const float* ph = pos_h + (size_t)p0i*768;
  const float* pw = pos_w + (size_t)p1i*768;
  float* o = out + base;
  float xv[3];
  #pragma unroll
  for (int i = 0; i < 3; ++i) {
    const int c = tid + i*256;
    xv[i] = (v[i]-mu)*rstd*g[c] + ph[c] + pw[c];
    o[c] = xv[i];
  }
  // second LN (layer-0 attention LN) on the register-resident row
  const float s2  = block_sum(xv[0]+xv[1]+xv[2], scratch, tid);
  const float ss2 = block_sum(xv[0]*xv[0]+xv[1]*xv[1]+xv[2]*xv[2], scratch, tid);
  const float mu2 = s2 * (1.0f/768.0f);
  const float rstd2 = rsqrtf(ss2*(1.0f/768.0f) - mu2*mu2 + 1e-5f);
  bf16* on = xn + base;
  #pragma unroll
  for (int i = 0; i < 3; ++i) {
    const int c = tid + i*256;
    on[c] = f2b((xv[i]-mu2)*rstd2*g2[c]);
  }
}

// ---------------------------------------------------------------- GEMM (MFMA, XOR-swizzled LDS)
// PD-deep global_load_lds pipeline, counted vmcnt (T3/T4), XCD-bijective swizzle (T1).
// SPLITK>1: blockIdx.z selects a K-chunk; partials to slab z, reduced in res2_ln/ln_pos2.
// RMSQKV (NTILE=64): this n-tile is exactly one head slice; epilogue applies qk-RMSnorm
// (cross-wave LDS reduce) and writes Qb/Kb, or transposes V into VT.
template<int DO_BIAS, int DO_GELU, int OUT_BF16, int DO_RES, int NTILE, int SPLITK, int RMSQKV>
__global__ __launch_bounds__(256)
void gemm_mfma(const bf16* __restrict__ A, const bf16* __restrict__ BT,
               const float* __restrict__ bias, float* __restrict__ Cf,
               bf16* __restrict__ Cb,
               const float* __restrict__ qg, const float* __restrict__ kg,
               bf16* __restrict__ Qp, bf16* __restrict__ Kp, bf16* __restrict__ Vp,
               int M, int Nn, int K)
{
  constexpr int NF  = NTILE / 32;           // n-frags per wave (2 or 4)
  constexpr int PD  = 3;                    // pipeline depth (LDS buffers)
  constexpr int LPI = 2 + NTILE/64;         // loads per thread per iter
  constexpr int VW  = (PD - 2) * LPI;       // steady-state vmcnt
  __shared__ bf16 As[PD][64*64];            // PD x 8 KB
  __shared__ bf16 Bs[PD][(NTILE/2)*64];     // PD x (4 or 8) KB
  const int tid = threadIdx.x;
  const int wid = tid >> 6, lane = tid & 63;
  const int quad = lane >> 4, l15 = lane & 15;
  const int wy = wid >> 1, wx = wid & 1;

  // XCD-aware bijective swizzle (m204 form), per K-chunk plane.
  const int gx  = gridDim.x;
  const int nwg = gx * gridDim.y;
  const int bid = blockIdx.y * gx + blockIdx.x;
  const int qq  = nwg >> 3, rm = nwg & 7;
  const int xcd = bid & 7,  li = bid >> 3;
  const int swz = (xcd < rm ? xcd * (qq + 1) : rm * (qq + 1) + (xcd - rm) * qq) + li;
  const int m0 = (swz / gx) * 128, n0 = (swz % gx) * NTILE;

  const int kz    = (SPLITK > 1) ? blockIdx.z : 0;
  const int kloc  = K / SPLITK;             // K per chunk
  const int kbase = kz * kloc;

  const int rl = lane >> 3;                 // local LDS row 0..7
  const int cs = lane & 7;                  // slot 0..7

  f32x4 acc[4][NF];
  #pragma unroll
  for (int i = 0; i < 4; ++i)
    #pragma unroll
    for (int j = 0; j < NF; ++j) acc[i][j] = (f32x4){0.f,0.f,0.f,0.f};

  auto stage = [&](int buf, int k0) {
    #pragma unroll
    for (int c = 0; c < 2; ++c) {
      const int rbase = wid*8 + c*32;
      const int r_abs = rbase + rl;
      const int ceff  = cs ^ (r_abs & 7);
      const int mg    = 2*r_abs + (ceff >> 2);
      const int jb    = (ceff & 3) * 16;
      async16((const char*)A + ((size_t)(m0 + mg)*K + k0)*2 + jb, (char*)As[buf] + rbase*128);
    }
    #pragma unroll
    for (int c = 0; c < NTILE/64; ++c) {
      const int rbase = wid*8 + c*32;
      const int r_abs = rbase + rl;
      const int ceff  = cs ^ (r_abs & 7);
      const int ng    = 2*r_abs + (ceff >> 2);
      const int jb    = (ceff & 3) * 16;
      async16((const char*)BT + ((size_t)(n0 + ng)*K + k0)*2 + jb, (char*)Bs[buf] + rbase*128);
    }
  };

  auto compute = [&](int cb) {
    s16x8 af[4], bfr[NF];
    #pragma unroll
    for (int mt = 0; mt < 4; ++mt) {
      const int m = wy*64 + mt*16 + l15;
      const int r = m >> 1;
      const int cq = (((m & 1) << 2) | quad) ^ (r & 7);
      af[mt] = *(const s16x8*)((const char*)As[cb] + r*128 + cq*16);
    }
    #pragma unroll
    for (int nt = 0; nt < NF; ++nt) {
      const int n = wx*(NTILE/2) + nt*16 + l15;
      const int r = n >> 1;
      const int cq = (((n & 1) << 2) | quad) ^ (r & 7);
      bfr[nt] = *(const s16x8*)((const char*)Bs[cb] + r*128 + cq*16);
    }
    #pragma unroll
    for (int mt = 0; mt < 4; ++mt)
      #pragma unroll
      for (int nt = 0; nt < NF; ++nt)
        acc[mt][nt] = mfma16(af[mt], bfr[nt], acc[mt][nt]);
  };

  const int nk = kloc >> 5;
  #pragma unroll
  for (int t = 0; t < PD - 1; ++t) stage(t, kbase + (t << 5));

  int cbuf = 0, sbuf = PD - 1;
  const int mainN = nk - (PD - 1);
  for (int kt = 0; kt < mainN; ++kt) {
    __builtin_amdgcn_sched_barrier(0);
    waitcnt_vm<VW>();                       // tile kt complete; later tiles stay in flight
    __builtin_amdgcn_s_barrier();
    __builtin_amdgcn_sched_barrier(0);
    stage(sbuf, kbase + ((kt + PD - 1) << 5));
    compute(cbuf);
    cbuf = (cbuf + 1 == PD) ? 0 : cbuf + 1;
    sbuf = (sbuf + 1 == PD) ? 0 : sbuf + 1;
  }
  for (int kt = mainN; kt < nk; ++kt) {     // tail: drain
    __builtin_amdgcn_sched_barrier(0);
    waitcnt_vm<0>();
    __builtin_amdgcn_s_barrier();
    __builtin_amdgcn_sched_barrier(0);
    compute(cbuf);
    cbuf = (cbuf + 1 == PD) ? 0 : cbuf + 1;
  }

  if constexpr (RMSQKV) {
    // NTILE==64: this n-tile is exactly one head slice. Rows of acc are tokens.
    __shared__ float red[128][2];
    const int hg = n0 >> 6;                 // 0..35
    const int region = hg / NH;             // 0:Q 1:K 2:V
    const int h  = hg - region*NH;
    const int b  = m0 >> 10;
    const int bh = b*NH + h;
    const int tokb = m0 & (NTOK-1);
    if (region < 2) {
      float sl[4][4];
      #pragma unroll
      for (int mt = 0; mt < 4; ++mt)
        #pragma unroll
        for (int rr = 0; rr < 4; ++rr) {
          float ssq = 0.f;
          #pragma unroll
          for (int nt = 0; nt < NF; ++nt) ssq += acc[mt][nt][rr]*acc[mt][nt][rr];
          #pragma unroll
          for (int o = 1; o <= 8; o <<= 1) ssq += __shfl_xor(ssq, o);
          sl[mt][rr] = ssq;
        }
      if (l15 == 0) {
        #pragma unroll
        for (int mt = 0; mt < 4; ++mt)
          #pragma unroll
          for (int rr = 0; rr < 4; ++rr)
            red[wy*64 + mt*16 + quad*4 + rr][wx] = sl[mt][rr];
      }
      __syncthreads();
      const float* gp = (region == 0) ? (qg + n0) : (kg + (n0 - 768));
      bf16* outb = (region == 0) ? Qp : Kp;
      #pragma unroll
      for (int mt = 0; mt < 4; ++mt)
        #pragma unroll
        for (int rr = 0; rr < 4; ++rr) {
          const int rlc = wy*64 + mt*16 + quad*4 + rr;
          const float rn = 8.0f / fmaxf(sqrtf(red[rlc][0] + red[rlc][1]), 1e-12f);
          const int tok = tokb + rlc;
          #pragma unroll
          for (int nt = 0; nt < NF; ++nt) {
            const int d = wx*32 + nt*16 + l15;
            outb[((size_t)bh*NTOK + tok)*64 + d] = f2b(acc[mt][nt][rr]*rn*gp[d]);
          }
        }
    } else {
      // V: write transposed VT[bh*64+d][tok], 4 consecutive tokens per 8B store
      #pragma unroll
      for (int mt = 0; mt < 4; ++mt)
        #pragma unroll
        for (int nt = 0; nt < NF; ++nt) {
          const int d = wx*32 + nt*16 + l15;
          const int tok = tokb + wy*64 + mt*16 + quad*4;
          s16x4 pk;
          #pragma unroll
          for (int rr = 0; rr < 4; ++rr) pk[rr] = (short)f2bu(acc[mt][nt][rr]);
          *(s16x4*)((short*)Vp + ((size_t)bh*64 + d)*NTOK + tok) = pk;
        }
    }
  } else {
    float* Cslab = (SPLITK > 1) ? (Cf + (size_t)kz * SLAB) : Cf;
    #pragma unroll
    for (int nt = 0; nt < NF; ++nt) {
      const int col = n0 + wx*(NTILE/2) + nt*16 + l15;
      float bv = 0.f;
      if constexpr (DO_BIAS) bv = bias[col];
      #pragma unroll
      for (int mt = 0; mt < 4; ++mt) {
        #pragma unroll
        for (int r = 0; r < 4; ++r) {
          const int row = m0 + wy*64 + mt*16 + quad*4 + r;
          float v = acc[mt][nt][r];
          if constexpr (DO_BIAS) v += bv;
          if constexpr (DO_GELU) v = 0.5f*v*(1.0f + erff(v*0.70710678118654752f));
          const size_t idx = (size_t)row*Nn + col;
          if constexpr (OUT_BF16) Cb[idx] = f2b(v);
          else if constexpr (DO_RES) Cslab[idx] += v;
          else Cslab[idx] = v;
        }
      }
    }
  }
}

// ---------------------------------------------------------------- small-M GEMM (M=16, K=768)
template<int IN_BF16, int DO_BIAS>
__global__ __launch_bounds__(256) void smallm_gemm(const void* __restrict__ Xv,
    const float* __restrict__ W, const float* __restrict__ bias,
    float* __restrict__ out, int Nn)
{
  __shared__ float Xs[16*768];
  __shared__ float red[4][16][64];
  const int tid = threadIdx.x;
  if constexpr (IN_BF16) {
    const bf16* X = (const bf16*)Xv;
    for (int i = tid; i < 16*768; i += 256) Xs[i] = b2f(X[i]);
  } else {
    const float* X = (const float*)Xv;
    for (int i = tid; i < 16*768; i += 256) Xs[i] = X[i];
  }
  __syncthreads();
  const int cl = tid & 63, kg = tid >> 6;
  const int c = blockIdx.x*64 + cl;
  float acc[16];
  #pragma unroll
  for (int r = 0; r < 16; ++r) acc[r] = 0.f;
  if (c < Nn) {
    const int k0 = kg*192;
    #pragma unroll 4
    for (int k = k0; k < k0 + 192; ++k) {
      const float w = W[(size_t)k*Nn + c];
      #pragma unroll
      for (int r = 0; r < 16; ++r) acc[r] += Xs[r*768 + k] * w;
    }
  }
  #pragma unroll
  for (int r = 0; r < 16; ++r) red[kg][r][cl] = acc[r];
  __syncthreads();
  if (kg == 0 && c < Nn) {
    #pragma unroll
    for (int r = 0; r < 16; ++r) {
      float v = red[0][r][cl] + red[1][r][cl] + red[2][r][cl] + red[3][r][cl];
      if constexpr (DO_BIAS) v += bias[c];
      out[(size_t)r*Nn + c] = v;
    }
  }
}

// ---------------------------------------------------------------- fused MFMA attention
__global__ __launch_bounds__(256) void attn_mfma(const bf16* __restrict__ Qb,
    const bf16* __restrict__ Kb, const bf16* __restrict__ VTb, bf16* __restrict__ Ob,
    const int* __restrict__ ids, const int* __restrict__ lens)
{
  __shared__ bf16 Ps[4][16*72];   // per-wave P tile [m=16][j=64], row stride 72 elems
  __shared__ int  ids_s[NTOK];
  const int qt = blockIdx.x, h = blockIdx.y, b = blockIdx.z;
  const int tid = threadIdx.x;
  const int wid = tid >> 6, lane = tid & 63;
  const int quad = lane >> 4, l15 = lane & 15;
  const int bh = b*NH + h;
  const int q0 = qt*64;
  const int len = lens[b];

  #pragma unroll
  for (int i = 0; i < 4; ++i) ids_s[i*256 + tid] = ids[b*NTOK + i*256 + tid];
  __syncthreads();

  const bf16* qrow = Qb + ((size_t)bh*NTOK + q0 + wid*16 + l15)*64;
  const s16x8 aq0 = *(const s16x8*)(qrow + quad*8);
  const s16x8 aq1 = *(const s16x8*)(qrow + 32 + quad*8);

  int idq[4];
  #pragma unroll
  for (int rr = 0; rr < 4; ++rr) idq[rr] = ids_s[q0 + wid*16 + quad*4 + rr];

  unsigned qm = 0;
  #pragma unroll
  for (int rr = 0; rr < 4; ++rr) qm |= 1u << (idq[rr] & 31);
  #pragma unroll
  for (int o = 32; o >= 1; o >>= 1) qm |= (unsigned)__shfl_xor((int)qm, o);

  f32x4 oacc[4];
  #pragma unroll
  for (int nt = 0; nt < 4; ++nt) oacc[nt] = (f32x4){0.f,0.f,0.f,0.f};
  float mrow[4] = {-3.0e38f,-3.0e38f,-3.0e38f,-3.0e38f};
  float lrow[4] = {0.f,0.f,0.f,0.f};

  const bf16* Kgb = Kb  + (size_t)bh*NTOK*64;
  const bf16* Vgb = VTb + (size_t)bh*64*NTOK;
  bf16* pw = Ps[wid];

  for (int kt = 0; kt < 16; ++kt) {
    const int k0 = kt*64;
    const int idk_l = ids_s[k0 + lane];
    const bool ok = ((k0 + lane) < len) && (((qm >> (idk_l & 31)) & 1u) != 0u);
    if (__ballot(ok) == 0ULL) continue;

    f32x4 sA[4];
    #pragma unroll
    for (int jt = 0; jt < 4; ++jt) {
      const bf16* krow = Kgb + (size_t)(k0 + jt*16 + l15)*64;
      const s16x8 bk0 = *(const s16x8*)(krow + quad*8);
      const s16x8 bk1 = *(const s16x8*)(krow + 32 + quad*8);
      f32x4 s = (f32x4){0.f,0.f,0.f,0.f};
      s = mfma16(aq0, bk0, s);
      s = mfma16(aq1, bk1, s);
      sA[jt] = s;
    }
    #pragma unroll
    for (int jt = 0; jt < 4; ++jt) {
      const int j = k0 + jt*16 + l15;
      const int idk = ids_s[j];
      const bool kvld = j < len;
      #pragma unroll
      for (int rr = 0; rr < 4; ++rr)
        sA[jt][rr] = (kvld && idk == idq[rr]) ? sA[jt][rr] : -3.0e38f;
    }
    float alpha[4], mnew[4];
    #pragma unroll
    for (int rr = 0; rr < 4; ++rr) {
      float mx = fmaxf(fmaxf(sA[0][rr], sA[1][rr]), fmaxf(sA[2][rr], sA[3][rr]));
      mx = fmaxf(mx, __shfl_xor(mx, 1));
      mx = fmaxf(mx, __shfl_xor(mx, 2));
      mx = fmaxf(mx, __shfl_xor(mx, 4));
      mx = fmaxf(mx, __shfl_xor(mx, 8));
      const float mn = fmaxf(mrow[rr], mx);
      mnew[rr] = mn;
      alpha[rr] = expf(mrow[rr] - mn);
      mrow[rr] = mn;
    }
    #pragma unroll
    for (int rr = 0; rr < 4; ++rr) {
      float rs = 0.f;
      #pragma unroll
      for (int jt = 0; jt < 4; ++jt) {
        const float pv = (sA[jt][rr] > -1.0e38f) ? expf(sA[jt][rr] - mnew[rr]) : 0.0f;
        sA[jt][rr] = pv;
        rs += pv;
      }
      rs += __shfl_xor(rs, 1);
      rs += __shfl_xor(rs, 2);
      rs += __shfl_xor(rs, 4);
      rs += __shfl_xor(rs, 8);
      lrow[rr] = lrow[rr]*alpha[rr] + rs;
      #pragma unroll
      for (int nt = 0; nt < 4; ++nt) oacc[nt][rr] *= alpha[rr];
    }
    #pragma unroll
    for (int jt = 0; jt < 4; ++jt)
      #pragma unroll
      for (int rr = 0; rr < 4; ++rr)
        pw[(quad*4+rr)*72 + jt*16 + l15] = f2b(sA[jt][rr]);
    #pragma unroll
    for (int ss = 0; ss < 2; ++ss) {
      const s16x8 ap = *(const s16x8*)(pw + l15*72 + ss*32 + quad*8);
      #pragma unroll
      for (int nt = 0; nt < 4; ++nt) {
        const s16x8 bv = *(const s16x8*)(Vgb + (size_t)(nt*16 + l15)*NTOK + k0 + ss*32 + quad*8);
        oacc[nt] = mfma16(ap, bv, oacc[nt]);
      }
    }
  }

  #pragma unroll
  for (int rr = 0; rr < 4; ++rr) {
    const float inv = lrow[rr] > 0.f ? 1.0f/lrow[rr] : 0.0f;
    const int n = q0 + wid*16 + quad*4 + rr;
    bf16* orow = Ob + ((size_t)b*NTOK + n)*768 + h*64;
    #pragma unroll
    for (int nt = 0; nt < 4; ++nt)
      orow[nt*16 + l15] = f2b(oacc[nt][rr]*inv);
  }
}

// ---------------------------------------------------------------- pooling path
__global__ __launch_bounds__(256) void pool_q_kernel(const float* __restrict__ pool_q,
    const float* __restrict__ pool_ln_g, const float* __restrict__ pWq,
    const float* __restrict__ p_qn_g, float* __restrict__ qp)
{
  __shared__ float xn[768];
  __shared__ float scratch[4];
  __shared__ float qraw[64];
  const int h = blockIdx.x, tid = threadIdx.x;
  float v0 = pool_q[tid], v1 = pool_q[tid+256], v2 = pool_q[tid+512];
  const float s  = block_sum(v0+v1+v2, scratch, tid);
  const float ss = block_sum(v0*v0+v1*v1+v2*v2, scratch, tid);
  const float mu = s*(1.0f/768.0f);
  const float rstd = rsqrtf(ss*(1.0f/768.0f) - mu*mu + 1e-5f);
  xn[tid]     = (v0-mu)*rstd*pool_ln_g[tid];
  xn[tid+256] = (v1-mu)*rstd*pool_ln_g[tid+256];
  xn[tid+512] = (v2-mu)*rstd*pool_ln_g[tid+512];
  __syncthreads();
  const int d = tid >> 2, pp = tid & 3;
  const int col = h*64 + d;
  float acc = 0.f;
  for (int k = pp*192; k < (pp+1)*192; ++k) acc += xn[k]*pWq[(size_t)k*768 + col];
  acc += __shfl_xor(acc, 1); acc += __shfl_xor(acc, 2);
  if (pp == 0) qraw[d] = acc;
  __syncthreads();
  if (tid < 64) {
    const float q = qraw[tid];
    float sq = q*q;
    #pragma unroll
    for (int o = 32; o >= 1; o >>= 1) sq += __shfl_xor(sq, o);
    const float rn = 8.0f / fmaxf(sqrtf(sq), 1e-12f);
    qp[h*64 + tid] = q * rn * p_qn_g[h*64 + tid];
  }
}

__global__ __launch_bounds__(256) void pool_attn_kernel(const bf16* __restrict__ kvp,
    const float* __restrict__ qp, const float* __restrict__ kg,
    const int* __restrict__ ids, const int* __restrict__ lens, float* __restrict__ pooled)
{
  __shared__ float sp[1024];
  __shared__ float qg_s[64];
  __shared__ float scratch[4];
  __shared__ float outred[4][64];
  const int h = blockIdx.x, img = blockIdx.y, b = blockIdx.z;
  const int tid = threadIdx.x;
  const int len = lens[b];
  if (tid < 64) qg_s[tid] = qp[h*64 + tid] * kg[h*64 + tid];
  __syncthreads();

  float smax = -3.0e38f;
  for (int j = tid; j < 1024; j += 256) {
    float sv = -3.0e38f;
    if (j < len && ids[b*NTOK + j] == img) {
      const bf16* kr = kvp + (size_t)(b*NTOK + j)*1536 + h*64;
      float ssq = 0.f, dq = 0.f;
      #pragma unroll
      for (int dd = 0; dd < 64; dd += 8) {
        s16x8 k8 = *(const s16x8*)(kr + dd);
        #pragma unroll
        for (int i = 0; i < 8; ++i) {
          const float kv = bu2f((unsigned short)k8[i]);
          ssq += kv*kv;
          dq  += qg_s[dd+i]*kv;
        }
      }
      const float rn = 8.0f / fmaxf(sqrtf(ssq), 1e-12f);
      sv = dq * rn;
    }
    sp[j] = sv;
    smax = fmaxf(smax, sv);
  }
  const float M = block_max(smax, scratch, tid);
  float lsum = 0.f;
  for (int j = tid; j < 1024; j += 256) {
    const float p = (sp[j] > -1.0e38f) ? expf(sp[j] - M) : 0.0f;
    sp[j] = p;
    lsum += p;
  }
  const float L = block_sum(lsum, scratch, tid);
  const float invL = L > 0.f ? 1.0f / L : 0.0f;

  const int d = tid & 63, jg = tid >> 6;
  float acc = 0.f;
  for (int j = jg; j < 1024; j += 4) {
    const float p = sp[j];
    if (p > 0.f) acc += p * b2f(kvp[(size_t)(b*NTOK + j)*1536 + 768 + h*64 + d]);
  }
  outred[jg][d] = acc;
  __syncthreads();
  if (tid < 64) {
    const float o = (outred[0][tid] + outred[1][tid] + outred[2][tid] + outred[3][tid]) * invL;
    pooled[((size_t)b*NIMG + img)*768 + h*64 + tid] = o;
  }
}

// ---------------------------------------------------------------- host
extern "C" void kernel_launch(void* const* d_in, const int* in_sizes, int n_in,
                              void* d_out, int out_size, void* d_ws, size_t ws_size,
                              hipStream_t stream)
{
  const float* patches    = (const float*)d_in[0];
  const int*   ppos       = (const int*)d_in[1];
  const int*   image_ids  = (const int*)d_in[2];
  const int*   lengths    = (const int*)d_in[3];
  const float* emb_ln_g   = (const float*)d_in[4];
  const float* W_emb      = (const float*)d_in[5];
  const float* b_emb      = (const float*)d_in[6];
  const float* emb_ln2_g  = (const float*)d_in[7];
  const float* pos_h      = (const float*)d_in[8];
  const float* pos_w      = (const float*)d_in[9];
  const float* ln_attn_g  = (const float*)d_in[10];
  const float* Wq         = (const float*)d_in[11];
  const float* Wkv        = (const float*)d_in[12];
  const float* qn_g       = (const float*)d_in[13];
  const float* kn_g       = (const float*)d_in[14];
  const float* Wo         = (const float*)d_in[15];
  const float* ln_ff_g    = (const float*)d_in[16];
  const float* W1         = (const float*)d_in[17];
  const float* b1         = (const float*)d_in[18];
  const float* W2         = (const float*)d_in[19];
  const float* b2v        = (const float*)d_in[20];
  const float* final_ln_g = (const float*)d_in[21];
  const float* pool_q     = (const float*)d_in[22];
  const float* pool_ln_g  = (const float*)d_in[23];
  const float* pWq        = (const float*)d_in[24];
  const float* pWkv       = (const float*)d_in[25];
  const float* p_qn_g     = (const float*)d_in[26];
  const float* p_kn_g     = (const float*)d_in[27];
  const float* pWo        = (const float*)d_in[28];
  const float* head_ln_g  = (const float*)d_in[29];
  const float* W_head     = (const float*)d_in[30];

  char* ws = (char*)d_ws;
  size_t off = 0;
  auto alloc = [&](size_t sz){ size_t r = off; off += (sz + 255) & ~(size_t)255; return r; };

  const size_t o_WembT = alloc((size_t)768*768*2);
  size_t o_QKVT[4], o_WoT[4], o_W1T[4], o_W2T[4];
  for (int l = 0; l < NLAYER; ++l) {
    o_QKVT[l] = alloc((size_t)2304*768*2);
    o_WoT[l]  = alloc((size_t)768*768*2);
    o_W1T[l]  = alloc((size_t)3072*768*2);
    o_W2T[l]  = alloc((size_t)768*3072*2);
  }
  const size_t o_pWkvT = alloc((size_t)1536*768*2);
  const size_t o_x     = alloc((size_t)MR*768*4);
  const size_t o_xn    = alloc((size_t)MR*768*2);
  const size_t o_kv    = alloc((size_t)MR*3072*2);   // bf16: sized for W1-out h (MRx3072); also pool kv
  const size_t o_P     = alloc((size_t)2*SLAB*4);    // split-K partial slabs (2x 12.6MB)
  const size_t o_Qb    = alloc((size_t)MR*768*2);
  const size_t o_Kb    = alloc((size_t)MR*768*2);
  const size_t o_VT    = alloc((size_t)MR*768*2);
  const size_t o_Ob    = alloc((size_t)MR*768*2);
  const size_t o_qp    = alloc((size_t)768*4);
  const size_t o_pool  = alloc((size_t)16*768*4);
  const size_t o_poolf = alloc((size_t)16*768*4);
  const size_t o_hl    = alloc((size_t)16*768*2);
  if (off > ws_size) return;  // workspace too small: fail visibly (poisoned out)

  float* x    = (float*)(ws + o_x);
  bf16*  xn   = (bf16*)(ws + o_xn);
  bf16*  hb   = (bf16*)(ws + o_kv);    // W1 output (bf16), MRx3072
  bf16*  kvb  = (bf16*)(ws + o_kv);    // pool kv (bf16), reuses same slab
  float* P    = (float*)(ws + o_P);
  bf16*  Qb   = (bf16*)(ws + o_Qb);
  bf16*  Kb   = (bf16*)(ws + o_Kb);
  bf16*  VTb  = (bf16*)(ws + o_VT);
  bf16*  Ob   = (bf16*)(ws + o_Ob);
  float* qp   = (float*)(ws + o_qp);
  float* pooled  = (float*)(ws + o_pool);
  float* pooledf = (float*)(ws + o_poolf);
  bf16*  hl   = (bf16*)(ws + o_hl);

  // ---- batched weight transpose + bf16 convert (64x64 tiles, 2 per block)
  TDesc td; int ne = 0, total = 0;
  auto add = [&](const float* s, size_t dofs, int R, int C){
    td.e[ne].src = s;
    td.e[ne].dst = (bf16*)(ws + dofs);
    td.e[ne].R = R; td.e[ne].C = C;
    td.e[ne].tiles = (R/64)*(C/64); td.e[ne].tC = C/64;
    total += td.e[ne].tiles; ++ne;
  };
  add(W_emb, o_WembT, 768, 768);
  for (int l = 0; l < NLAYER; ++l) {
    add(Wq  + (size_t)l*768*768,  o_QKVT[l],                 768, 768);
    add(Wkv + (size_t)l*768*1536, o_QKVT[l] + (size_t)768*768*2, 768, 1536);
    add(Wo  + (size_t)l*768*768,  o_WoT[l],                  768, 768);
    add(W1  + (size_t)l*768*3072, o_W1T[l],                  768, 3072);
    add(W2  + (size_t)l*3072*768, o_W2T[l],                  3072, 768);
  }
  add(pWkv, o_pWkvT, 768, 1536);
  transpose_kernel<<<total/2, 256, 0, stream>>>(td, ne);   // all entries have even tile counts

  // ---- embed: LN -> split-K GEMM -> fused reduce+bias+LN+pos+attnLN0
  ln768_kernel<<<MR, 256, 0, stream>>>(patches, emb_ln_g, xn);
  gemm_mfma<0,0,0,0,64,2,0><<<dim3(12,32,2), 256, 0, stream>>>(xn, (const bf16*)(ws+o_WembT), nullptr,
      P, nullptr, nullptr, nullptr, nullptr, nullptr, nullptr, MR, 768, 768);
  ln_pos2_kernel<<<MR, 256, 0, stream>>>(P, b_emb, emb_ln2_g, pos_h, pos_w, ppos, x, ln_attn_g, xn);

  // ---- transformer layers (xn holds LN(x) with this layer's attn gamma at loop entry)
  for (int l = 0; l < NLAYER; ++l) {
    // qkv GEMM with fused qk-RMSnorm + V-transpose epilogue -> Qb/Kb/VTb directly
    gemm_mfma<0,0,0,0,64,1,1><<<dim3(36,32), 256, 0, stream>>>(xn, (const bf16*)(ws+o_QKVT[l]), nullptr,
        nullptr, nullptr, qn_g + (size_t)l*768, kn_g + (size_t)l*768, Qb, Kb, VTb, MR, 2304, 768);
    attn_mfma<<<dim3(16,NH,NB), 256, 0, stream>>>(Qb, Kb, VTb, Ob, image_ids, lengths);
    // Wo: split-K -> partials; fused reduce+residual+LN(ff gamma)
    gemm_mfma<0,0,0,0,64,2,0><<<dim3(12,32,2), 256, 0, stream>>>(Ob, (const bf16*)(ws+o_WoT[l]), nullptr,
        P, nullptr, nullptr, nullptr, nullptr, nullptr, nullptr, MR, 768, 768);
    res2_ln_kernel<0><<<MR, 256, 0, stream>>>(x, P, nullptr, ln_ff_g + (size_t)l*768, xn);
    gemm_mfma<1,1,1,0,128,1,0><<<dim3(24,32), 256, 0, stream>>>(xn, (const bf16*)(ws+o_W1T[l]), b1 + (size_t)l*3072,
        nullptr, hb, nullptr, nullptr, nullptr, nullptr, nullptr, MR, 3072, 768);
    // W2: split-K -> partials; fused reduce+bias+residual+LN(next gamma)
    gemm_mfma<0,0,0,0,64,2,0><<<dim3(12,32,2), 256, 0, stream>>>(hb, (const bf16*)(ws+o_W2T[l]), nullptr,
        P, nullptr, nullptr, nullptr, nullptr, nullptr, nullptr, MR, 768, 3072);
    const float* gnext = (l + 1 < NLAYER) ? (ln_attn_g + (size_t)(l+1)*768) : final_ln_g;
    res2_ln_kernel<1><<<MR, 256, 0, stream>>>(x, P, b2v + (size_t)l*768, gnext, xn);
  }

  // ---- pooling + head (xn = LN(x, final_ln_g) from the last res2_ln)
  gemm_mfma<0,0,1,0,64,1,0><<<dim3(24,32), 256, 0, stream>>>(xn, (const bf16*)(ws+o_pWkvT), nullptr,
      nullptr, kvb, nullptr, nullptr, nullptr, nullptr, nullptr, MR, 1536, 768);
  pool_q_kernel<<<NH, 256, 0, stream>>>(pool_q, pool_ln_g, pWq, p_qn_g, qp);
  pool_attn_kernel<<<dim3(NH,NIMG,NB), 256, 0, stream>>>(kvb, qp, p_kn_g, image_ids, lengths, pooled);
  // pooled_final = pooled @ pWo + pool_q (k-parallel small-M GEMM)
  smallm_gemm<0,1><<<12, 256, 0, stream>>>(pooled, pWo, pool_q, pooledf, 768);
  ln768_kernel<<<16, 256, 0, stream>>>(pooledf, head_ln_g, hl);
  // out = LN(pooledf) @ W_head
  smallm_gemm<1,0><<<16, 256, 0, stream>>>(hl, W_head, nullptr, (float*)d_out, NCLS);
}

// Round 8
// 1013.434 us; speedup vs baseline: 1.1061x; 1.0697x over previous
//
#include <hip/hip_runtime.h>
#include <hip/hip_bf16.h>
#include <math.h>

using bf16 = __hip_bfloat16;
typedef short s16x8 __attribute__((ext_vector_type(8)));
typedef short s16x4 __attribute__((ext_vector_type(4)));
typedef float f32x4 __attribute__((ext_vector_type(4)));

#define DEVI __device__ __forceinline__

static constexpr int NB    = 4;
static constexpr int NTOK  = 1024;
static constexpr int DIM   = 768;
static constexpr int NH    = 12;
static constexpr int MLPD  = 3072;
static constexpr int NLAYER= 4;
static constexpr int NIMG  = 4;
static constexpr int NCLS  = 1000;
static constexpr int MR    = NB * NTOK;   // 4096 rows
static constexpr size_t SLAB = (size_t)MR * 768;  // split-K partial slab (f32 elems)

DEVI float b2f(bf16 v){ return __bfloat162float(v); }
DEVI bf16  f2b(float v){ return __float2bfloat16(v); }
DEVI float bu2f(unsigned short u){ union{unsigned u32; float f;} w; w.u32 = ((unsigned)u)<<16; return w.f; }
DEVI unsigned short f2bu(float f){ bf16 b = f2b(f); return *(unsigned short*)&b; }

DEVI void async16(const void* g, void* l) {
  __builtin_amdgcn_global_load_lds((const __attribute__((address_space(1))) void*)g,
                                   (__attribute__((address_space(3))) void*)l, 16, 0, 0);
}

DEVI f32x4 mfma16(s16x8 a, s16x8 b, f32x4 c) {
  return __builtin_amdgcn_mfma_f32_16x16x32_bf16(a, b, c, 0, 0, 0);
}

template<int N> DEVI void waitcnt_vm() {
  if constexpr (N == 0)      asm volatile("s_waitcnt vmcnt(0)" ::: "memory");
  else if constexpr (N == 2) asm volatile("s_waitcnt vmcnt(2)" ::: "memory");
  else if constexpr (N == 3) asm volatile("s_waitcnt vmcnt(3)" ::: "memory");
  else if constexpr (N == 4) asm volatile("s_waitcnt vmcnt(4)" ::: "memory");
  else if constexpr (N == 6) asm volatile("s_waitcnt vmcnt(6)" ::: "memory");
}

DEVI float block_sum(float v, float* scratch, int tid) {
  #pragma unroll
  for (int o = 32; o >= 1; o >>= 1) v += __shfl_xor(v, o);
  __syncthreads();
  if ((tid & 63) == 0) scratch[tid >> 6] = v;
  __syncthreads();
  return scratch[0] + scratch[1] + scratch[2] + scratch[3];
}

DEVI float block_max(float v, float* scratch, int tid) {
  #pragma unroll
  for (int o = 32; o >= 1; o >>= 1) v = fmaxf(v, __shfl_xor(v, o));
  __syncthreads();
  if ((tid & 63) == 0) scratch[tid >> 6] = v;
  __syncthreads();
  return fmaxf(fmaxf(scratch[0], scratch[1]), fmaxf(scratch[2], scratch[3]));
}

// ---------------------------------------------------------------- transpose + f32->bf16 convert
// 2x 64x64 tiles per block; pitch 70 u16 keeps the phase-2 gather ~conflict-free.
struct TEntry { const float* src; bf16* dst; int R, C, tiles, tC; };
struct TDesc  { TEntry e[22]; };

__global__ __launch_bounds__(256) void transpose_kernel(TDesc D, int nent) {
  int tix = blockIdx.x * 2, ei = 0;            // tile index (entries all have even tile counts)
  while (ei < nent - 1 && tix >= D.e[ei].tiles) { tix -= D.e[ei].tiles; ++ei; }
  const TEntry E = D.e[ei];
  __shared__ unsigned short t[2][64][70];      // 2 x 8.75 KB
  const int tid = threadIdx.x;
  const int r = tid >> 4, c = (tid & 15) * 4;
  float4 v[2][4];
  #pragma unroll
  for (int q = 0; q < 2; ++q) {
    const int tr = (tix + q) / E.tC, tc = (tix + q) % E.tC;
    #pragma unroll
    for (int p = 0; p < 4; ++p)
      v[q][p] = *(const float4*)(E.src + (size_t)(tr*64 + p*16 + r)*E.C + tc*64 + c);
  }
  #pragma unroll
  for (int q = 0; q < 2; ++q) {
    #pragma unroll
    for (int p = 0; p < 4; ++p) {
      unsigned short* dst = &t[q][p*16 + r][c];
      dst[0] = f2bu(v[q][p].x); dst[1] = f2bu(v[q][p].y);
      dst[2] = f2bu(v[q][p].z); dst[3] = f2bu(v[q][p].w);
    }
    __syncthreads();
    const int tr = (tix + q) / E.tC, tc = (tix + q) % E.tC;
    #pragma unroll
    for (int p = 0; p < 2; ++p) {
      const int n = p*32 + (tid >> 3);
      const int r0 = (tid & 7) * 8;
      s16x8 o;
      #pragma unroll
      for (int i = 0; i < 8; ++i) o[i] = (short)t[q][r0 + i][n];
      *(s16x8*)((short*)E.dst + (size_t)(tc*64 + n)*E.R + tr*64 + r0) = o;
    }
  }
}

// ---------------------------------------------------------------- LayerNorm (768 cols), f32 in, bf16 out
__global__ __launch_bounds__(256) void ln768_kernel(const float* __restrict__ in,
    const float* __restrict__ g, bf16* __restrict__ out)
{
  __shared__ float scratch[4];
  const int row = blockIdx.x, tid = threadIdx.x;
  const float* p = in + (size_t)row*768;
  const float v0 = p[tid], v1 = p[tid+256], v2 = p[tid+512];
  const float s  = block_sum(v0+v1+v2, scratch, tid);
  const float ss = block_sum(v0*v0+v1*v1+v2*v2, scratch, tid);
  const float mu = s * (1.0f/768.0f);
  const float var = ss * (1.0f/768.0f) - mu*mu;
  const float rstd = rsqrtf(var + 1e-5f);
  bf16* o = out + (size_t)row*768;
  o[tid]     = f2b((v0-mu)*rstd*g[tid]);
  o[tid+256] = f2b((v1-mu)*rstd*g[tid+256]);
  o[tid+512] = f2b((v2-mu)*rstd*g[tid+512]);
}

// Fused split-K reduce + residual + LayerNorm:
// x += P0 + P1 (+bias); xn = LN(x)*g (bf16). x updated in place.
template<int HAS_BIAS>
__global__ __launch_bounds__(256) void res2_ln_kernel(float* __restrict__ x,
    const float* __restrict__ P, const float* __restrict__ bias,
    const float* __restrict__ g, bf16* __restrict__ xn)
{
  __shared__ float scratch[4];
  const int row = blockIdx.x, tid = threadIdx.x;
  const size_t base = (size_t)row*768;
  const float* p0 = P + base;
  const float* p1 = P + SLAB + base;
  float* xr = x + base;
  float v[3];
  #pragma unroll
  for (int i = 0; i < 3; ++i) {
    const int c = tid + i*256;
    float t = xr[c] + p0[c] + p1[c];
    if constexpr (HAS_BIAS) t += bias[c];
    v[i] = t;
    xr[c] = t;
  }
  const float s  = block_sum(v[0]+v[1]+v[2], scratch, tid);
  const float ss = block_sum(v[0]*v[0]+v[1]*v[1]+v[2]*v[2], scratch, tid);
  const float mu = s * (1.0f/768.0f);
  const float rstd = rsqrtf(ss*(1.0f/768.0f) - mu*mu + 1e-5f);
  bf16* o = xn + base;
  #pragma unroll
  for (int i = 0; i < 3; ++i) {
    const int c = tid + i*256;
    o[c] = f2b((v[i]-mu)*rstd*g[c]);
  }
}

// Fused embed: v = P0+P1+b_emb; x = LN(v)*g + pos_h + pos_w; xn = LN(x)*g2 (layer-0 attn LN)
__global__ __launch_bounds__(256) void ln_pos2_kernel(const float* __restrict__ P,
    const float* __restrict__ bias, const float* __restrict__ g,
    const float* __restrict__ pos_h, const float* __restrict__ pos_w,
    const int* __restrict__ ppos, float* __restrict__ out,
    const float* __restrict__ g2, bf16* __restrict__ xn)
{
  __shared__ float scratch[4];
  const int row = blockIdx.x, tid = threadIdx.x;
  const size_t base = (size_t)row*768;
  const float* p0 = P + base;
  const float* p1 = P + SLAB + base;
  float v[3];
  #pragma unroll
  for (int i = 0; i < 3; ++i) {
    const int c = tid + i*256;
    v[i] = p0[c] + p1[c] + bias[c];
  }
  const float s  = block_sum(v[0]+v[1]+v[2], scratch, tid);
  const float ss = block_sum(v[0]*v[0]+v[1]*v[1]+v[2]*v[2], scratch, tid);
  const float mu = s * (1.0f/768.0f);
  const float rstd = rsqrtf(ss*(1.0f/768.0f) - mu*mu + 1e-5f);
  const int p0i = ppos[row*2], p1i = ppos[row*2+1];
  const float* ph = pos_h + (size_t)p0i*768;
  const float* pw = pos_w + (size_t)p1i*768;
  float* o = out + base;
  float xv[3];
  #pragma unroll
  for (int i = 0; i < 3; ++i) {
    const int c = tid + i*256;
    xv[i] = (v[i]-mu)*rstd*g[c] + ph[c] + pw[c];
    o[c] = xv[i];
  }
  // second LN (layer-0 attention LN) on the register-resident row
  const float s2  = block_sum(xv[0]+xv[1]+xv[2], scratch, tid);
  const float ss2 = block_sum(xv[0]*xv[0]+xv[1]*xv[1]+xv[2]*xv[2], scratch, tid);
  const float mu2 = s2 * (1.0f/768.0f);
  const float rstd2 = rsqrtf(ss2*(1.0f/768.0f) - mu2*mu2 + 1e-5f);
  bf16* on = xn + base;
  #pragma unroll
  for (int i = 0; i < 3; ++i) {
    const int c = tid + i*256;
    on[c] = f2b((xv[i]-mu2)*rstd2*g2[c]);
  }
}

// ---------------------------------------------------------------- GEMM (MFMA, XOR-swizzled LDS)
// PD-deep global_load_lds pipeline, counted vmcnt (T3/T4), XCD-bijective swizzle (T1).
// WAVES=4 (256 thr) or 8 (512 thr): 8-wave splits the 128xNTILE tile 4x2 (each wave 32x64)
// for 2x waves/CU TLP on the big-N GEMMs. SPLITK>1: blockIdx.z selects a K-chunk; partials
// to slab z, reduced in res2_ln/ln_pos2. RMSQKV (NTILE=128 only): each wave's 64-col half
// is exactly one head; epilogue applies qk-RMSnorm fully in-wave and writes Qb/Kb, or
// transposes V into VT.
template<int DO_BIAS, int DO_GELU, int OUT_BF16, int DO_RES, int NTILE, int SPLITK,
         int RMSQKV, int WAVES, int PD>
__global__ __launch_bounds__(WAVES*64)
void gemm_mfma(const bf16* __restrict__ A, const bf16* __restrict__ BT,
               const float* __restrict__ bias, float* __restrict__ Cf,
               bf16* __restrict__ Cb,
               const float* __restrict__ qg, const float* __restrict__ kg,
               bf16* __restrict__ Qp, bf16* __restrict__ Kp, bf16* __restrict__ Vp,
               int M, int Nn, int K)
{
  constexpr int NF    = NTILE / 32;         // n-frags per wave (2 or 4)
  constexpr int WY    = WAVES / 2;          // waves along M
  constexpr int MROWS = 128 / WY;           // rows per wave (64 or 32)
  constexpr int MF    = MROWS / 16;         // m-frags per wave (4 or 2)
  constexpr int ALOOPS = 64 / (8*WAVES);    // A-stage iterations (LDS rows 64)
  constexpr int BLOOPS = (NTILE/2) / (8*WAVES);
  constexpr int LPI   = ALOOPS + BLOOPS;    // glld per thread per stage
  constexpr int VW    = (PD - 2) * LPI;     // steady-state vmcnt
  __shared__ bf16 As[PD][64*64];            // PD x 8 KB
  __shared__ bf16 Bs[PD][(NTILE/2)*64];     // PD x (4 or 8) KB
  const int tid = threadIdx.x;
  const int wid = tid >> 6, lane = tid & 63;
  const int quad = lane >> 4, l15 = lane & 15;
  const int wy = wid >> 1, wx = wid & 1;

  // XCD-aware bijective swizzle (m204 form), per K-chunk plane.
  const int gx  = gridDim.x;
  const int nwg = gx * gridDim.y;
  const int bid = blockIdx.y * gx + blockIdx.x;
  const int qq  = nwg >> 3, rm = nwg & 7;
  const int xcd = bid & 7,  li = bid >> 3;
  const int swz = (xcd < rm ? xcd * (qq + 1) : rm * (qq + 1) + (xcd - rm) * qq) + li;
  const int m0 = (swz / gx) * 128, n0 = (swz % gx) * NTILE;

  const int kz    = (SPLITK > 1) ? blockIdx.z : 0;
  const int kloc  = K / SPLITK;             // K per chunk
  const int kbase = kz * kloc;

  const int rl = lane >> 3;                 // local LDS row 0..7
  const int cs = lane & 7;                  // slot 0..7

  f32x4 acc[MF][NF];
  #pragma unroll
  for (int i = 0; i < MF; ++i)
    #pragma unroll
    for (int j = 0; j < NF; ++j) acc[i][j] = (f32x4){0.f,0.f,0.f,0.f};

  auto stage = [&](int buf, int k0) {
    #pragma unroll
    for (int c = 0; c < ALOOPS; ++c) {
      const int rbase = wid*8 + c*(8*WAVES);
      const int r_abs = rbase + rl;
      const int ceff  = cs ^ (r_abs & 7);
      const int mg    = 2*r_abs + (ceff >> 2);
      const int jb    = (ceff & 3) * 16;
      async16((const char*)A + ((size_t)(m0 + mg)*K + k0)*2 + jb, (char*)As[buf] + rbase*128);
    }
    #pragma unroll
    for (int c = 0; c < BLOOPS; ++c) {
      const int rbase = wid*8 + c*(8*WAVES);
      const int r_abs = rbase + rl;
      const int ceff  = cs ^ (r_abs & 7);
      const int ng    = 2*r_abs + (ceff >> 2);
      const int jb    = (ceff & 3) * 16;
      async16((const char*)BT + ((size_t)(n0 + ng)*K + k0)*2 + jb, (char*)Bs[buf] + rbase*128);
    }
  };

  auto compute = [&](int cb) {
    s16x8 af[MF], bfr[NF];
    #pragma unroll
    for (int mt = 0; mt < MF; ++mt) {
      const int m = wy*MROWS + mt*16 + l15;
      const int r = m >> 1;
      const int cq = (((m & 1) << 2) | quad) ^ (r & 7);
      af[mt] = *(const s16x8*)((const char*)As[cb] + r*128 + cq*16);
    }
    #pragma unroll
    for (int nt = 0; nt < NF; ++nt) {
      const int n = wx*(NTILE/2) + nt*16 + l15;
      const int r = n >> 1;
      const int cq = (((n & 1) << 2) | quad) ^ (r & 7);
      bfr[nt] = *(const s16x8*)((const char*)Bs[cb] + r*128 + cq*16);
    }
    #pragma unroll
    for (int mt = 0; mt < MF; ++mt)
      #pragma unroll
      for (int nt = 0; nt < NF; ++nt)
        acc[mt][nt] = mfma16(af[mt], bfr[nt], acc[mt][nt]);
  };

  const int nk = kloc >> 5;
  #pragma unroll
  for (int t = 0; t < PD - 1; ++t) stage(t, kbase + (t << 5));

  int cbuf = 0, sbuf = PD - 1;
  const int mainN = nk - (PD - 1);
  for (int kt = 0; kt < mainN; ++kt) {
    __builtin_amdgcn_sched_barrier(0);
    waitcnt_vm<VW>();                       // tile kt complete; later tiles stay in flight
    __builtin_amdgcn_s_barrier();
    __builtin_amdgcn_sched_barrier(0);
    stage(sbuf, kbase + ((kt + PD - 1) << 5));
    compute(cbuf);
    cbuf = (cbuf + 1 == PD) ? 0 : cbuf + 1;
    sbuf = (sbuf + 1 == PD) ? 0 : sbuf + 1;
  }
  for (int kt = mainN; kt < nk; ++kt) {     // tail: drain
    __builtin_amdgcn_sched_barrier(0);
    waitcnt_vm<0>();
    __builtin_amdgcn_s_barrier();
    __builtin_amdgcn_sched_barrier(0);
    compute(cbuf);
    cbuf = (cbuf + 1 == PD) ? 0 : cbuf + 1;
  }

  if constexpr (RMSQKV) {
    // NTILE==128: wave wx's 64-col half is exactly one head slice; rms fully in-wave.
    const int hslice = (n0 >> 6) + wx;      // 0..35 (tiles never straddle Q/K/V regions)
    const int region = hslice / NH;         // 0:Q 1:K 2:V
    const int h  = hslice - region*NH;
    const int b  = m0 >> 10;
    const int bh = b*NH + h;
    const int tokb = m0 & (NTOK-1);
    if (region < 2) {
      const float* gp = (region == 0) ? (qg + h*64) : (kg + h*64);
      bf16* outb = (region == 0) ? Qp : Kp;
      #pragma unroll
      for (int mt = 0; mt < MF; ++mt)
        #pragma unroll
        for (int rr = 0; rr < 4; ++rr) {
          float ssq = 0.f;
          #pragma unroll
          for (int nt = 0; nt < NF; ++nt) ssq += acc[mt][nt][rr]*acc[mt][nt][rr];
          #pragma unroll
          for (int o = 1; o <= 8; o <<= 1) ssq += __shfl_xor(ssq, o);
          const float rn = 8.0f / fmaxf(sqrtf(ssq), 1e-12f);
          const int tok = tokb + wy*MROWS + mt*16 + quad*4 + rr;
          #pragma unroll
          for (int nt = 0; nt < NF; ++nt) {
            const int d = nt*16 + l15;
            outb[((size_t)bh*NTOK + tok)*64 + d] = f2b(acc[mt][nt][rr]*rn*gp[d]);
          }
        }
    } else {
      // V: write transposed VT[bh*64+d][tok], 4 consecutive tokens per 8B store
      #pragma unroll
      for (int mt = 0; mt < MF; ++mt)
        #pragma unroll
        for (int nt = 0; nt < NF; ++nt) {
          const int d = nt*16 + l15;
          const int tok = tokb + wy*MROWS + mt*16 + quad*4;
          s16x4 pk;
          #pragma unroll
          for (int rr = 0; rr < 4; ++rr) pk[rr] = (short)f2bu(acc[mt][nt][rr]);
          *(s16x4*)((short*)Vp + ((size_t)bh*64 + d)*NTOK + tok) = pk;
        }
    }
  } else {
    float* Cslab = (SPLITK > 1) ? (Cf + (size_t)kz * SLAB) : Cf;
    #pragma unroll
    for (int nt = 0; nt < NF; ++nt) {
      const int col = n0 + wx*(NTILE/2) + nt*16 + l15;
      float bv = 0.f;
      if constexpr (DO_BIAS) bv = bias[col];
      #pragma unroll
      for (int mt = 0; mt < MF; ++mt) {
        #pragma unroll
        for (int r = 0; r < 4; ++r) {
          const int row = m0 + wy*MROWS + mt*16 + quad*4 + r;
          float v = acc[mt][nt][r];
          if constexpr (DO_BIAS) v += bv;
          if constexpr (DO_GELU) v = 0.5f*v*(1.0f + erff(v*0.70710678118654752f));
          const size_t idx = (size_t)row*Nn + col;
          if constexpr (OUT_BF16) Cb[idx] = f2b(v);
          else if constexpr (DO_RES) Cslab[idx] += v;
          else Cslab[idx] = v;
        }
      }
    }
  }
}

// ---------------------------------------------------------------- small-M GEMM (M=16, K=768)
template<int IN_BF16, int DO_BIAS>
__global__ __launch_bounds__(256) void smallm_gemm(const void* __restrict__ Xv,
    const float* __restrict__ W, const float* __restrict__ bias,
    float* __restrict__ out, int Nn)
{
  __shared__ float Xs[16*768];
  __shared__ float red[4][16][64];
  const int tid = threadIdx.x;
  if constexpr (IN_BF16) {
    const bf16* X = (const bf16*)Xv;
    for (int i = tid; i < 16*768; i += 256) Xs[i] = b2f(X[i]);
  } else {
    const float* X = (const float*)Xv;
    for (int i = tid; i < 16*768; i += 256) Xs[i] = X[i];
  }
  __syncthreads();
  const int cl = tid & 63, kg = tid >> 6;
  const int c = blockIdx.x*64 + cl;
  float acc[16];
  #pragma unroll
  for (int r = 0; r < 16; ++r) acc[r] = 0.f;
  if (c < Nn) {
    const int k0 = kg*192;
    #pragma unroll 4
    for (int k = k0; k < k0 + 192; ++k) {
      const float w = W[(size_t)k*Nn + c];
      #pragma unroll
      for (int r = 0; r < 16; ++r) acc[r] += Xs[r*768 + k] * w;
    }
  }
  #pragma unroll
  for (int r = 0; r < 16; ++r) red[kg][r][cl] = acc[r];
  __syncthreads();
  if (kg == 0 && c < Nn) {
    #pragma unroll
    for (int r = 0; r < 16; ++r) {
      float v = red[0][r][cl] + red[1][r][cl] + red[2][r][cl] + red[3][r][cl];
      if constexpr (DO_BIAS) v += bias[c];
      out[(size_t)r*Nn + c] = v;
    }
  }
}

// ---------------------------------------------------------------- fused MFMA attention
__global__ __launch_bounds__(256) void attn_mfma(const bf16* __restrict__ Qb,
    const bf16* __restrict__ Kb, const bf16* __restrict__ VTb, bf16* __restrict__ Ob,
    const int* __restrict__ ids, const int* __restrict__ lens)
{
  __shared__ bf16 Ps[4][16*72];   // per-wave P tile [m=16][j=64], row stride 72 elems
  __shared__ int  ids_s[NTOK];
  const int qt = blockIdx.x, h = blockIdx.y, b = blockIdx.z;
  const int tid = threadIdx.x;
  const int wid = tid >> 6, lane = tid & 63;
  const int quad = lane >> 4, l15 = lane & 15;
  const int bh = b*NH + h;
  const int q0 = qt*64;
  const int len = lens[b];

  #pragma unroll
  for (int i = 0; i < 4; ++i) ids_s[i*256 + tid] = ids[b*NTOK + i*256 + tid];
  __syncthreads();

  const bf16* qrow = Qb + ((size_t)bh*NTOK + q0 + wid*16 + l15)*64;
  const s16x8 aq0 = *(const s16x8*)(qrow + quad*8);
  const s16x8 aq1 = *(const s16x8*)(qrow + 32 + quad*8);

  int idq[4];
  #pragma unroll
  for (int rr = 0; rr < 4; ++rr) idq[rr] = ids_s[q0 + wid*16 + quad*4 + rr];

  unsigned qm = 0;
  #pragma unroll
  for (int rr = 0; rr < 4; ++rr) qm |= 1u << (idq[rr] & 31);
  #pragma unroll
  for (int o = 32; o >= 1; o >>= 1) qm |= (unsigned)__shfl_xor((int)qm, o);

  f32x4 oacc[4];
  #pragma unroll
  for (int nt = 0; nt < 4; ++nt) oacc[nt] = (f32x4){0.f,0.f,0.f,0.f};
  float mrow[4] = {-3.0e38f,-3.0e38f,-3.0e38f,-3.0e38f};
  float lrow[4] = {0.f,0.f,0.f,0.f};

  const bf16* Kgb = Kb  + (size_t)bh*NTOK*64;
  const bf16* Vgb = VTb + (size_t)bh*64*NTOK;
  bf16* pw = Ps[wid];

  for (int kt = 0; kt < 16; ++kt) {
    const int k0 = kt*64;
    const int idk_l = ids_s[k0 + lane];
    const bool ok = ((k0 + lane) < len) && (((qm >> (idk_l & 31)) & 1u) != 0u);
    if (__ballot(ok) == 0ULL) continue;

    f32x4 sA[4];
    #pragma unroll
    for (int jt = 0; jt < 4; ++jt) {
      const bf16* krow = Kgb + (size_t)(k0 + jt*16 + l15)*64;
      const s16x8 bk0 = *(const s16x8*)(krow + quad*8);
      const s16x8 bk1 = *(const s16x8*)(krow + 32 + quad*8);
      f32x4 s = (f32x4){0.f,0.f,0.f,0.f};
      s = mfma16(aq0, bk0, s);
      s = mfma16(aq1, bk1, s);
      sA[jt] = s;
    }
    #pragma unroll
    for (int jt = 0; jt < 4; ++jt) {
      const int j = k0 + jt*16 + l15;
      const int idk = ids_s[j];
      const bool kvld = j < len;
      #pragma unroll
      for (int rr = 0; rr < 4; ++rr)
        sA[jt][rr] = (kvld && idk == idq[rr]) ? sA[jt][rr] : -3.0e38f;
    }
    float alpha[4], mnew[4];
    #pragma unroll
    for (int rr = 0; rr < 4; ++rr) {
      float mx = fmaxf(fmaxf(sA[0][rr], sA[1][rr]), fmaxf(sA[2][rr], sA[3][rr]));
      mx = fmaxf(mx, __shfl_xor(mx, 1));
      mx = fmaxf(mx, __shfl_xor(mx, 2));
      mx = fmaxf(mx, __shfl_xor(mx, 4));
      mx = fmaxf(mx, __shfl_xor(mx, 8));
      const float mn = fmaxf(mrow[rr], mx);
      mnew[rr] = mn;
      alpha[rr] = expf(mrow[rr] - mn);
      mrow[rr] = mn;
    }
    #pragma unroll
    for (int rr = 0; rr < 4; ++rr) {
      float rs = 0.f;
      #pragma unroll
      for (int jt = 0; jt < 4; ++jt) {
        const float pv = (sA[jt][rr] > -1.0e38f) ? expf(sA[jt][rr] - mnew[rr]) : 0.0f;
        sA[jt][rr] = pv;
        rs += pv;
      }
      rs += __shfl_xor(rs, 1);
      rs += __shfl_xor(rs, 2);
      rs += __shfl_xor(rs, 4);
      rs += __shfl_xor(rs, 8);
      lrow[rr] = lrow[rr]*alpha[rr] + rs;
      #pragma unroll
      for (int nt = 0; nt < 4; ++nt) oacc[nt][rr] *= alpha[rr];
    }
    #pragma unroll
    for (int jt = 0; jt < 4; ++jt)
      #pragma unroll
      for (int rr = 0; rr < 4; ++rr)
        pw[(quad*4+rr)*72 + jt*16 + l15] = f2b(sA[jt][rr]);
    #pragma unroll
    for (int ss = 0; ss < 2; ++ss) {
      const s16x8 ap = *(const s16x8*)(pw + l15*72 + ss*32 + quad*8);
      #pragma unroll
      for (int nt = 0; nt < 4; ++nt) {
        const s16x8 bv = *(const s16x8*)(Vgb + (size_t)(nt*16 + l15)*NTOK + k0 + ss*32 + quad*8);
        oacc[nt] = mfma16(ap, bv, oacc[nt]);
      }
    }
  }

  #pragma unroll
  for (int rr = 0; rr < 4; ++rr) {
    const float inv = lrow[rr] > 0.f ? 1.0f/lrow[rr] : 0.0f;
    const int n = q0 + wid*16 + quad*4 + rr;
    bf16* orow = Ob + ((size_t)b*NTOK + n)*768 + h*64;
    #pragma unroll
    for (int nt = 0; nt < 4; ++nt)
      orow[nt*16 + l15] = f2b(oacc[nt][rr]*inv);
  }
}

// ---------------------------------------------------------------- pooling path
__global__ __launch_bounds__(256) void pool_q_kernel(const float* __restrict__ pool_q,
    const float* __restrict__ pool_ln_g, const float* __restrict__ pWq,
    const float* __restrict__ p_qn_g, float* __restrict__ qp)
{
  __shared__ float xn[768];
  __shared__ float scratch[4];
  __shared__ float qraw[64];
  const int h = blockIdx.x, tid = threadIdx.x;
  float v0 = pool_q[tid], v1 = pool_q[tid+256], v2 = pool_q[tid+512];
  const float s  = block_sum(v0+v1+v2, scratch, tid);
  const float ss = block_sum(v0*v0+v1*v1+v2*v2, scratch, tid);
  const float mu = s*(1.0f/768.0f);
  const float rstd = rsqrtf(ss*(1.0f/768.0f) - mu*mu + 1e-5f);
  xn[tid]     = (v0-mu)*rstd*pool_ln_g[tid];
  xn[tid+256] = (v1-mu)*rstd*pool_ln_g[tid+256];
  xn[tid+512] = (v2-mu)*rstd*pool_ln_g[tid+512];
  __syncthreads();
  const int d = tid >> 2, pp = tid & 3;
  const int col = h*64 + d;
  float acc = 0.f;
  for (int k = pp*192; k < (pp+1)*192; ++k) acc += xn[k]*pWq[(size_t)k*768 + col];
  acc += __shfl_xor(acc, 1); acc += __shfl_xor(acc, 2);
  if (pp == 0) qraw[d] = acc;
  __syncthreads();
  if (tid < 64) {
    const float q = qraw[tid];
    float sq = q*q;
    #pragma unroll
    for (int o = 32; o >= 1; o >>= 1) sq += __shfl_xor(sq, o);
    const float rn = 8.0f / fmaxf(sqrtf(sq), 1e-12f);
    qp[h*64 + tid] = q * rn * p_qn_g[h*64 + tid];
  }
}

__global__ __launch_bounds__(256) void pool_attn_kernel(const bf16* __restrict__ kvp,
    const float* __restrict__ qp, const float* __restrict__ kg,
    const int* __restrict__ ids, const int* __restrict__ lens, float* __restrict__ pooled)
{
  __shared__ float sp[1024];
  __shared__ float qg_s[64];
  __shared__ float scratch[4];
  __shared__ float outred[4][64];
  const int h = blockIdx.x, img = blockIdx.y, b = blockIdx.z;
  const int tid = threadIdx.x;
  const int len = lens[b];
  if (tid < 64) qg_s[tid] = qp[h*64 + tid] * kg[h*64 + tid];
  __syncthreads();

  float smax = -3.0e38f;
  for (int j = tid; j < 1024; j += 256) {
    float sv = -3.0e38f;
    if (j < len && ids[b*NTOK + j] == img) {
      const bf16* kr = kvp + (size_t)(b*NTOK + j)*1536 + h*64;
      float ssq = 0.f, dq = 0.f;
      #pragma unroll
      for (int dd = 0; dd < 64; dd += 8) {
        s16x8 k8 = *(const s16x8*)(kr + dd);
        #pragma unroll
        for (int i = 0; i < 8; ++i) {
          const float kv = bu2f((unsigned short)k8[i]);
          ssq += kv*kv;
          dq  += qg_s[dd+i]*kv;
        }
      }
      const float rn = 8.0f / fmaxf(sqrtf(ssq), 1e-12f);
      sv = dq * rn;
    }
    sp[j] = sv;
    smax = fmaxf(smax, sv);
  }
  const float M = block_max(smax, scratch, tid);
  float lsum = 0.f;
  for (int j = tid; j < 1024; j += 256) {
    const float p = (sp[j] > -1.0e38f) ? expf(sp[j] - M) : 0.0f;
    sp[j] = p;
    lsum += p;
  }
  const float L = block_sum(lsum, scratch, tid);
  const float invL = L > 0.f ? 1.0f / L : 0.0f;

  const int d = tid & 63, jg = tid >> 6;
  float acc = 0.f;
  for (int j = jg; j < 1024; j += 4) {
    const float p = sp[j];
    if (p > 0.f) acc += p * b2f(kvp[(size_t)(b*NTOK + j)*1536 + 768 + h*64 + d]);
  }
  outred[jg][d] = acc;
  __syncthreads();
  if (tid < 64) {
    const float o = (outred[0][tid] + outred[1][tid] + outred[2][tid] + outred[3][tid]) * invL;
    pooled[((size_t)b*NIMG + img)*768 + h*64 + tid] = o;
  }
}

// ---------------------------------------------------------------- host
extern "C" void kernel_launch(void* const* d_in, const int* in_sizes, int n_in,
                              void* d_out, int out_size, void* d_ws, size_t ws_size,
                              hipStream_t stream)
{
  const float* patches    = (const float*)d_in[0];
  const int*   ppos       = (const int*)d_in[1];
  const int*   image_ids  = (const int*)d_in[2];
  const int*   lengths    = (const int*)d_in[3];
  const float* emb_ln_g   = (const float*)d_in[4];
  const float* W_emb      = (const float*)d_in[5];
  const float* b_emb      = (const float*)d_in[6];
  const float* emb_ln2_g  = (const float*)d_in[7];
  const float* pos_h      = (const float*)d_in[8];
  const float* pos_w      = (const float*)d_in[9];
  const float* ln_attn_g  = (const float*)d_in[10];
  const float* Wq         = (const float*)d_in[11];
  const float* Wkv        = (const float*)d_in[12];
  const float* qn_g       = (const float*)d_in[13];
  const float* kn_g       = (const float*)d_in[14];
  const float* Wo         = (const float*)d_in[15];
  const float* ln_ff_g    = (const float*)d_in[16];
  const float* W1         = (const float*)d_in[17];
  const float* b1         = (const float*)d_in[18];
  const float* W2         = (const float*)d_in[19];
  const float* b2v        = (const float*)d_in[20];
  const float* final_ln_g = (const float*)d_in[21];
  const float* pool_q     = (const float*)d_in[22];
  const float* pool_ln_g  = (const float*)d_in[23];
  const float* pWq        = (const float*)d_in[24];
  const float* pWkv       = (const float*)d_in[25];
  const float* p_qn_g     = (const float*)d_in[26];
  const float* p_kn_g     = (const float*)d_in[27];
  const float* pWo        = (const float*)d_in[28];
  const float* head_ln_g  = (const float*)d_in[29];
  const float* W_head     = (const float*)d_in[30];

  char* ws = (char*)d_ws;
  size_t off = 0;
  auto alloc = [&](size_t sz){ size_t r = off; off += (sz + 255) & ~(size_t)255; return r; };

  const size_t o_WembT = alloc((size_t)768*768*2);
  size_t o_QKVT[4], o_WoT[4], o_W1T[4], o_W2T[4];
  for (int l = 0; l < NLAYER; ++l) {
    o_QKVT[l] = alloc((size_t)2304*768*2);
    o_WoT[l]  = alloc((size_t)768*768*2);
    o_W1T[l]  = alloc((size_t)3072*768*2);
    o_W2T[l]  = alloc((size_t)768*3072*2);
  }
  const size_t o_pWkvT = alloc((size_t)1536*768*2);
  const size_t o_x     = alloc((size_t)MR*768*4);
  const size_t o_xn    = alloc((size_t)MR*768*2);
  const size_t o_kv    = alloc((size_t)MR*3072*2);   // bf16: sized for W1-out h (MRx3072); also pool kv
  const size_t o_P     = alloc((size_t)2*SLAB*4);    // split-K partial slabs (2x 12.6MB)
  const size_t o_Qb    = alloc((size_t)MR*768*2);
  const size_t o_Kb    = alloc((size_t)MR*768*2);
  const size_t o_VT    = alloc((size_t)MR*768*2);
  const size_t o_Ob    = alloc((size_t)MR*768*2);
  const size_t o_qp    = alloc((size_t)768*4);
  const size_t o_pool  = alloc((size_t)16*768*4);
  const size_t o_poolf = alloc((size_t)16*768*4);
  const size_t o_hl    = alloc((size_t)16*768*2);
  if (off > ws_size) return;  // workspace too small: fail visibly (poisoned out)

  float* x    = (float*)(ws + o_x);
  bf16*  xn   = (bf16*)(ws + o_xn);
  bf16*  hb   = (bf16*)(ws + o_kv);    // W1 output (bf16), MRx3072
  bf16*  kvb  = (bf16*)(ws + o_kv);    // pool kv (bf16), reuses same slab
  float* P    = (float*)(ws + o_P);
  bf16*  Qb   = (bf16*)(ws + o_Qb);
  bf16*  Kb   = (bf16*)(ws + o_Kb);
  bf16*  VTb  = (bf16*)(ws + o_VT);
  bf16*  Ob   = (bf16*)(ws + o_Ob);
  float* qp   = (float*)(ws + o_qp);
  float* pooled  = (float*)(ws + o_pool);
  float* pooledf = (float*)(ws + o_poolf);
  bf16*  hl   = (bf16*)(ws + o_hl);

  // ---- batched weight transpose + bf16 convert (64x64 tiles, 2 per block)
  TDesc td; int ne = 0, total = 0;
  auto add = [&](const float* s, size_t dofs, int R, int C){
    td.e[ne].src = s;
    td.e[ne].dst = (bf16*)(ws + dofs);
    td.e[ne].R = R; td.e[ne].C = C;
    td.e[ne].tiles = (R/64)*(C/64); td.e[ne].tC = C/64;
    total += td.e[ne].tiles; ++ne;
  };
  add(W_emb, o_WembT, 768, 768);
  for (int l = 0; l < NLAYER; ++l) {
    add(Wq  + (size_t)l*768*768,  o_QKVT[l],                 768, 768);
    add(Wkv + (size_t)l*768*1536, o_QKVT[l] + (size_t)768*768*2, 768, 1536);
    add(Wo  + (size_t)l*768*768,  o_WoT[l],                  768, 768);
    add(W1  + (size_t)l*768*3072, o_W1T[l],                  768, 3072);
    add(W2  + (size_t)l*3072*768, o_W2T[l],                  3072, 768);
  }
  add(pWkv, o_pWkvT, 768, 1536);
  transpose_kernel<<<total/2, 256, 0, stream>>>(td, ne);   // all entries have even tile counts

  // ---- embed: LN -> split-K GEMM (PD=4) -> fused reduce+bias+LN+pos+attnLN0
  ln768_kernel<<<MR, 256, 0, stream>>>(patches, emb_ln_g, xn);
  gemm_mfma<0,0,0,0,64,2,0,4,4><<<dim3(12,32,2), 256, 0, stream>>>(xn, (const bf16*)(ws+o_WembT), nullptr,
      P, nullptr, nullptr, nullptr, nullptr, nullptr, nullptr, MR, 768, 768);
  ln_pos2_kernel<<<MR, 256, 0, stream>>>(P, b_emb, emb_ln2_g, pos_h, pos_w, ppos, x, ln_attn_g, xn);

  // ---- transformer layers (xn holds LN(x) with this layer's attn gamma at loop entry)
  for (int l = 0; l < NLAYER; ++l) {
    // qkv GEMM: 8-wave 128x128 tile, fused in-wave qk-RMSnorm + V-transpose epilogue
    gemm_mfma<0,0,0,0,128,1,1,8,3><<<dim3(18,32), 512, 0, stream>>>(xn, (const bf16*)(ws+o_QKVT[l]), nullptr,
        nullptr, nullptr, qn_g + (size_t)l*768, kn_g + (size_t)l*768, Qb, Kb, VTb, MR, 2304, 768);
    attn_mfma<<<dim3(16,NH,NB), 256, 0, stream>>>(Qb, Kb, VTb, Ob, image_ids, lengths);
    // Wo: split-K PD=4 -> partials; fused reduce+residual+LN(ff gamma)
    gemm_mfma<0,0,0,0,64,2,0,4,4><<<dim3(12,32,2), 256, 0, stream>>>(Ob, (const bf16*)(ws+o_WoT[l]), nullptr,
        P, nullptr, nullptr, nullptr, nullptr, nullptr, nullptr, MR, 768, 768);
    res2_ln_kernel<0><<<MR, 256, 0, stream>>>(x, P, nullptr, ln_ff_g + (size_t)l*768, xn);
    // W1: 8-wave 128x128 tile, GELU, bf16 out
    gemm_mfma<1,1,1,0,128,1,0,8,3><<<dim3(24,32), 512, 0, stream>>>(xn, (const bf16*)(ws+o_W1T[l]), b1 + (size_t)l*3072,
        nullptr, hb, nullptr, nullptr, nullptr, nullptr, nullptr, MR, 3072, 768);
    // W2: split-K PD=4 -> partials; fused reduce+bias+residual+LN(next gamma)
    gemm_mfma<0,0,0,0,64,2,0,4,4><<<dim3(12,32,2), 256, 0, stream>>>(hb, (const bf16*)(ws+o_W2T[l]), nullptr,
        P, nullptr, nullptr, nullptr, nullptr, nullptr, nullptr, MR, 768, 3072);
    const float* gnext = (l + 1 < NLAYER) ? (ln_attn_g + (size_t)(l+1)*768) : final_ln_g;
    res2_ln_kernel<1><<<MR, 256, 0, stream>>>(x, P, b2v + (size_t)l*768, gnext, xn);
  }

  // ---- pooling + head (xn = LN(x, final_ln_g) from the last res2_ln)
  gemm_mfma<0,0,1,0,64,1,0,4,4><<<dim3(24,32), 256, 0, stream>>>(xn, (const bf16*)(ws+o_pWkvT), nullptr,
      nullptr, kvb, nullptr, nullptr, nullptr, nullptr, nullptr, MR, 1536, 768);
  pool_q_kernel<<<NH, 256, 0, stream>>>(pool_q, pool_ln_g, pWq, p_qn_g, qp);
  pool_attn_kernel<<<dim3(NH,NIMG,NB), 256, 0, stream>>>(kvb, qp, p_kn_g, image_ids, lengths, pooled);
  // pooled_final = pooled @ pWo + pool_q (k-parallel small-M GEMM)
  smallm_gemm<0,1><<<12, 256, 0, stream>>>(pooled, pWo, pool_q, pooledf, 768);
  ln768_kernel<<<16, 256, 0, stream>>>(pooledf, head_ln_g, hl);
  // out = LN(pooledf) @ W_head
  smallm_gemm<1,0><<<16, 256, 0, stream>>>(hl, W_head, nullptr, (float*)d_out, NCLS);
}

// Round 9
// 1002.738 us; speedup vs baseline: 1.1179x; 1.0107x over previous
//
#include <hip/hip_runtime.h>
#include <hip/hip_bf16.h>
#include <math.h>

using bf16 = __hip_bfloat16;
typedef short s16x8 __attribute__((ext_vector_type(8)));
typedef short s16x4 __attribute__((ext_vector_type(4)));
typedef float f32x4 __attribute__((ext_vector_type(4)));

#define DEVI __device__ __forceinline__

static constexpr int NB    = 4;
static constexpr int NTOK  = 1024;
static constexpr int DIM   = 768;
static constexpr int NH    = 12;
static constexpr int MLPD  = 3072;
static constexpr int NLAYER= 4;
static constexpr int NIMG  = 4;
static constexpr int NCLS  = 1000;
static constexpr int MR    = NB * NTOK;   // 4096 rows
static constexpr size_t SLAB = (size_t)MR * 768;  // split-K partial slab (f32 elems)

DEVI float b2f(bf16 v){ return __bfloat162float(v); }
DEVI bf16  f2b(float v){ return __float2bfloat16(v); }
DEVI float bu2f(unsigned short u){ union{unsigned u32; float f;} w; w.u32 = ((unsigned)u)<<16; return w.f; }
DEVI unsigned short f2bu(float f){ bf16 b = f2b(f); return *(unsigned short*)&b; }

DEVI void async16(const void* g, void* l) {
  __builtin_amdgcn_global_load_lds((const __attribute__((address_space(1))) void*)g,
                                   (__attribute__((address_space(3))) void*)l, 16, 0, 0);
}

DEVI f32x4 mfma16(s16x8 a, s16x8 b, f32x4 c) {
  return __builtin_amdgcn_mfma_f32_16x16x32_bf16(a, b, c, 0, 0, 0);
}

template<int N> DEVI void waitcnt_vm() {
  if constexpr (N == 0)      asm volatile("s_waitcnt vmcnt(0)" ::: "memory");
  else if constexpr (N == 1) asm volatile("s_waitcnt vmcnt(1)" ::: "memory");
  else if constexpr (N == 2) asm volatile("s_waitcnt vmcnt(2)" ::: "memory");
  else if constexpr (N == 3) asm volatile("s_waitcnt vmcnt(3)" ::: "memory");
  else if constexpr (N == 4) asm volatile("s_waitcnt vmcnt(4)" ::: "memory");
  else if constexpr (N == 6) asm volatile("s_waitcnt vmcnt(6)" ::: "memory");
}

DEVI float block_sum(float v, float* scratch, int tid) {
  #pragma unroll
  for (int o = 32; o >= 1; o >>= 1) v += __shfl_xor(v, o);
  __syncthreads();
  if ((tid & 63) == 0) scratch[tid >> 6] = v;
  __syncthreads();
  return scratch[0] + scratch[1] + scratch[2] + scratch[3];
}

DEVI float block_max(float v, float* scratch, int tid) {
  #pragma unroll
  for (int o = 32; o >= 1; o >>= 1) v = fmaxf(v, __shfl_xor(v, o));
  __syncthreads();
  if ((tid & 63) == 0) scratch[tid >> 6] = v;
  __syncthreads();
  return fmaxf(fmaxf(scratch[0], scratch[1]), fmaxf(scratch[2], scratch[3]));
}

// ---------------------------------------------------------------- transpose + f32->bf16 convert
// 2x 64x64 tiles per block; pitch 70 u16 keeps the phase-2 gather ~conflict-free.
struct TEntry { const float* src; bf16* dst; int R, C, tiles, tC; };
struct TDesc  { TEntry e[22]; };

__global__ __launch_bounds__(256) void transpose_kernel(TDesc D, int nent) {
  int tix = blockIdx.x * 2, ei = 0;            // tile index (entries all have even tile counts)
  while (ei < nent - 1 && tix >= D.e[ei].tiles) { tix -= D.e[ei].tiles; ++ei; }
  const TEntry E = D.e[ei];
  __shared__ unsigned short t[2][64][70];      // 2 x 8.75 KB
  const int tid = threadIdx.x;
  const int r = tid >> 4, c = (tid & 15) * 4;
  float4 v[2][4];
  #pragma unroll
  for (int q = 0; q < 2; ++q) {
    const int tr = (tix + q) / E.tC, tc = (tix + q) % E.tC;
    #pragma unroll
    for (int p = 0; p < 4; ++p)
      v[q][p] = *(const float4*)(E.src + (size_t)(tr*64 + p*16 + r)*E.C + tc*64 + c);
  }
  #pragma unroll
  for (int q = 0; q < 2; ++q) {
    #pragma unroll
    for (int p = 0; p < 4; ++p) {
      unsigned short* dst = &t[q][p*16 + r][c];
      dst[0] = f2bu(v[q][p].x); dst[1] = f2bu(v[q][p].y);
      dst[2] = f2bu(v[q][p].z); dst[3] = f2bu(v[q][p].w);
    }
    __syncthreads();
    const int tr = (tix + q) / E.tC, tc = (tix + q) % E.tC;
    #pragma unroll
    for (int p = 0; p < 2; ++p) {
      const int n = p*32 + (tid >> 3);
      const int r0 = (tid & 7) * 8;
      s16x8 o;
      #pragma unroll
      for (int i = 0; i < 8; ++i) o[i] = (short)t[q][r0 + i][n];
      *(s16x8*)((short*)E.dst + (size_t)(tc*64 + n)*E.R + tr*64 + r0) = o;
    }
  }
}

// ---------------------------------------------------------------- LayerNorm (768 cols), f32 in, bf16 out
__global__ __launch_bounds__(256) void ln768_kernel(const float* __restrict__ in,
    const float* __restrict__ g, bf16* __restrict__ out)
{
  __shared__ float scratch[4];
  const int row = blockIdx.x, tid = threadIdx.x;
  const float* p = in + (size_t)row*768;
  const float v0 = p[tid], v1 = p[tid+256], v2 = p[tid+512];
  const float s  = block_sum(v0+v1+v2, scratch, tid);
  const float ss = block_sum(v0*v0+v1*v1+v2*v2, scratch, tid);
  const float mu = s * (1.0f/768.0f);
  const float var = ss * (1.0f/768.0f) - mu*mu;
  const float rstd = rsqrtf(var + 1e-5f);
  bf16* o = out + (size_t)row*768;
  o[tid]     = f2b((v0-mu)*rstd*g[tid]);
  o[tid+256] = f2b((v1-mu)*rstd*g[tid+256]);
  o[tid+512] = f2b((v2-mu)*rstd*g[tid+512]);
}

// Fused split-K reduce + residual + LayerNorm:
// x += P0 + P1 (+bias); xn = LN(x)*g (bf16). x updated in place.
template<int HAS_BIAS>
__global__ __launch_bounds__(256) void res2_ln_kernel(float* __restrict__ x,
    const float* __restrict__ P, const float* __restrict__ bias,
    const float* __restrict__ g, bf16* __restrict__ xn)
{
  __shared__ float scratch[4];
  const int row = blockIdx.x, tid = threadIdx.x;
  const size_t base = (size_t)row*768;
  const float* p0 = P + base;
  const float* p1 = P + SLAB + base;
  float* xr = x + base;
  float v[3];
  #pragma unroll
  for (int i = 0; i < 3; ++i) {
    const int c = tid + i*256;
    float t = xr[c] + p0[c] + p1[c];
    if constexpr (HAS_BIAS) t += bias[c];
    v[i] = t;
    xr[c] = t;
  }
  const float s  = block_sum(v[0]+v[1]+v[2], scratch, tid);
  const float ss = block_sum(v[0]*v[0]+v[1]*v[1]+v[2]*v[2], scratch, tid);
  const float mu = s * (1.0f/768.0f);
  const float rstd = rsqrtf(ss*(1.0f/768.0f) - mu*mu + 1e-5f);
  bf16* o = xn + base;
  #pragma unroll
  for (int i = 0; i < 3; ++i) {
    const int c = tid + i*256;
    o[c] = f2b((v[i]-mu)*rstd*g[c]);
  }
}

// Fused embed: v = P0+P1+b_emb; x = LN(v)*g + pos_h + pos_w; xn = LN(x)*g2 (layer-0 attn LN)
__global__ __launch_bounds__(256) void ln_pos2_kernel(const float* __restrict__ P,
    const float* __restrict__ bias, const float* __restrict__ g,
    const float* __restrict__ pos_h, const float* __restrict__ pos_w,
    const int* __restrict__ ppos, float* __restrict__ out,
    const float* __restrict__ g2, bf16* __restrict__ xn)
{
  __shared__ float scratch[4];
  const int row = blockIdx.x, tid = threadIdx.x;
  const size_t base = (size_t)row*768;
  const float* p0 = P + base;
  const float* p1 = P + SLAB + base;
  float v[3];
  #pragma unroll
  for (int i = 0; i < 3; ++i) {
    const int c = tid + i*256;
    v[i] = p0[c] + p1[c] + bias[c];
  }
  const float s  = block_sum(v[0]+v[1]+v[2], scratch, tid);
  const float ss = block_sum(v[0]*v[0]+v[1]*v[1]+v[2]*v[2], scratch, tid);
  const float mu = s * (1.0f/768.0f);
  const float rstd = rsqrtf(ss*(1.0f/768.0f) - mu*mu + 1e-5f);
  const int p0i = ppos[row*2], p1i = ppos[row*2+1];
  const float* ph = pos_h + (size_t)p0i*768;
  const float* pw = pos_w + (size_t)p1i*768;
  float* o = out + base;
  float xv[3];
  #pragma unroll
  for (int i = 0; i < 3; ++i) {
    const int c = tid + i*256;
    xv[i] = (v[i]-mu)*rstd*g[c] + ph[c] + pw[c];
    o[c] = xv[i];
  }
  // second LN (layer-0 attention LN) on the register-resident row
  const float s2  = block_sum(xv[0]+xv[1]+xv[2], scratch, tid);
  const float ss2 = block_sum(xv[0]*xv[0]+xv[1]*xv[1]+xv[2]*xv[2], scratch, tid);
  const float mu2 = s2 * (1.0f/768.0f);
  const float rstd2 = rsqrtf(ss2*(1.0f/768.0f) - mu2*mu2 + 1e-5f);
  bf16* on = xn + base;
  #pragma unroll
  for (int i = 0; i < 3; ++i) {
    const int c = tid + i*256;
    on[c] = f2b((xv[i]-mu2)*rstd2*g2[c]);
  }
}

// ---------------------------------------------------------------- GEMM (MFMA, XOR-swizzled LDS)
// PD-deep global_load_lds pipeline, counted vmcnt (T3/T4), XCD-bijective swizzle (T1).
// WAVES=4/8. Staging is a unified LDS-row list (A rows 0..63 then B rows 0..NTILE/2-1),
// RPL=8*WAVES rows per loop; for WAVES=8/NTILE=64 the last loop is half-active (waves 0-3
// load B, 4-7 idle) with per-wave-class vmcnt. SPLITK>1: blockIdx.z selects a K-chunk;
// partials to slab z, reduced in res2_ln/ln_pos2. RMSQKV (NTILE=128 only): each wave's
// 64-col half is one head; epilogue does in-wave qk-RMSnorm -> Qb/Kb, or V-transpose -> VT.
template<int DO_BIAS, int DO_GELU, int OUT_BF16, int DO_RES, int NTILE, int SPLITK,
         int RMSQKV, int WAVES, int PD>
__global__ __launch_bounds__(WAVES*64)
void gemm_mfma(const bf16* __restrict__ A, const bf16* __restrict__ BT,
               const float* __restrict__ bias, float* __restrict__ Cf,
               bf16* __restrict__ Cb,
               const float* __restrict__ qg, const float* __restrict__ kg,
               bf16* __restrict__ Qp, bf16* __restrict__ Kp, bf16* __restrict__ Vp,
               int M, int Nn, int K)
{
  constexpr int NF    = NTILE / 32;         // n-frags per wave (2 or 4)
  constexpr int WY    = WAVES / 2;          // waves along M
  constexpr int MROWS = 128 / WY;           // rows per wave (64 or 32)
  constexpr int MF    = MROWS / 16;         // m-frags per wave (4 or 2)
  constexpr int TOTROWS = 64 + NTILE/2;     // LDS rows per K-step (A then B)
  constexpr int RPL   = 8*WAVES;            // rows staged per loop
  constexpr int NLOOPS= (TOTROWS + RPL - 1) / RPL;
  constexpr bool UNEVEN = (TOTROWS % RPL) != 0;
  constexpr int VW_HI = (PD - 2) * NLOOPS;  // steady-state vmcnt (full waves)
  constexpr int VW_LO = (PD - 2) * (NLOOPS - 1);  // waves idle in last loop
  __shared__ bf16 As[PD][64*64];            // PD x 8 KB
  __shared__ bf16 Bs[PD][(NTILE/2)*64];     // PD x (4 or 8) KB
  const int tid = threadIdx.x;
  const int wid = tid >> 6, lane = tid & 63;
  const int quad = lane >> 4, l15 = lane & 15;
  const int wy = wid >> 1, wx = wid & 1;

  // XCD-aware bijective swizzle (m204 form), per K-chunk plane.
  const int gx  = gridDim.x;
  const int nwg = gx * gridDim.y;
  const int bid = blockIdx.y * gx + blockIdx.x;
  const int qq  = nwg >> 3, rm = nwg & 7;
  const int xcd = bid & 7,  li = bid >> 3;
  const int swz = (xcd < rm ? xcd * (qq + 1) : rm * (qq + 1) + (xcd - rm) * qq) + li;
  const int m0 = (swz / gx) * 128, n0 = (swz % gx) * NTILE;

  const int kz    = (SPLITK > 1) ? blockIdx.z : 0;
  const int kloc  = K / SPLITK;             // K per chunk
  const int kbase = kz * kloc;

  const int rl = lane >> 3;                 // local LDS row 0..7
  const int cs = lane & 7;                  // slot 0..7

  f32x4 acc[MF][NF];
  #pragma unroll
  for (int i = 0; i < MF; ++i)
    #pragma unroll
    for (int j = 0; j < NF; ++j) acc[i][j] = (f32x4){0.f,0.f,0.f,0.f};

  auto stage = [&](int buf, int k0) {
    #pragma unroll
    for (int c = 0; c < NLOOPS; ++c) {
      const int rbase = wid*8 + c*RPL;      // wave-uniform
      if (UNEVEN && rbase >= TOTROWS) continue;
      if (rbase < 64) {                     // A rows
        const int r_abs = rbase + rl;
        const int ceff  = cs ^ (r_abs & 7);
        const int mg    = 2*r_abs + (ceff >> 2);
        const int jb    = (ceff & 3) * 16;
        async16((const char*)A + ((size_t)(m0 + mg)*K + k0)*2 + jb, (char*)As[buf] + rbase*128);
      } else {                              // B rows
        const int rb2   = rbase - 64;
        const int r_abs = rb2 + rl;
        const int ceff  = cs ^ (r_abs & 7);
        const int ng    = 2*r_abs + (ceff >> 2);
        const int jb    = (ceff & 3) * 16;
        async16((const char*)BT + ((size_t)(n0 + ng)*K + k0)*2 + jb, (char*)Bs[buf] + rb2*128);
      }
    }
  };

  auto wait_steady = [&]() {
    if constexpr (UNEVEN) {
      if (wid*8 + (NLOOPS-1)*RPL < TOTROWS) waitcnt_vm<VW_HI>();
      else waitcnt_vm<VW_LO>();
    } else {
      waitcnt_vm<VW_HI>();
    }
  };

  auto compute = [&](int cb) {
    s16x8 af[MF], bfr[NF];
    #pragma unroll
    for (int mt = 0; mt < MF; ++mt) {
      const int m = wy*MROWS + mt*16 + l15;
      const int r = m >> 1;
      const int cq = (((m & 1) << 2) | quad) ^ (r & 7);
      af[mt] = *(const s16x8*)((const char*)As[cb] + r*128 + cq*16);
    }
    #pragma unroll
    for (int nt = 0; nt < NF; ++nt) {
      const int n = wx*(NTILE/2) + nt*16 + l15;
      const int r = n >> 1;
      const int cq = (((n & 1) << 2) | quad) ^ (r & 7);
      bfr[nt] = *(const s16x8*)((const char*)Bs[cb] + r*128 + cq*16);
    }
    #pragma unroll
    for (int mt = 0; mt < MF; ++mt)
      #pragma unroll
      for (int nt = 0; nt < NF; ++nt)
        acc[mt][nt] = mfma16(af[mt], bfr[nt], acc[mt][nt]);
  };

  const int nk = kloc >> 5;
  #pragma unroll
  for (int t = 0; t < PD - 1; ++t) stage(t, kbase + (t << 5));

  int cbuf = 0, sbuf = PD - 1;
  const int mainN = nk - (PD - 1);
  for (int kt = 0; kt < mainN; ++kt) {
    __builtin_amdgcn_sched_barrier(0);
    wait_steady();                          // tile kt complete; later tiles stay in flight
    __builtin_amdgcn_s_barrier();
    __builtin_amdgcn_sched_barrier(0);
    stage(sbuf, kbase + ((kt + PD - 1) << 5));
    compute(cbuf);
    cbuf = (cbuf + 1 == PD) ? 0 : cbuf + 1;
    sbuf = (sbuf + 1 == PD) ? 0 : sbuf + 1;
  }
  for (int kt = mainN; kt < nk; ++kt) {     // tail: drain
    __builtin_amdgcn_sched_barrier(0);
    waitcnt_vm<0>();
    __builtin_amdgcn_s_barrier();
    __builtin_amdgcn_sched_barrier(0);
    compute(cbuf);
    cbuf = (cbuf + 1 == PD) ? 0 : cbuf + 1;
  }

  if constexpr (RMSQKV) {
    // NTILE==128: wave wx's 64-col half is exactly one head slice; rms fully in-wave.
    const int hslice = (n0 >> 6) + wx;      // 0..35 (tiles never straddle Q/K/V regions)
    const int region = hslice / NH;         // 0:Q 1:K 2:V
    const int h  = hslice - region*NH;
    const int b  = m0 >> 10;
    const int bh = b*NH + h;
    const int tokb = m0 & (NTOK-1);
    if (region < 2) {
      const float* gp = (region == 0) ? (qg + h*64) : (kg + h*64);
      bf16* outb = (region == 0) ? Qp : Kp;
      #pragma unroll
      for (int mt = 0; mt < MF; ++mt)
        #pragma unroll
        for (int rr = 0; rr < 4; ++rr) {
          float ssq = 0.f;
          #pragma unroll
          for (int nt = 0; nt < NF; ++nt) ssq += acc[mt][nt][rr]*acc[mt][nt][rr];
          #pragma unroll
          for (int o = 1; o <= 8; o <<= 1) ssq += __shfl_xor(ssq, o);
          const float rn = 8.0f / fmaxf(sqrtf(ssq), 1e-12f);
          const int tok = tokb + wy*MROWS + mt*16 + quad*4 + rr;
          #pragma unroll
          for (int nt = 0; nt < NF; ++nt) {
            const int d = nt*16 + l15;
            outb[((size_t)bh*NTOK + tok)*64 + d] = f2b(acc[mt][nt][rr]*rn*gp[d]);
          }
        }
    } else {
      // V: write transposed VT[bh*64+d][tok], 4 consecutive tokens per 8B store
      #pragma unroll
      for (int mt = 0; mt < MF; ++mt)
        #pragma unroll
        for (int nt = 0; nt < NF; ++nt) {
          const int d = nt*16 + l15;
          const int tok = tokb + wy*MROWS + mt*16 + quad*4;
          s16x4 pk;
          #pragma unroll
          for (int rr = 0; rr < 4; ++rr) pk[rr] = (short)f2bu(acc[mt][nt][rr]);
          *(s16x4*)((short*)Vp + ((size_t)bh*64 + d)*NTOK + tok) = pk;
        }
    }
  } else {
    float* Cslab = (SPLITK > 1) ? (Cf + (size_t)kz * SLAB) : Cf;
    #pragma unroll
    for (int nt = 0; nt < NF; ++nt) {
      const int col = n0 + wx*(NTILE/2) + nt*16 + l15;
      float bv = 0.f;
      if constexpr (DO_BIAS) bv = bias[col];
      #pragma unroll
      for (int mt = 0; mt < MF; ++mt) {
        #pragma unroll
        for (int r = 0; r < 4; ++r) {
          const int row = m0 + wy*MROWS + mt*16 + quad*4 + r;
          float v = acc[mt][nt][r];
          if constexpr (DO_BIAS) v += bv;
          if constexpr (DO_GELU) v = 0.5f*v*(1.0f + erff(v*0.70710678118654752f));
          const size_t idx = (size_t)row*Nn + col;
          if constexpr (OUT_BF16) Cb[idx] = f2b(v);
          else if constexpr (DO_RES) Cslab[idx] += v;
          else Cslab[idx] = v;
        }
      }
    }
  }
}

// ---------------------------------------------------------------- small-M GEMM (M=16, K=768)
template<int IN_BF16, int DO_BIAS>
__global__ __launch_bounds__(256) void smallm_gemm(const void* __restrict__ Xv,
    const float* __restrict__ W, const float* __restrict__ bias,
    float* __restrict__ out, int Nn)
{
  __shared__ float Xs[16*768];
  __shared__ float red[4][16][64];
  const int tid = threadIdx.x;
  if constexpr (IN_BF16) {
    const bf16* X = (const bf16*)Xv;
    for (int i = tid; i < 16*768; i += 256) Xs[i] = b2f(X[i]);
  } else {
    const float* X = (const float*)Xv;
    for (int i = tid; i < 16*768; i += 256) Xs[i] = X[i];
  }
  __syncthreads();
  const int cl = tid & 63, kg = tid >> 6;
  const int c = blockIdx.x*64 + cl;
  float acc[16];
  #pragma unroll
  for (int r = 0; r < 16; ++r) acc[r] = 0.f;
  if (c < Nn) {
    const int k0 = kg*192;
    #pragma unroll 4
    for (int k = k0; k < k0 + 192; ++k) {
      const float w = W[(size_t)k*Nn + c];
      #pragma unroll
      for (int r = 0; r < 16; ++r) acc[r] += Xs[r*768 + k] * w;
    }
  }
  #pragma unroll
  for (int r = 0; r < 16; ++r) red[kg][r][cl] = acc[r];
  __syncthreads();
  if (kg == 0 && c < Nn) {
    #pragma unroll
    for (int r = 0; r < 16; ++r) {
      float v = red[0][r][cl] + red[1][r][cl] + red[2][r][cl] + red[3][r][cl];
      if constexpr (DO_BIAS) v += bias[c];
      out[(size_t)r*Nn + c] = v;
    }
  }
}

// ---------------------------------------------------------------- fused MFMA attention
__global__ __launch_bounds__(256) void attn_mfma(const bf16* __restrict__ Qb,
    const bf16* __restrict__ Kb, const bf16* __restrict__ VTb, bf16* __restrict__ Ob,
    const int* __restrict__ ids, const int* __restrict__ lens)
{
  __shared__ bf16 Ps[4][16*72];   // per-wave P tile [m=16][j=64], row stride 72 elems
  __shared__ int  ids_s[NTOK];
  const int qt = blockIdx.x, h = blockIdx.y, b = blockIdx.z;
  const int tid = threadIdx.x;
  const int wid = tid >> 6, lane = tid & 63;
  const int quad = lane >> 4, l15 = lane & 15;
  const int bh = b*NH + h;
  const int q0 = qt*64;
  const int len = lens[b];

  #pragma unroll
  for (int i = 0; i < 4; ++i) ids_s[i*256 + tid] = ids[b*NTOK + i*256 + tid];
  __syncthreads();

  const bf16* qrow = Qb + ((size_t)bh*NTOK + q0 + wid*16 + l15)*64;
  const s16x8 aq0 = *(const s16x8*)(qrow + quad*8);
  const s16x8 aq1 = *(const s16x8*)(qrow + 32 + quad*8);

  int idq[4];
  #pragma unroll
  for (int rr = 0; rr < 4; ++rr) idq[rr] = ids_s[q0 + wid*16 + quad*4 + rr];

  unsigned qm = 0;
  #pragma unroll
  for (int rr = 0; rr < 4; ++rr) qm |= 1u << (idq[rr] & 31);
  #pragma unroll
  for (int o = 32; o >= 1; o >>= 1) qm |= (unsigned)__shfl_xor((int)qm, o);

  f32x4 oacc[4];
  #pragma unroll
  for (int nt = 0; nt < 4; ++nt) oacc[nt] = (f32x4){0.f,0.f,0.f,0.f};
  float mrow[4] = {-3.0e38f,-3.0e38f,-3.0e38f,-3.0e38f};
  float lrow[4] = {0.f,0.f,0.f,0.f};

  const bf16* Kgb = Kb  + (size_t)bh*NTOK*64;
  const bf16* Vgb = VTb + (size_t)bh*64*NTOK;
  bf16* pw = Ps[wid];

  for (int kt = 0; kt < 16; ++kt) {
    const int k0 = kt*64;
    const int idk_l = ids_s[k0 + lane];
    const bool ok = ((k0 + lane) < len) && (((qm >> (idk_l & 31)) & 1u) != 0u);
    if (__ballot(ok) == 0ULL) continue;

    f32x4 sA[4];
    #pragma unroll
    for (int jt = 0; jt < 4; ++jt) {
      const bf16* krow = Kgb + (size_t)(k0 + jt*16 + l15)*64;
      const s16x8 bk0 = *(const s16x8*)(krow + quad*8);
      const s16x8 bk1 = *(const s16x8*)(krow + 32 + quad*8);
      f32x4 s = (f32x4){0.f,0.f,0.f,0.f};
      s = mfma16(aq0, bk0, s);
      s = mfma16(aq1, bk1, s);
      sA[jt] = s;
    }
    #pragma unroll
    for (int jt = 0; jt < 4; ++jt) {
      const int j = k0 + jt*16 + l15;
      const int idk = ids_s[j];
      const bool kvld = j < len;
      #pragma unroll
      for (int rr = 0; rr < 4; ++rr)
        sA[jt][rr] = (kvld && idk == idq[rr]) ? sA[jt][rr] : -3.0e38f;
    }
    float alpha[4], mnew[4];
    #pragma unroll
    for (int rr = 0; rr < 4; ++rr) {
      float mx = fmaxf(fmaxf(sA[0][rr], sA[1][rr]), fmaxf(sA[2][rr], sA[3][rr]));
      mx = fmaxf(mx, __shfl_xor(mx, 1));
      mx = fmaxf(mx, __shfl_xor(mx, 2));
      mx = fmaxf(mx, __shfl_xor(mx, 4));
      mx = fmaxf(mx, __shfl_xor(mx, 8));
      const float mn = fmaxf(mrow[rr], mx);
      mnew[rr] = mn;
      alpha[rr] = expf(mrow[rr] - mn);
      mrow[rr] = mn;
    }
    #pragma unroll
    for (int rr = 0; rr < 4; ++rr) {
      float rs = 0.f;
      #pragma unroll
      for (int jt = 0; jt < 4; ++jt) {
        const float pv = (sA[jt][rr] > -1.0e38f) ? expf(sA[jt][rr] - mnew[rr]) : 0.0f;
        sA[jt][rr] = pv;
        rs += pv;
      }
      rs += __shfl_xor(rs, 1);
      rs += __shfl_xor(rs, 2);
      rs += __shfl_xor(rs, 4);
      rs += __shfl_xor(rs, 8);
      lrow[rr] = lrow[rr]*alpha[rr] + rs;
      #pragma unroll
      for (int nt = 0; nt < 4; ++nt) oacc[nt][rr] *= alpha[rr];
    }
    #pragma unroll
    for (int jt = 0; jt < 4; ++jt)
      #pragma unroll
      for (int rr = 0; rr < 4; ++rr)
        pw[(quad*4+rr)*72 + jt*16 + l15] = f2b(sA[jt][rr]);
    #pragma unroll
    for (int ss = 0; ss < 2; ++ss) {
      const s16x8 ap = *(const s16x8*)(pw + l15*72 + ss*32 + quad*8);
      #pragma unroll
      for (int nt = 0; nt < 4; ++nt) {
        const s16x8 bv = *(const s16x8*)(Vgb + (size_t)(nt*16 + l15)*NTOK + k0 + ss*32 + quad*8);
        oacc[nt] = mfma16(ap, bv, oacc[nt]);
      }
    }
  }

  #pragma unroll
  for (int rr = 0; rr < 4; ++rr) {
    const float inv = lrow[rr] > 0.f ? 1.0f/lrow[rr] : 0.0f;
    const int n = q0 + wid*16 + quad*4 + rr;
    bf16* orow = Ob + ((size_t)b*NTOK + n)*768 + h*64;
    #pragma unroll
    for (int nt = 0; nt < 4; ++nt)
      orow[nt*16 + l15] = f2b(oacc[nt][rr]*inv);
  }
}

// ---------------------------------------------------------------- pooling path
__global__ __launch_bounds__(256) void pool_q_kernel(const float* __restrict__ pool_q,
    const float* __restrict__ pool_ln_g, const float* __restrict__ pWq,
    const float* __restrict__ p_qn_g, float* __restrict__ qp)
{
  __shared__ float xn[768];
  __shared__ float scratch[4];
  __shared__ float qraw[64];
  const int h = blockIdx.x, tid = threadIdx.x;
  float v0 = pool_q[tid], v1 = pool_q[tid+256], v2 = pool_q[tid+512];
  const float s  = block_sum(v0+v1+v2, scratch, tid);
  const float ss = block_sum(v0*v0+v1*v1+v2*v2, scratch, tid);
  const float mu = s*(1.0f/768.0f);
  const float rstd = rsqrtf(ss*(1.0f/768.0f) - mu*mu + 1e-5f);
  xn[tid]     = (v0-mu)*rstd*pool_ln_g[tid];
  xn[tid+256] = (v1-mu)*rstd*pool_ln_g[tid+256];
  xn[tid+512] = (v2-mu)*rstd*pool_ln_g[tid+512];
  __syncthreads();
  const int d = tid >> 2, pp = tid & 3;
  const int col = h*64 + d;
  float acc = 0.f;
  for (int k = pp*192; k < (pp+1)*192; ++k) acc += xn[k]*pWq[(size_t)k*768 + col];
  acc += __shfl_xor(acc, 1); acc += __shfl_xor(acc, 2);
  if (pp == 0) qraw[d] = acc;
  __syncthreads();
  if (tid < 64) {
    const float q = qraw[tid];
    float sq = q*q;
    #pragma unroll
    for (int o = 32; o >= 1; o >>= 1) sq += __shfl_xor(sq, o);
    const float rn = 8.0f / fmaxf(sqrtf(sq), 1e-12f);
    qp[h*64 + tid] = q * rn * p_qn_g[h*64 + tid];
  }
}

__global__ __launch_bounds__(256) void pool_attn_kernel(const bf16* __restrict__ kvp,
    const float* __restrict__ qp, const float* __restrict__ kg,
    const int* __restrict__ ids, const int* __restrict__ lens, float* __restrict__ pooled)
{
  __shared__ float sp[1024];
  __shared__ float qg_s[64];
  __shared__ float scratch[4];
  __shared__ float outred[4][64];
  const int h = blockIdx.x, img = blockIdx.y, b = blockIdx.z;
  const int tid = threadIdx.x;
  const int len = lens[b];
  if (tid < 64) qg_s[tid] = qp[h*64 + tid] * kg[h*64 + tid];
  __syncthreads();

  float smax = -3.0e38f;
  for (int j = tid; j < 1024; j += 256) {
    float sv = -3.0e38f;
    if (j < len && ids[b*NTOK + j] == img) {
      const bf16* kr = kvp + (size_t)(b*NTOK + j)*1536 + h*64;
      float ssq = 0.f, dq = 0.f;
      #pragma unroll
      for (int dd = 0; dd < 64; dd += 8) {
        s16x8 k8 = *(const s16x8*)(kr + dd);
        #pragma unroll
        for (int i = 0; i < 8; ++i) {
          const float kv = bu2f((unsigned short)k8[i]);
          ssq += kv*kv;
          dq  += qg_s[dd+i]*kv;
        }
      }
      const float rn = 8.0f / fmaxf(sqrtf(ssq), 1e-12f);
      sv = dq * rn;
    }
    sp[j] = sv;
    smax = fmaxf(smax, sv);
  }
  const float M = block_max(smax, scratch, tid);
  float lsum = 0.f;
  for (int j = tid; j < 1024; j += 256) {
    const float p = (sp[j] > -1.0e38f) ? expf(sp[j] - M) : 0.0f;
    sp[j] = p;
    lsum += p;
  }
  const float L = block_sum(lsum, scratch, tid);
  const float invL = L > 0.f ? 1.0f / L : 0.0f;

  const int d = tid & 63, jg = tid >> 6;
  float acc = 0.f;
  for (int j = jg; j < 1024; j += 4) {
    const float p = sp[j];
    if (p > 0.f) acc += p * b2f(kvp[(size_t)(b*NTOK + j)*1536 + 768 + h*64 + d]);
  }
  outred[jg][d] = acc;
  __syncthreads();
  if (tid < 64) {
    const float o = (outred[0][tid] + outred[1][tid] + outred[2][tid] + outred[3][tid]) * invL;
    pooled[((size_t)b*NIMG + img)*768 + h*64 + tid] = o;
  }
}

// ---------------------------------------------------------------- host
extern "C" void kernel_launch(void* const* d_in, const int* in_sizes, int n_in,
                              void* d_out, int out_size, void* d_ws, size_t ws_size,
                              hipStream_t stream)
{
  const float* patches    = (const float*)d_in[0];
  const int*   ppos       = (const int*)d_in[1];
  const int*   image_ids  = (const int*)d_in[2];
  const int*   lengths    = (const int*)d_in[3];
  const float* emb_ln_g   = (const float*)d_in[4];
  const float* W_emb      = (const float*)d_in[5];
  const float* b_emb      = (const float*)d_in[6];
  const float* emb_ln2_g  = (const float*)d_in[7];
  const float* pos_h      = (const float*)d_in[8];
  const float* pos_w      = (const float*)d_in[9];
  const float* ln_attn_g  = (const float*)d_in[10];
  const float* Wq         = (const float*)d_in[11];
  const float* Wkv        = (const float*)d_in[12];
  const float* qn_g       = (const float*)d_in[13];
  const float* kn_g       = (const float*)d_in[14];
  const float* Wo         = (const float*)d_in[15];
  const float* ln_ff_g    = (const float*)d_in[16];
  const float* W1         = (const float*)d_in[17];
  const float* b1         = (const float*)d_in[18];
  const float* W2         = (const float*)d_in[19];
  const float* b2v        = (const float*)d_in[20];
  const float* final_ln_g = (const float*)d_in[21];
  const float* pool_q     = (const float*)d_in[22];
  const float* pool_ln_g  = (const float*)d_in[23];
  const float* pWq        = (const float*)d_in[24];
  const float* pWkv       = (const float*)d_in[25];
  const float* p_qn_g     = (const float*)d_in[26];
  const float* p_kn_g     = (const float*)d_in[27];
  const float* pWo        = (const float*)d_in[28];
  const float* head_ln_g  = (const float*)d_in[29];
  const float* W_head     = (const float*)d_in[30];

  char* ws = (char*)d_ws;
  size_t off = 0;
  auto alloc = [&](size_t sz){ size_t r = off; off += (sz + 255) & ~(size_t)255; return r; };

  const size_t o_WembT = alloc((size_t)768*768*2);
  size_t o_QKVT[4], o_WoT[4], o_W1T[4], o_W2T[4];
  for (int l = 0; l < NLAYER; ++l) {
    o_QKVT[l] = alloc((size_t)2304*768*2);
    o_WoT[l]  = alloc((size_t)768*768*2);
    o_W1T[l]  = alloc((size_t)3072*768*2);
    o_W2T[l]  = alloc((size_t)768*3072*2);
  }
  const size_t o_pWkvT = alloc((size_t)1536*768*2);
  const size_t o_x     = alloc((size_t)MR*768*4);
  const size_t o_xn    = alloc((size_t)MR*768*2);
  const size_t o_kv    = alloc((size_t)MR*3072*2);   // bf16: sized for W1-out h (MRx3072); also pool kv
  const size_t o_P     = alloc((size_t)2*SLAB*4);    // split-K partial slabs (2x 12.6MB)
  const size_t o_Qb    = alloc((size_t)MR*768*2);
  const size_t o_Kb    = alloc((size_t)MR*768*2);
  const size_t o_VT    = alloc((size_t)MR*768*2);
  const size_t o_Ob    = alloc((size_t)MR*768*2);
  const size_t o_qp    = alloc((size_t)768*4);
  const size_t o_pool  = alloc((size_t)16*768*4);
  const size_t o_poolf = alloc((size_t)16*768*4);
  const size_t o_hl    = alloc((size_t)16*768*2);
  if (off > ws_size) return;  // workspace too small: fail visibly (poisoned out)

  float* x    = (float*)(ws + o_x);
  bf16*  xn   = (bf16*)(ws + o_xn);
  bf16*  hb   = (bf16*)(ws + o_kv);    // W1 output (bf16), MRx3072
  bf16*  kvb  = (bf16*)(ws + o_kv);    // pool kv (bf16), reuses same slab
  float* P    = (float*)(ws + o_P);
  bf16*  Qb   = (bf16*)(ws + o_Qb);
  bf16*  Kb   = (bf16*)(ws + o_Kb);
  bf16*  VTb  = (bf16*)(ws + o_VT);
  bf16*  Ob   = (bf16*)(ws + o_Ob);
  float* qp   = (float*)(ws + o_qp);
  float* pooled  = (float*)(ws + o_pool);
  float* pooledf = (float*)(ws + o_poolf);
  bf16*  hl   = (bf16*)(ws + o_hl);

  // ---- batched weight transpose + bf16 convert (64x64 tiles, 2 per block)
  TDesc td; int ne = 0, total = 0;
  auto add = [&](const float* s, size_t dofs, int R, int C){
    td.e[ne].src = s;
    td.e[ne].dst = (bf16*)(ws + dofs);
    td.e[ne].R = R; td.e[ne].C = C;
    td.e[ne].tiles = (R/64)*(C/64); td.e[ne].tC = C/64;
    total += td.e[ne].tiles; ++ne;
  };
  add(W_emb, o_WembT, 768, 768);
  for (int l = 0; l < NLAYER; ++l) {
    add(Wq  + (size_t)l*768*768,  o_QKVT[l],                 768, 768);
    add(Wkv + (size_t)l*768*1536, o_QKVT[l] + (size_t)768*768*2, 768, 1536);
    add(Wo  + (size_t)l*768*768,  o_WoT[l],                  768, 768);
    add(W1  + (size_t)l*768*3072, o_W1T[l],                  768, 3072);
    add(W2  + (size_t)l*3072*768, o_W2T[l],                  3072, 768);
  }
  add(pWkv, o_pWkvT, 768, 1536);
  transpose_kernel<<<total/2, 256, 0, stream>>>(td, ne);   // all entries have even tile counts

  // ---- embed: LN -> 8-wave split-K GEMM -> fused reduce+bias+LN+pos+attnLN0
  ln768_kernel<<<MR, 256, 0, stream>>>(patches, emb_ln_g, xn);
  gemm_mfma<0,0,0,0,64,2,0,8,3><<<dim3(12,32,2), 512, 0, stream>>>(xn, (const bf16*)(ws+o_WembT), nullptr,
      P, nullptr, nullptr, nullptr, nullptr, nullptr, nullptr, MR, 768, 768);
  ln_pos2_kernel<<<MR, 256, 0, stream>>>(P, b_emb, emb_ln2_g, pos_h, pos_w, ppos, x, ln_attn_g, xn);

  // ---- transformer layers (xn holds LN(x) with this layer's attn gamma at loop entry)
  for (int l = 0; l < NLAYER; ++l) {
    // qkv GEMM: 8-wave 128x128 tile, fused in-wave qk-RMSnorm + V-transpose epilogue
    gemm_mfma<0,0,0,0,128,1,1,8,3><<<dim3(18,32), 512, 0, stream>>>(xn, (const bf16*)(ws+o_QKVT[l]), nullptr,
        nullptr, nullptr, qn_g + (size_t)l*768, kn_g + (size_t)l*768, Qb, Kb, VTb, MR, 2304, 768);
    attn_mfma<<<dim3(16,NH,NB), 256, 0, stream>>>(Qb, Kb, VTb, Ob, image_ids, lengths);
    // Wo: 8-wave split-K -> partials; fused reduce+residual+LN(ff gamma)
    gemm_mfma<0,0,0,0,64,2,0,8,3><<<dim3(12,32,2), 512, 0, stream>>>(Ob, (const bf16*)(ws+o_WoT[l]), nullptr,
        P, nullptr, nullptr, nullptr, nullptr, nullptr, nullptr, MR, 768, 768);
    res2_ln_kernel<0><<<MR, 256, 0, stream>>>(x, P, nullptr, ln_ff_g + (size_t)l*768, xn);
    // W1: 8-wave 128x128 tile, GELU, bf16 out
    gemm_mfma<1,1,1,0,128,1,0,8,3><<<dim3(24,32), 512, 0, stream>>>(xn, (const bf16*)(ws+o_W1T[l]), b1 + (size_t)l*3072,
        nullptr, hb, nullptr, nullptr, nullptr, nullptr, nullptr, MR, 3072, 768);
    // W2: 8-wave split-K -> partials; fused reduce+bias+residual+LN(next gamma)
    gemm_mfma<0,0,0,0,64,2,0,8,3><<<dim3(12,32,2), 512, 0, stream>>>(hb, (const bf16*)(ws+o_W2T[l]), nullptr,
        P, nullptr, nullptr, nullptr, nullptr, nullptr, nullptr, MR, 768, 3072);
    const float* gnext = (l + 1 < NLAYER) ? (ln_attn_g + (size_t)(l+1)*768) : final_ln_g;
    res2_ln_kernel<1><<<MR, 256, 0, stream>>>(x, P, b2v + (size_t)l*768, gnext, xn);
  }

  // ---- pooling + head (xn = LN(x, final_ln_g) from the last res2_ln)
  gemm_mfma<0,0,1,0,64,1,0,8,3><<<dim3(24,32), 512, 0, stream>>>(xn, (const bf16*)(ws+o_pWkvT), nullptr,
      nullptr, kvb, nullptr, nullptr, nullptr, nullptr, nullptr, MR, 1536, 768);
  pool_q_kernel<<<NH, 256, 0, stream>>>(pool_q, pool_ln_g, pWq, p_qn_g, qp);
  pool_attn_kernel<<<dim3(NH,NIMG,NB), 256, 0, stream>>>(kvb, qp, p_kn_g, image_ids, lengths, pooled);
  // pooled_final = pooled @ pWo + pool_q (k-parallel small-M GEMM)
  smallm_gemm<0,1><<<12, 256, 0, stream>>>(pooled, pWo, pool_q, pooledf, 768);
  ln768_kernel<<<16, 256, 0, stream>>>(pooledf, head_ln_g, hl);
  // out = LN(pooledf) @ W_head
  smallm_gemm<1,0><<<16, 256, 0, stream>>>(hl, W_head, nullptr, (float*)d_out, NCLS);
}